// Round 5
// baseline (606.231 us; speedup 1.0000x reference)
//
#include <hip/hip_runtime.h>
#include <hip/hip_bf16.h>
#include <math.h>

#define D_   4096
#define NIMG 16
#define NPER 64
#define RPER 512
#define NTOT 1024
#define RTOT 8192
#define DC   2048
#define DT   1024
#define LDO  10240   // fused output row stride (4096 ws | 4096 wo | 2048 conv)

typedef __attribute__((ext_vector_type(4))) float f32x4;
typedef __attribute__((ext_vector_type(8))) short bf16x8;

// ---------------------------------------------------------------------------
// multi-region f32 -> bf16 cast, 6 regions, one dispatch. 2048 elems/block.
// ---------------------------------------------------------------------------
struct Cast6 {
    const float* src[6];
    __hip_bfloat16* dst[6];
    int cum[6];   // cumulative block starts of regions 1..6 (cum[5] = total)
};

__global__ __launch_bounds__(256) void cast_multi(Cast6 a)
{
    const int b = blockIdx.x;
    int r = 0;
#pragma unroll
    for (int i = 0; i < 5; ++i) r += (b >= a.cum[i]) ? 1 : 0;
    const float* s = a.src[r];
    __hip_bfloat16* d = a.dst[r];
    const int rb = r ? b - a.cum[r - 1] : b;
    const int i = (rb * 256 + threadIdx.x) * 8;
    float4 v0 = *(const float4*)(s + i);
    float4 v1 = *(const float4*)(s + i + 4);
    union { __hip_bfloat16 h[8]; ushort4 u[2]; } cv;
    cv.h[0] = __float2bfloat16(v0.x); cv.h[1] = __float2bfloat16(v0.y);
    cv.h[2] = __float2bfloat16(v0.z); cv.h[3] = __float2bfloat16(v0.w);
    cv.h[4] = __float2bfloat16(v1.x); cv.h[5] = __float2bfloat16(v1.y);
    cv.h[6] = __float2bfloat16(v1.z); cv.h[7] = __float2bfloat16(v1.w);
    *(ushort4*)(d + i)     = cv.u[0];
    *(ushort4*)(d + i + 4) = cv.u[1];
}

// ---------------------------------------------------------------------------
__global__ __launch_bounds__(256) void concat_bias(
    const float* __restrict__ b0, const float* __restrict__ b1,
    const float* __restrict__ b2, float* __restrict__ cb)
{
    const int i = blockIdx.x * 256 + threadIdx.x;
    float v;
    if (i < 4096) v = b0[i];
    else if (i < 8192) v = b1[i - 4096];
    else v = b2[i - 8192];
    cb[i] = v;
}

// ---------------------------------------------------------------------------
// No-LDS MFMA GEMM, C = A @ B^T (+bias, act). bf16 in, f32 out.
// BM x BN tile, 256 thr (2x2 waves, wave tile BM/2 x BN/2), BK=32.
// Fragments loaded DIRECTLY global -> VGPR (A is 8MB and B N-column tiles are
// ~1MB: both L2/L3-resident given nt-grouped XCD swizzle). No LDS, no
// barriers, no bank conflicts; waves fully independent; cur/next frag sets
// ping-pong via manual 2x unroll (static indexing only).
// Frag addressing: lane reads row (lane&15), k-chunk (lane>>4)*8; frag deltas
// (m*16 rows) are wave-uniform SGPR bases.
// mode: 0 = +bias; 2 = relu(resid + . + bias); 3 = +bias, relu iff col>=reluStart
// ---------------------------------------------------------------------------
template<int BM, int BN>
__global__ __launch_bounds__(256) void gemm_nl(
    const ushort* __restrict__ A, const ushort* __restrict__ B,
    const float* __restrict__ bias, const float* __restrict__ resid,
    float* __restrict__ C, int M, int K, int ldc, int mode, int reluStart)
{
    constexpr int MREP = BM / 32;
    constexpr int NREP = BN / 32;

    const int t = threadIdx.x;
    const int lane = t & 63;
    const int wid = t >> 6;
    const int wr = wid >> 1, wc = wid & 1;

    const int MT = M / BM;
    const int G = gridDim.x;
    const int bid = blockIdx.x;
    const int wgid = (bid & 7) * (G >> 3) + (bid >> 3);   // XCD swizzle (G%8==0)
    const int nt = wgid / MT, mt = wgid % MT;             // mt-major: same-nt
    const int bm = mt * BM, bn = nt * BN;                 // blocks share an XCD

    const int lrow = lane & 15;
    const int lk   = (lane >> 4) << 3;                    // 0,8,16,24

    const ushort* pa[MREP];
    const ushort* pb[NREP];
#pragma unroll
    for (int m = 0; m < MREP; ++m)
        pa[m] = A + (size_t)(bm + wr * (BM / 2) + m * 16 + lrow) * K + lk;
#pragma unroll
    for (int n = 0; n < NREP; ++n)
        pb[n] = B + (size_t)(bn + wc * (BN / 2) + n * 16 + lrow) * K + lk;

    f32x4 acc[MREP][NREP] = {};
    bf16x8 aC[MREP], bC[NREP], aN[MREP], bN[NREP];

    // prologue: frags for k-step 0
#pragma unroll
    for (int m = 0; m < MREP; ++m) aC[m] = *(const bf16x8*)(pa[m]);
#pragma unroll
    for (int n = 0; n < NREP; ++n) bC[n] = *(const bf16x8*)(pb[n]);

    const int NT = K >> 5;   // even for all our shapes (128, 128, 32)
    for (int tt = 0; tt < NT; tt += 2) {
        // phase 0: load k-step tt+1 into N-set, MFMA on C-set
        {
            const int kp = (tt + 1) << 5;
#pragma unroll
            for (int m = 0; m < MREP; ++m) aN[m] = *(const bf16x8*)(pa[m] + kp);
#pragma unroll
            for (int n = 0; n < NREP; ++n) bN[n] = *(const bf16x8*)(pb[n] + kp);
#pragma unroll
            for (int m = 0; m < MREP; ++m)
#pragma unroll
                for (int n = 0; n < NREP; ++n)
                    acc[m][n] = __builtin_amdgcn_mfma_f32_16x16x32_bf16(
                        aC[m], bC[n], acc[m][n], 0, 0, 0);
        }
        // phase 1: load k-step tt+2 (guarded) into C-set, MFMA on N-set
        {
            const int kp = (tt + 2 < NT) ? ((tt + 2) << 5) : 0;
#pragma unroll
            for (int m = 0; m < MREP; ++m) aC[m] = *(const bf16x8*)(pa[m] + kp);
#pragma unroll
            for (int n = 0; n < NREP; ++n) bC[n] = *(const bf16x8*)(pb[n] + kp);
#pragma unroll
            for (int m = 0; m < MREP; ++m)
#pragma unroll
                for (int n = 0; n < NREP; ++n)
                    acc[m][n] = __builtin_amdgcn_mfma_f32_16x16x32_bf16(
                        aN[m], bN[n], acc[m][n], 0, 0, 0);
        }
    }

    // --- epilogue: C/D map col=lane&15, row=(lane>>4)*4+reg ---
    const int col0 = bn + wc * (BN / 2) + (lane & 15);
    const int row0 = bm + wr * (BM / 2) + ((lane >> 4) << 2);
#pragma unroll
    for (int m = 0; m < MREP; ++m) {
#pragma unroll
        for (int n = 0; n < NREP; ++n) {
            const int cn = col0 + n * 16;
            const float bz = bias[cn];
#pragma unroll
            for (int rg = 0; rg < 4; ++rg) {
                const int gm = row0 + m * 16 + rg;
                float v = acc[m][n][rg] + bz;
                if (mode == 2) v = fmaxf(v + resid[(size_t)gm * ldc + cn], 0.f);
                else if (mode == 3 && cn >= reluStart) v = fmaxf(v, 0.f);
                C[(size_t)gm * ldc + cn] = v;
            }
        }
    }
}

// ---------------------------------------------------------------------------
// atten[r] = sum_d ws[s[r],d] * wo[o[r],d] * phr[r,d] * Www[d]  + Wwb
// ---------------------------------------------------------------------------
__global__ __launch_bounds__(256) void atten_kernel(
    const float* __restrict__ allout, const float* __restrict__ phr,
    const int* __restrict__ rel, const float* __restrict__ Www,
    const float* __restrict__ Wwb, float* __restrict__ atten)
{
    const int r = blockIdx.x;
    const int s = rel[r * 3 + 1], o = rel[r * 3 + 2];
    const int t = threadIdx.x;
    const float4* pws = (const float4*)(allout + (size_t)s * LDO);
    const float4* pwo = (const float4*)(allout + (size_t)o * LDO + 4096);
    const float4* pph = (const float4*)(phr + (size_t)r * D_);
    const float4* pww = (const float4*)Www;
    float sum = 0.f;
    for (int qq = t; qq < D_ / 4; qq += 256) {
        float4 a = pws[qq], b = pwo[qq], c = pph[qq], w = pww[qq];
        sum += a.x * b.x * c.x * w.x + a.y * b.y * c.y * w.y
             + a.z * b.z * c.z * w.z + a.w * b.w * c.w * w.w;
    }
    for (int off = 32; off > 0; off >>= 1) sum += __shfl_down(sum, off);
    __shared__ float red[4];
    if ((t & 63) == 0) red[t >> 6] = sum;
    __syncthreads();
    if (t == 0) atten[r] = red[0] + red[1] + red[2] + red[3] + Wwb[0];
}

// ---------------------------------------------------------------------------
__global__ __launch_bounds__(256) void build_A(
    const int* __restrict__ rel, const float* __restrict__ atten,
    float* __restrict__ Anorm)
{
    const int g = blockIdx.x;
    const int t = threadIdx.x;
    __shared__ float Am[64][64];
    __shared__ float S[64];
    __shared__ int headSh;
    for (int i = t; i < 4096; i += 256) ((float*)Am)[i] = 0.f;
    if (t == 0) headSh = 0x7fffffff;

    int lmin = 0x7fffffff;
    for (int rr = t; rr < RPER; rr += 256) {
        const int base = (g * RPER + rr) * 3;
        lmin = min(lmin, min(rel[base + 1], rel[base + 2]));
    }
    for (int off = 32; off > 0; off >>= 1) lmin = min(lmin, __shfl_down(lmin, off));
    __syncthreads();
    if ((t & 63) == 0) atomicMin(&headSh, lmin);
    __syncthreads();
    const int head = headSh;

    for (int rr = t; rr < RPER; rr += 256) {
        const int base = (g * RPER + rr) * 3;
        atomicAdd(&Am[rel[base + 1] - head][rel[base + 2] - head],
                  atten[g * RPER + rr]);
    }
    __syncthreads();

    for (int idx = t; idx < 4096; idx += 256) {
        const int i = idx >> 6, j = idx & 63;
        float v = 1.f / (1.f + expf(-Am[i][j]));
        if (i == j) v = 0.f;
        Am[i][j] = v;
    }
    __syncthreads();

    if (t < 64) {
        float sum = 0.f;
        for (int k = 0; k < 64; ++k) sum += Am[t][k];
        S[t] = sum;
    }
    __syncthreads();

    float* outg = Anorm + (size_t)g * 4096;
    for (int idx = t; idx < 4096; idx += 256) {
        const int j = idx & 63;
        outg[idx] = ((const float*)Am)[idx] / S[j];
    }
}

// ---------------------------------------------------------------------------
__device__ __forceinline__ void fma4(float4& d, float s, const float4 c) {
    d.x = fmaf(s, c.x, d.x); d.y = fmaf(s, c.y, d.y);
    d.z = fmaf(s, c.z, d.z); d.w = fmaf(s, c.w, d.w);
}
__device__ __forceinline__ void st4bf(__hip_bfloat16* p, float4 v) {
    union { __hip_bfloat16 h[4]; ushort4 u; } cv;
    cv.h[0] = __float2bfloat16(v.x); cv.h[1] = __float2bfloat16(v.y);
    cv.h[2] = __float2bfloat16(v.z); cv.h[3] = __float2bfloat16(v.w);
    *(ushort4*)p = cv.u;
}

__global__ __launch_bounds__(256) void ctx_kernel(
    const float* __restrict__ Anorm, const float* __restrict__ allout,
    __hip_bfloat16* __restrict__ ctx)
{
    const int g = blockIdx.x >> 6;
    const int i = blockIdx.x & 63;
    const int t = threadIdx.x;
    __shared__ float Arow[64], Acol[64];
    if (t < 64) Arow[t] = Anorm[(size_t)g * 4096 + i * 64 + t];
    else if (t < 128) { const int j = t - 64; Acol[j] = Anorm[(size_t)g * 4096 + j * 64 + i]; }
    __syncthreads();

    const float* cg = allout + (size_t)g * NPER * LDO + 8192;
    float4 a0 = {0,0,0,0}, a1 = a0, a2 = a0, a3 = a0;
    for (int j = 0; j < 64; ++j) {
        const float ar = Arow[j], ac = Acol[j];
        float4 c0 = *(const float4*)(cg + (size_t)j * LDO + (t << 2));
        float4 c1 = *(const float4*)(cg + (size_t)j * LDO + 1024 + (t << 2));
        fma4(a0, ar, c0); fma4(a1, ar, c1);
        fma4(a2, ac, c0); fma4(a3, ac, c1);
    }
    __hip_bfloat16* crow = ctx + (size_t)(g * NPER + i) * D_;
    st4bf(crow + (t << 2),        a0);
    st4bf(crow + 1024 + (t << 2), a1);
    st4bf(crow + 2048 + (t << 2), a2);
    st4bf(crow + 3072 + (t << 2), a3);
}

// ---------------------------------------------------------------------------
__global__ __launch_bounds__(256) void ln_relu_kernel(
    const float* __restrict__ h, const float* __restrict__ gamma,
    const float* __restrict__ beta, __hip_bfloat16* __restrict__ hb)
{
    const int row = blockIdx.x;
    const int t = threadIdx.x;
    const float* hr = h + (size_t)row * DT;
    float4 v = *(const float4*)(hr + (t << 2));
    float s  = v.x + v.y + v.z + v.w;
    float ss = v.x * v.x + v.y * v.y + v.z * v.z + v.w * v.w;
    for (int off = 32; off > 0; off >>= 1) {
        s  += __shfl_down(s, off);
        ss += __shfl_down(ss, off);
    }
    __shared__ float rs[4], rss[4];
    if ((t & 63) == 0) { rs[t >> 6] = s; rss[t >> 6] = ss; }
    __syncthreads();
    const float tot  = rs[0] + rs[1] + rs[2] + rs[3];
    const float tot2 = rss[0] + rss[1] + rss[2] + rss[3];
    const float mu   = tot * (1.f / DT);
    const float var  = tot2 * (1.f / DT) - mu * mu;
    const float rstd = rsqrtf(var + 1e-5f);
    float4 g4 = *(const float4*)(gamma + (t << 2));
    float4 b4 = *(const float4*)(beta + (t << 2));
    float4 o;
    o.x = fmaxf(fmaf((v.x - mu) * rstd, g4.x, b4.x), 0.f);
    o.y = fmaxf(fmaf((v.y - mu) * rstd, g4.y, b4.y), 0.f);
    o.z = fmaxf(fmaf((v.z - mu) * rstd, g4.z, b4.z), 0.f);
    o.w = fmaxf(fmaf((v.w - mu) * rstd, g4.w, b4.w), 0.f);
    st4bf(hb + (size_t)row * DT + (t << 2), o);
}

// ---------------------------------------------------------------------------
extern "C" void kernel_launch(void* const* d_in, const int* in_sizes, int n_in,
                              void* d_out, int out_size, void* d_ws, size_t ws_size,
                              hipStream_t stream)
{
    const float* obj   = (const float*)d_in[0];
    const float* phr   = (const float*)d_in[1];
    const int*   rel   = (const int*)d_in[3];
    const float* Ws_w  = (const float*)d_in[5];
    const float* Ws_b  = (const float*)d_in[6];
    const float* Wo_w  = (const float*)d_in[7];
    const float* Wo_b  = (const float*)d_in[8];
    const float* Ww_w  = (const float*)d_in[9];
    const float* Ww_b  = (const float*)d_in[10];
    const float* Wc_w  = (const float*)d_in[11];
    const float* Wc_b  = (const float*)d_in[12];
    const float* Wt1_w = (const float*)d_in[13];
    const float* Wt1_b = (const float*)d_in[14];
    const float* ln_g  = (const float*)d_in[15];
    const float* ln_b  = (const float*)d_in[16];
    const float* Wt2_w = (const float*)d_in[17];
    const float* Wt2_b = (const float*)d_in[18];
    float* out = (float*)d_out;

    float* ws = (float*)d_ws;
    // workspace layout (float units), peak ~134.6 MB:
    __hip_bfloat16* wbuf    = (__hip_bfloat16*)ws;             // Ws|Wo|Wc concat, 41.9M bf16
    __hip_bfloat16* wbuf_t1 = (__hip_bfloat16*)(ws + 33697792);// 4.2M bf16
    __hip_bfloat16* wbuf_t2 = (__hip_bfloat16*)(ws + 35794944);// 4.2M bf16
    __hip_bfloat16* obj_bf  = (__hip_bfloat16*)(ws + 20971520);// 4.2M bf16
    __hip_bfloat16* ctx_bf  = obj_bf;                          // reuse after fused GEMM
    float* allout = ws + 23068672;                             // 1024 x 10240 f32
    float* h_f32  = allout;                                    // reuse after ctx
    __hip_bfloat16* h_bf = (__hip_bfloat16*)(allout + 1048576);
    float* atten  = ws + 33554432;                             // 8192
    float* Anorm  = ws + 33562624;                             // 65536
    float* cbias  = ws + 33628160;                             // 10240

    const dim3 blk(256);

    // 1. one dispatch: cast obj, Ws, Wo, Wc, Wt1, Wt2 -> bf16
    Cast6 c;
    c.src[0] = obj;   c.dst[0] = obj_bf;
    c.src[1] = Ws_w;  c.dst[1] = wbuf;
    c.src[2] = Wo_w;  c.dst[2] = wbuf + 16777216;
    c.src[3] = Wc_w;  c.dst[3] = wbuf + 33554432;
    c.src[4] = Wt1_w; c.dst[4] = wbuf_t1;
    c.src[5] = Wt2_w; c.dst[5] = wbuf_t2;
    c.cum[0] = 2048;   // obj  4.2M
    c.cum[1] = 10240;  // + Ws 16.8M
    c.cum[2] = 18432;  // + Wo 16.8M
    c.cum[3] = 22528;  // + Wc 8.4M
    c.cum[4] = 24576;  // + Wt1 4.2M
    c.cum[5] = 26624;  // + Wt2 4.2M
    cast_multi<<<dim3(26624), blk, 0, stream>>>(c);

    concat_bias<<<dim3(40), blk, 0, stream>>>(Ws_b, Wo_b, Wc_b, cbias);

    // 2. fused ws|wo|conv GEMM: [1024 x 4096] @ [10240 x 4096]^T -> allout
    gemm_nl<128, 128><<<dim3(640), blk, 0, stream>>>(
        (const ushort*)obj_bf, (const ushort*)wbuf, cbias, nullptr,
        allout, NTOT, D_, LDO, 3, 8192);

    // 3. small/fused tail
    atten_kernel<<<dim3(RTOT), blk, 0, stream>>>(allout, phr, rel, Ww_w, Ww_b, atten);
    build_A<<<dim3(NIMG), blk, 0, stream>>>(rel, atten, Anorm);
    ctx_kernel<<<dim3(1024), blk, 0, stream>>>(Anorm, allout, ctx_bf);

    gemm_nl<64, 64><<<dim3(256), blk, 0, stream>>>(
        (const ushort*)ctx_bf, (const ushort*)wbuf_t1, Wt1_b, nullptr,
        h_f32, NTOT, D_, DT, 0, 0);
    ln_relu_kernel<<<dim3(NTOT), blk, 0, stream>>>(h_f32, ln_g, ln_b, h_bf);
    gemm_nl<128, 128><<<dim3(256), blk, 0, stream>>>(
        (const ushort*)h_bf, (const ushort*)wbuf_t2, Wt2_b, obj,
        out, NTOT, DT, D_, 2, 0);
}

// Round 6
// 494.089 us; speedup vs baseline: 1.2270x; 1.2270x over previous
//
#include <hip/hip_runtime.h>
#include <hip/hip_bf16.h>
#include <math.h>

#define D_   4096
#define NIMG 16
#define NPER 64
#define RPER 512
#define NTOT 1024
#define RTOT 8192
#define DC   2048
#define DT   1024
#define LDO  10240   // fused output row stride (4096 ws | 4096 wo | 2048 conv)

typedef __attribute__((ext_vector_type(4))) float f32x4;
typedef __attribute__((ext_vector_type(8))) short bf16x8;

#define GLD16(gp, lp) __builtin_amdgcn_global_load_lds( \
    (const __attribute__((address_space(1))) unsigned int*)(gp), \
    (__attribute__((address_space(3))) unsigned int*)(lp), 16, 0, 0)

template<int N> __device__ __forceinline__ void waitvm() {
    asm volatile("s_waitcnt vmcnt(%0)" :: "n"(N) : "memory");
}

// ---------------------------------------------------------------------------
// cast obj -> bf16 (blocks 0..2047, 2048 elems each) + bias concat (40 blocks)
// ---------------------------------------------------------------------------
__global__ __launch_bounds__(256) void cast_obj_bias(
    const float* __restrict__ obj, __hip_bfloat16* __restrict__ obj_bf,
    const float* __restrict__ b0, const float* __restrict__ b1,
    const float* __restrict__ b2, float* __restrict__ cb)
{
    const int b = blockIdx.x;
    if (b < 2048) {
        const int i = (b * 256 + threadIdx.x) * 8;
        float4 v0 = *(const float4*)(obj + i);
        float4 v1 = *(const float4*)(obj + i + 4);
        union { __hip_bfloat16 h[8]; ushort4 u[2]; } cv;
        cv.h[0] = __float2bfloat16(v0.x); cv.h[1] = __float2bfloat16(v0.y);
        cv.h[2] = __float2bfloat16(v0.z); cv.h[3] = __float2bfloat16(v0.w);
        cv.h[4] = __float2bfloat16(v1.x); cv.h[5] = __float2bfloat16(v1.y);
        cv.h[6] = __float2bfloat16(v1.z); cv.h[7] = __float2bfloat16(v1.w);
        *(ushort4*)(obj_bf + i)     = cv.u[0];
        *(ushort4*)(obj_bf + i + 4) = cv.u[1];
    } else {
        const int i = (b - 2048) * 256 + threadIdx.x;   // 0..10239
        float v;
        if (i < 4096) v = b0[i];
        else if (i < 8192) v = b1[i - 4096];
        else v = b2[i - 8192];
        cb[i] = v;
    }
}

// ---------------------------------------------------------------------------
// Hybrid MFMA GEMM: C = A @ B^T (+bias, act). A bf16, B FP32 (converted
// in-flight), C f32.
// BM x BN tile, 256 thr (2x2 waves, wave tile BM/2 x BN/2), BK=32.
// 3 LDS buffers, 2-deep prefetch. A: global_load_lds (pre-swizzled source,
// linear LDS dest). B: f32 global->VGPR (2 x dwordx4/slot), cvt bf16,
// ds_write_b128 (same swizzled content as A path). Two named B-reg sets
// ping-pong (static indexing). vmcnt counts NA gld_lds + 2*NB reg loads per
// step; wait vmcnt(NA+2NB) retires exactly step t+1's ops. lgkmcnt(0)
// commits ds_writes before each barrier.
// LDS slot s of row r holds global K-quarter (s&3)^(r&3).
// B given as 3 row-blocks (B0|B1|B2 split at ns1/ns2) - avoids weight concat.
// mode: 0 = +bias; 2 = relu(resid + . + bias); 3 = +bias, relu iff col>=reluStart
// ---------------------------------------------------------------------------
template<int BM, int BN>
__global__ __launch_bounds__(256) void gemm_h(
    const ushort* __restrict__ A,
    const float* __restrict__ B0, const float* __restrict__ B1,
    const float* __restrict__ B2, int ns1, int ns2,
    const float* __restrict__ bias, const float* __restrict__ resid,
    float* __restrict__ C, int M, int K, int ldc, int mode, int reluStart)
{
    constexpr int MREP = BM / 32;
    constexpr int NREP = BN / 32;
    constexpr int SA = BM * 4;            // A 16B slots per tile
    constexpr int SB = BN * 4;            // B 16B slots per tile
    constexpr int NA = SA / 256;          // A gld_lds per thread per step
    constexpr int NB = SB / 256;          // B slots per thread per step
    constexpr int INFLIGHT = NA + 2 * NB; // vmem ops per step per thread
    constexpr int BUFE = (SA + SB) * 8;   // ushorts per buffer

    __shared__ ushort lds[3][BUFE];

    const int t = threadIdx.x;
    const int lane = t & 63;
    const int wid = t >> 6;
    const int wr = wid >> 1, wc = wid & 1;

    const int MT = M / BM;
    const int G = gridDim.x;
    const int bid = blockIdx.x;
    const int wgid = (bid & 7) * (G >> 3) + (bid >> 3);   // XCD swizzle (G%8==0)
    const int nt = wgid / MT, mt = wgid % MT;             // same-nt blocks share XCD
    const int bm = mt * BM, bn = nt * BN;

    // --- A staging (gld_lds): thread serves slots {t + i*256} ---
    const ushort* gpa[NA];
    int lofa[NA];
#pragma unroll
    for (int i = 0; i < NA; ++i) {
        const int slot = i * 256 + t;
        const int row = slot >> 2;
        const int q = (slot & 3) ^ (row & 3);             // pre-swizzled source
        gpa[i] = A + (size_t)(bm + row) * K + q * 8;
        lofa[i] = slot * 8;                               // linear LDS dest
    }
    // --- B staging (f32 reg): thread serves B-slots {t + i*256} ---
    const float* gpb[NB];
    int lofb[NB];
#pragma unroll
    for (int i = 0; i < NB; ++i) {
        const int sb = i * 256 + t;
        const int row = sb >> 2;
        const int q = (sb & 3) ^ (row & 3);
        const int gn = bn + row;
        const float* bp = (gn < ns1) ? B0 + (size_t)gn * K
                        : (gn < ns2) ? B1 + (size_t)(gn - ns1) * K
                                     : B2 + (size_t)(gn - ns2) * K;
        gpb[i] = bp + q * 8;
        lofb[i] = (SA + sb) * 8;
    }

    auto stageA = [&](int b, int kpos) {
#pragma unroll
        for (int i = 0; i < NA; ++i) GLD16(gpa[i] + kpos, &lds[b][lofa[i]]);
    };
    auto loadB = [&](f32x4 (&br)[NB][2], int kpos) {
#pragma unroll
        for (int i = 0; i < NB; ++i) {
            br[i][0] = *(const f32x4*)(gpb[i] + kpos);
            br[i][1] = *(const f32x4*)(gpb[i] + kpos + 4);
        }
    };
    auto writeB = [&](f32x4 (&br)[NB][2], int b) {
#pragma unroll
        for (int i = 0; i < NB; ++i) {
            union { __hip_bfloat16 h[8]; uint4 q; } cv;
#pragma unroll
            for (int j = 0; j < 4; ++j) {
                cv.h[j]     = __float2bfloat16(br[i][0][j]);
                cv.h[4 + j] = __float2bfloat16(br[i][1][j]);
            }
            *(uint4*)&lds[b][lofb[i]] = cv.q;
        }
    };

    // --- fragment read offsets (swizzled) ---
    int aoff[MREP], boff[NREP];
    const int sx = (((lane >> 4) ^ (lane & 3))) << 3;
#pragma unroll
    for (int m = 0; m < MREP; ++m)
        aoff[m] = (wr * (BM / 2) + (lane & 15) + m * 16) * 32 + sx;
#pragma unroll
    for (int n = 0; n < NREP; ++n)
        boff[n] = SA * 8 + (wc * (BN / 2) + (lane & 15) + n * 16) * 32 + sx;

    f32x4 acc[MREP][NREP] = {};
    f32x4 br0[NB][2], br1[NB][2];

    const int NT = K >> 5;   // NT even for all shapes used (128, 128, 32)

    // prologue: issue steps 0 and 1; write B(0); open buf0
    stageA(0, 0);  loadB(br0, 0);
    stageA(1, 32); loadB(br1, 32);
    waitvm<INFLIGHT>();                  // A(0),B(0) retired; A(1),B(1) in flight
    writeB(br0, 0);
    asm volatile("s_waitcnt lgkmcnt(0)" ::: "memory");
    __builtin_amdgcn_sched_barrier(0);
    __builtin_amdgcn_s_barrier();
    __builtin_amdgcn_sched_barrier(0);

    auto step = [&](int tt, auto& brW, auto& brL) {
        const bool more = (tt + 2 < NT);
        if (more) {                      // issue step t+2
            stageA((tt + 2) % 3, (tt + 2) << 5);
            loadB(brL, (tt + 2) << 5);
        }
        __builtin_amdgcn_sched_barrier(0);

        const ushort* lb = lds[tt % 3];
        bf16x8 af[MREP], bfv[NREP];
#pragma unroll
        for (int m = 0; m < MREP; ++m) af[m] = *(const bf16x8*)(lb + aoff[m]);
#pragma unroll
        for (int n = 0; n < NREP; ++n) bfv[n] = *(const bf16x8*)(lb + boff[n]);
#pragma unroll
        for (int m = 0; m < MREP; ++m)
#pragma unroll
            for (int n = 0; n < NREP; ++n)
                acc[m][n] = __builtin_amdgcn_mfma_f32_16x16x32_bf16(
                    af[m], bfv[n], acc[m][n], 0, 0, 0);
        __builtin_amdgcn_sched_barrier(0);

        if (tt + 1 < NT) {               // finish buf[t+1]: B-half write
            if (more) waitvm<INFLIGHT>(); else waitvm<0>();
            __builtin_amdgcn_sched_barrier(0);
            writeB(brW, (tt + 1) % 3);
            asm volatile("s_waitcnt lgkmcnt(0)" ::: "memory");
            __builtin_amdgcn_sched_barrier(0);
            __builtin_amdgcn_s_barrier();
            __builtin_amdgcn_sched_barrier(0);
        }
    };

    for (int tt = 0; tt < NT; tt += 2) {
        step(tt,     br1, br0);   // writes B(t+1)=br1, loads B(t+2)->br0
        step(tt + 1, br0, br1);   // writes B(t+2)=br0, loads B(t+3)->br1
    }

    // --- epilogue: C/D map col=lane&15, row=(lane>>4)*4+reg ---
    const int col0 = bn + wc * (BN / 2) + (lane & 15);
    const int row0 = bm + wr * (BM / 2) + ((lane >> 4) << 2);
#pragma unroll
    for (int m = 0; m < MREP; ++m) {
#pragma unroll
        for (int n = 0; n < NREP; ++n) {
            const int cn = col0 + n * 16;
            const float bz = bias[cn];
#pragma unroll
            for (int rg = 0; rg < 4; ++rg) {
                const int gm = row0 + m * 16 + rg;
                float v = acc[m][n][rg] + bz;
                if (mode == 2) v = fmaxf(v + resid[(size_t)gm * ldc + cn], 0.f);
                else if (mode == 3 && cn >= reluStart) v = fmaxf(v, 0.f);
                C[(size_t)gm * ldc + cn] = v;
            }
        }
    }
}

// ---------------------------------------------------------------------------
// atten[r] = sum_d ws[s[r],d] * wo[o[r],d] * phr[r,d] * Www[d]  + Wwb
// ---------------------------------------------------------------------------
__global__ __launch_bounds__(256) void atten_kernel(
    const float* __restrict__ allout, const float* __restrict__ phr,
    const int* __restrict__ rel, const float* __restrict__ Www,
    const float* __restrict__ Wwb, float* __restrict__ atten)
{
    const int r = blockIdx.x;
    const int s = rel[r * 3 + 1], o = rel[r * 3 + 2];
    const int t = threadIdx.x;
    const float4* pws = (const float4*)(allout + (size_t)s * LDO);
    const float4* pwo = (const float4*)(allout + (size_t)o * LDO + 4096);
    const float4* pph = (const float4*)(phr + (size_t)r * D_);
    const float4* pww = (const float4*)Www;
    float sum = 0.f;
    for (int qq = t; qq < D_ / 4; qq += 256) {
        float4 a = pws[qq], b = pwo[qq], c = pph[qq], w = pww[qq];
        sum += a.x * b.x * c.x * w.x + a.y * b.y * c.y * w.y
             + a.z * b.z * c.z * w.z + a.w * b.w * c.w * w.w;
    }
    for (int off = 32; off > 0; off >>= 1) sum += __shfl_down(sum, off);
    __shared__ float red[4];
    if ((t & 63) == 0) red[t >> 6] = sum;
    __syncthreads();
    if (t == 0) atten[r] = red[0] + red[1] + red[2] + red[3] + Wwb[0];
}

// ---------------------------------------------------------------------------
__global__ __launch_bounds__(256) void build_A(
    const int* __restrict__ rel, const float* __restrict__ atten,
    float* __restrict__ Anorm)
{
    const int g = blockIdx.x;
    const int t = threadIdx.x;
    __shared__ float Am[64][64];
    __shared__ float S[64];
    __shared__ int headSh;
    for (int i = t; i < 4096; i += 256) ((float*)Am)[i] = 0.f;
    if (t == 0) headSh = 0x7fffffff;

    int lmin = 0x7fffffff;
    for (int rr = t; rr < RPER; rr += 256) {
        const int base = (g * RPER + rr) * 3;
        lmin = min(lmin, min(rel[base + 1], rel[base + 2]));
    }
    for (int off = 32; off > 0; off >>= 1) lmin = min(lmin, __shfl_down(lmin, off));
    __syncthreads();
    if ((t & 63) == 0) atomicMin(&headSh, lmin);
    __syncthreads();
    const int head = headSh;

    for (int rr = t; rr < RPER; rr += 256) {
        const int base = (g * RPER + rr) * 3;
        atomicAdd(&Am[rel[base + 1] - head][rel[base + 2] - head],
                  atten[g * RPER + rr]);
    }
    __syncthreads();

    for (int idx = t; idx < 4096; idx += 256) {
        const int i = idx >> 6, j = idx & 63;
        float v = 1.f / (1.f + expf(-Am[i][j]));
        if (i == j) v = 0.f;
        Am[i][j] = v;
    }
    __syncthreads();

    if (t < 64) {
        float sum = 0.f;
        for (int k = 0; k < 64; ++k) sum += Am[t][k];
        S[t] = sum;
    }
    __syncthreads();

    float* outg = Anorm + (size_t)g * 4096;
    for (int idx = t; idx < 4096; idx += 256) {
        const int j = idx & 63;
        outg[idx] = ((const float*)Am)[idx] / S[j];
    }
}

// ---------------------------------------------------------------------------
__device__ __forceinline__ void fma4(float4& d, float s, const float4 c) {
    d.x = fmaf(s, c.x, d.x); d.y = fmaf(s, c.y, d.y);
    d.z = fmaf(s, c.z, d.z); d.w = fmaf(s, c.w, d.w);
}
__device__ __forceinline__ void st4bf(__hip_bfloat16* p, float4 v) {
    union { __hip_bfloat16 h[4]; ushort4 u; } cv;
    cv.h[0] = __float2bfloat16(v.x); cv.h[1] = __float2bfloat16(v.y);
    cv.h[2] = __float2bfloat16(v.z); cv.h[3] = __float2bfloat16(v.w);
    *(ushort4*)p = cv.u;
}

__global__ __launch_bounds__(256) void ctx_kernel(
    const float* __restrict__ Anorm, const float* __restrict__ allout,
    __hip_bfloat16* __restrict__ ctx)
{
    const int g = blockIdx.x >> 6;
    const int i = blockIdx.x & 63;
    const int t = threadIdx.x;
    __shared__ float Arow[64], Acol[64];
    if (t < 64) Arow[t] = Anorm[(size_t)g * 4096 + i * 64 + t];
    else if (t < 128) { const int j = t - 64; Acol[j] = Anorm[(size_t)g * 4096 + j * 64 + i]; }
    __syncthreads();

    const float* cg = allout + (size_t)g * NPER * LDO + 8192;
    float4 a0 = {0,0,0,0}, a1 = a0, a2 = a0, a3 = a0;
    for (int j = 0; j < 64; ++j) {
        const float ar = Arow[j], ac = Acol[j];
        float4 c0 = *(const float4*)(cg + (size_t)j * LDO + (t << 2));
        float4 c1 = *(const float4*)(cg + (size_t)j * LDO + 1024 + (t << 2));
        fma4(a0, ar, c0); fma4(a1, ar, c1);
        fma4(a2, ac, c0); fma4(a3, ac, c1);
    }
    __hip_bfloat16* crow = ctx + (size_t)(g * NPER + i) * D_;
    st4bf(crow + (t << 2),        a0);
    st4bf(crow + 1024 + (t << 2), a1);
    st4bf(crow + 2048 + (t << 2), a2);
    st4bf(crow + 3072 + (t << 2), a3);
}

// ---------------------------------------------------------------------------
__global__ __launch_bounds__(256) void ln_relu_kernel(
    const float* __restrict__ h, const float* __restrict__ gamma,
    const float* __restrict__ beta, __hip_bfloat16* __restrict__ hb)
{
    const int row = blockIdx.x;
    const int t = threadIdx.x;
    const float* hr = h + (size_t)row * DT;
    float4 v = *(const float4*)(hr + (t << 2));
    float s  = v.x + v.y + v.z + v.w;
    float ss = v.x * v.x + v.y * v.y + v.z * v.z + v.w * v.w;
    for (int off = 32; off > 0; off >>= 1) {
        s  += __shfl_down(s, off);
        ss += __shfl_down(ss, off);
    }
    __shared__ float rs[4], rss[4];
    if ((t & 63) == 0) { rs[t >> 6] = s; rss[t >> 6] = ss; }
    __syncthreads();
    const float tot  = rs[0] + rs[1] + rs[2] + rs[3];
    const float tot2 = rss[0] + rss[1] + rss[2] + rss[3];
    const float mu   = tot * (1.f / DT);
    const float var  = tot2 * (1.f / DT) - mu * mu;
    const float rstd = rsqrtf(var + 1e-5f);
    float4 g4 = *(const float4*)(gamma + (t << 2));
    float4 b4 = *(const float4*)(beta + (t << 2));
    float4 o;
    o.x = fmaxf(fmaf((v.x - mu) * rstd, g4.x, b4.x), 0.f);
    o.y = fmaxf(fmaf((v.y - mu) * rstd, g4.y, b4.y), 0.f);
    o.z = fmaxf(fmaf((v.z - mu) * rstd, g4.z, b4.z), 0.f);
    o.w = fmaxf(fmaf((v.w - mu) * rstd, g4.w, b4.w), 0.f);
    st4bf(hb + (size_t)row * DT + (t << 2), o);
}

// ---------------------------------------------------------------------------
extern "C" void kernel_launch(void* const* d_in, const int* in_sizes, int n_in,
                              void* d_out, int out_size, void* d_ws, size_t ws_size,
                              hipStream_t stream)
{
    const float* obj   = (const float*)d_in[0];
    const float* phr   = (const float*)d_in[1];
    const int*   rel   = (const int*)d_in[3];
    const float* Ws_w  = (const float*)d_in[5];
    const float* Ws_b  = (const float*)d_in[6];
    const float* Wo_w  = (const float*)d_in[7];
    const float* Wo_b  = (const float*)d_in[8];
    const float* Ww_w  = (const float*)d_in[9];
    const float* Ww_b  = (const float*)d_in[10];
    const float* Wc_w  = (const float*)d_in[11];
    const float* Wc_b  = (const float*)d_in[12];
    const float* Wt1_w = (const float*)d_in[13];
    const float* Wt1_b = (const float*)d_in[14];
    const float* ln_g  = (const float*)d_in[15];
    const float* ln_b  = (const float*)d_in[16];
    const float* Wt2_w = (const float*)d_in[17];
    const float* Wt2_b = (const float*)d_in[18];
    float* out = (float*)d_out;

    float* ws = (float*)d_ws;
    // workspace layout (float units), peak ~51 MB:
    __hip_bfloat16* obj_bf = (__hip_bfloat16*)ws;              // 4.2M bf16
    __hip_bfloat16* ctx_bf = obj_bf;                           // alias (after fused GEMM)
    float* allout = ws + 2097152;                              // 1024 x 10240 f32
    float* h_f32  = allout;                                    // alias (after ctx)
    __hip_bfloat16* h_bf = (__hip_bfloat16*)(allout + 1048576);
    float* atten  = ws + 12582912;                             // 8192
    float* Anorm  = ws + 12591104;                             // 65536
    float* cbias  = ws + 12656640;                             // 10240

    const dim3 blk(256);
    const int BIG = 1 << 30;

    // 1. cast obj -> bf16 + bias concat, one dispatch
    cast_obj_bias<<<dim3(2088), blk, 0, stream>>>(obj, obj_bf, Ws_b, Wo_b, Wc_b, cbias);

    // 2. fused ws|wo|conv GEMM: [1024x4096]bf16 @ ([10240x4096]f32)^T -> allout
    gemm_h<128, 128><<<dim3(640), blk, 0, stream>>>(
        (const ushort*)obj_bf, Ws_w, Wo_w, Wc_w, 4096, 8192,
        cbias, nullptr, allout, NTOT, D_, LDO, 3, 8192);

    // 3. small/fused tail
    atten_kernel<<<dim3(RTOT), blk, 0, stream>>>(allout, phr, rel, Ww_w, Ww_b, atten);
    build_A<<<dim3(NIMG), blk, 0, stream>>>(rel, atten, Anorm);
    ctx_kernel<<<dim3(1024), blk, 0, stream>>>(Anorm, allout, ctx_bf);

    // 4. Wt1 -> LN+relu -> Wt2 (+resid relu)
    gemm_h<64, 64><<<dim3(256), blk, 0, stream>>>(
        (const ushort*)ctx_bf, Wt1_w, Wt1_w, Wt1_w, BIG, BIG,
        Wt1_b, nullptr, h_f32, NTOT, D_, DT, 0, 0);
    ln_relu_kernel<<<dim3(NTOT), blk, 0, stream>>>(h_f32, ln_g, ln_b, h_bf);
    gemm_h<128, 128><<<dim3(256), blk, 0, stream>>>(
        (const ushort*)h_bf, Wt2_w, Wt2_w, Wt2_w, BIG, BIG,
        Wt2_b, obj, out, NTOT, DT, D_, 2, 0);
}

// Round 7
// 377.769 us; speedup vs baseline: 1.6048x; 1.3079x over previous
//
#include <hip/hip_runtime.h>
#include <hip/hip_bf16.h>
#include <math.h>

#define D_   4096
#define NIMG 16
#define NPER 64
#define RPER 512
#define NTOT 1024
#define RTOT 8192
#define DC   2048
#define DT   1024
#define LDO  10240   // fused output row stride (4096 ws | 4096 wo | 2048 conv)

typedef __attribute__((ext_vector_type(4))) float f32x4;
typedef __attribute__((ext_vector_type(8))) short bf16x8;

#define GLD16(gp, lp) __builtin_amdgcn_global_load_lds( \
    (const __attribute__((address_space(1))) unsigned int*)(gp), \
    (__attribute__((address_space(3))) unsigned int*)(lp), 16, 0, 0)

// ---------------------------------------------------------------------------
// multi-region f32 -> bf16 cast. Each block converts 2048 elems.
// ---------------------------------------------------------------------------
struct Cast6 {
    const float* src[6];
    __hip_bfloat16* dst[6];
    int cum[6];
};

__global__ __launch_bounds__(256) void cast_multi(Cast6 a)
{
    const int b = blockIdx.x;
    int r = 0;
#pragma unroll
    for (int i = 0; i < 5; ++i) r += (b >= a.cum[i]) ? 1 : 0;
    const float* s = a.src[r];
    __hip_bfloat16* d = a.dst[r];
    const int rb = r ? b - a.cum[r - 1] : b;
    const int i = (rb * 256 + threadIdx.x) * 8;
    float4 v0 = *(const float4*)(s + i);
    float4 v1 = *(const float4*)(s + i + 4);
    union { __hip_bfloat16 h[8]; ushort4 u[2]; } cv;
    cv.h[0] = __float2bfloat16(v0.x); cv.h[1] = __float2bfloat16(v0.y);
    cv.h[2] = __float2bfloat16(v0.z); cv.h[3] = __float2bfloat16(v0.w);
    cv.h[4] = __float2bfloat16(v1.x); cv.h[5] = __float2bfloat16(v1.y);
    cv.h[6] = __float2bfloat16(v1.z); cv.h[7] = __float2bfloat16(v1.w);
    *(ushort4*)(d + i)     = cv.u[0];
    *(ushort4*)(d + i + 4) = cv.u[1];
}

// ---------------------------------------------------------------------------
__global__ __launch_bounds__(256) void concat_bias(
    const float* __restrict__ b0, const float* __restrict__ b1,
    const float* __restrict__ b2, float* __restrict__ cb)
{
    const int i = blockIdx.x * 256 + threadIdx.x;
    float v;
    if (i < 4096) v = b0[i];
    else if (i < 8192) v = b1[i - 4096];
    else v = b2[i - 8192];
    cb[i] = v;
}

// ---------------------------------------------------------------------------
// Phase-split MFMA GEMM (T3+T4+T5): C = A @ B^T (+bias, act). bf16 in, f32 out.
// 256x256 tile, 512 thr = 8 waves (2M x 4N), wave tile 128x64, BK=32.
// 2 LDS double-buffers (64 KB). Window T (K-tile of 32) = 2 phases:
//   {ds_read subtile; barrier; lgkm; setprio(1) 16 MFMA setprio(0); barrier}
// Tile T+1 is staged (global_load_lds x4/thread) at the top of window T into
// buf (T+1)&1, whose previous readers (tile T-1) finished at window T-1's
// final barrier -> race-free. vmcnt(0) once per window, ~2 phases after the
// loads were issued (near-free). Counted prologue: vmcnt(4) keeps tile 1 in
// flight.
// LDS rows: 32 bf16 = 4 x 16B slots; slot s of local row r holds K-quarter
// s ^ ((r>>1)&3)  -> frag ds_read_b128 is 2-way (free) bank aliased.
// Staging swizzle applied on the GLOBAL source; LDS dest stays linear.
// mode: 0 = +bias(nullable); 2 = relu(resid + . + bias); 3 = +bias, relu iff
// col >= reluStart.  grid.z = K-slices (partials to C + z*zstride).
// ---------------------------------------------------------------------------
__global__ __launch_bounds__(512, 2) void gemm8(
    const ushort* __restrict__ A, const ushort* __restrict__ B,
    const float* __restrict__ bias, const float* __restrict__ resid,
    float* __restrict__ C, int K, int Klen, size_t zstride,
    int ldc, int mode, int reluStart)
{
    __shared__ ushort lds[2][16384];   // 2 x (A 8192 | B 8192) ushorts = 64 KB

    const int t = threadIdx.x;
    const int lane = t & 63;
    const int wid = t >> 6;
    const int wm = wid >> 2, wn = wid & 3;
    const int bn = blockIdx.x * 256, bm = blockIdx.y * 256;
    const int kOff = blockIdx.z * Klen;
    C += (size_t)blockIdx.z * zstride;

    // --- staging: thread serves 16B slots t and t+512 of each of A,B ---
    const int s0 = t, s1 = t + 512;
    const int r0 = s0 >> 2, r1 = s1 >> 2;              // rows 0-127 / 128-255
    const int q0 = (s0 & 3) ^ ((r0 >> 1) & 3);         // pre-swizzled source
    const int q1 = (s1 & 3) ^ ((r1 >> 1) & 3);
    const ushort* gA0 = A + (size_t)(bm + r0) * K + kOff + q0 * 8;
    const ushort* gA1 = A + (size_t)(bm + r1) * K + kOff + q1 * 8;
    const ushort* gB0 = B + (size_t)(bn + r0) * K + kOff + q0 * 8;
    const ushort* gB1 = B + (size_t)(bn + r1) * K + kOff + q1 * 8;
    const int dA0 = s0 * 8, dA1 = s1 * 8;              // linear LDS dests
    const int dB0 = 8192 + s0 * 8, dB1 = 8192 + s1 * 8;

    auto stage = [&](int b, int kpos) {
        GLD16(gA0 + kpos, &lds[b][dA0]);
        GLD16(gA1 + kpos, &lds[b][dA1]);
        GLD16(gB0 + kpos, &lds[b][dB0]);
        GLD16(gB1 + kpos, &lds[b][dB1]);
    };

    // --- fragment read offsets (ushort units, swizzled) ---
    const int sx8 = ((lane >> 4) ^ ((lane >> 1) & 3)) * 8;
    int aoff[8], boff[4];
#pragma unroll
    for (int m = 0; m < 8; ++m)
        aoff[m] = (wm * 128 + m * 16 + (lane & 15)) * 32 + sx8;
#pragma unroll
    for (int n = 0; n < 4; ++n)
        boff[n] = 8192 + (wn * 64 + n * 16 + (lane & 15)) * 32 + sx8;

    f32x4 acc[8][4] = {};
    const int NT = Klen >> 5;   // >= 2 for all shapes used

    stage(0, 0);
    stage(1, 32);
    asm volatile("s_waitcnt vmcnt(4)" ::: "memory");   // tile 0 resident
    __builtin_amdgcn_sched_barrier(0);
    __builtin_amdgcn_s_barrier();
    __builtin_amdgcn_sched_barrier(0);

    for (int T = 0; T < NT; ++T) {
        const ushort* lb = lds[T & 1];
        if (T >= 1 && T + 1 < NT) stage((T + 1) & 1, (T + 1) * 32);
        __builtin_amdgcn_sched_barrier(0);

        bf16x8 av[4], bv[4];
        // ---- phase 0: m 0-3 ----
#pragma unroll
        for (int n = 0; n < 4; ++n) bv[n] = *(const bf16x8*)(lb + boff[n]);
#pragma unroll
        for (int m = 0; m < 4; ++m) av[m] = *(const bf16x8*)(lb + aoff[m]);
        __builtin_amdgcn_sched_barrier(0);
        __builtin_amdgcn_s_barrier();
        __builtin_amdgcn_sched_barrier(0);
        __builtin_amdgcn_s_setprio(1);
#pragma unroll
        for (int m = 0; m < 4; ++m)
#pragma unroll
            for (int n = 0; n < 4; ++n)
                acc[m][n] = __builtin_amdgcn_mfma_f32_16x16x32_bf16(
                    av[m], bv[n], acc[m][n], 0, 0, 0);
        __builtin_amdgcn_s_setprio(0);
        __builtin_amdgcn_sched_barrier(0);
        __builtin_amdgcn_s_barrier();
        __builtin_amdgcn_sched_barrier(0);
        // ---- phase 1: m 4-7 (B frags reused from registers) ----
#pragma unroll
        for (int m = 0; m < 4; ++m) av[m] = *(const bf16x8*)(lb + aoff[4 + m]);
        __builtin_amdgcn_sched_barrier(0);
        __builtin_amdgcn_s_barrier();
        __builtin_amdgcn_sched_barrier(0);
        __builtin_amdgcn_s_setprio(1);
#pragma unroll
        for (int m = 0; m < 4; ++m)
#pragma unroll
            for (int n = 0; n < 4; ++n)
                acc[4 + m][n] = __builtin_amdgcn_mfma_f32_16x16x32_bf16(
                    av[m], bv[n], acc[4 + m][n], 0, 0, 0);
        __builtin_amdgcn_s_setprio(0);
        __builtin_amdgcn_sched_barrier(0);
        // ---- window boundary: next tile must be resident ----
        if (T + 1 < NT) asm volatile("s_waitcnt vmcnt(0)" ::: "memory");
        __builtin_amdgcn_sched_barrier(0);
        __builtin_amdgcn_s_barrier();
        __builtin_amdgcn_sched_barrier(0);
    }

    // --- epilogue: C/D map col=lane&15, row=(lane>>4)*4+reg ---
    const int col0 = bn + wn * 64 + (lane & 15);
    const int row0 = bm + wm * 128 + ((lane >> 4) << 2);
#pragma unroll
    for (int m = 0; m < 8; ++m) {
#pragma unroll
        for (int n = 0; n < 4; ++n) {
            const int cn = col0 + n * 16;
            const float bz = bias ? bias[cn] : 0.f;
#pragma unroll
            for (int rg = 0; rg < 4; ++rg) {
                const int gm = row0 + m * 16 + rg;
                float v = acc[m][n][rg] + bz;
                if (mode == 2) v = fmaxf(v + resid[(size_t)gm * ldc + cn], 0.f);
                else if (mode == 3 && cn >= reluStart) v = fmaxf(v, 0.f);
                C[(size_t)gm * ldc + cn] = v;
            }
        }
    }
}

// ---------------------------------------------------------------------------
// atten[r] = sum_d ws[s[r],d] * wo[o[r],d] * phr[r,d] * Www[d]  + Wwb
// ---------------------------------------------------------------------------
__global__ __launch_bounds__(256) void atten_kernel(
    const float* __restrict__ allout, const float* __restrict__ phr,
    const int* __restrict__ rel, const float* __restrict__ Www,
    const float* __restrict__ Wwb, float* __restrict__ atten)
{
    const int r = blockIdx.x;
    const int s = rel[r * 3 + 1], o = rel[r * 3 + 2];
    const int t = threadIdx.x;
    const float4* pws = (const float4*)(allout + (size_t)s * LDO);
    const float4* pwo = (const float4*)(allout + (size_t)o * LDO + 4096);
    const float4* pph = (const float4*)(phr + (size_t)r * D_);
    const float4* pww = (const float4*)Www;
    float sum = 0.f;
    for (int qq = t; qq < D_ / 4; qq += 256) {
        float4 a = pws[qq], b = pwo[qq], c = pph[qq], w = pww[qq];
        sum += a.x * b.x * c.x * w.x + a.y * b.y * c.y * w.y
             + a.z * b.z * c.z * w.z + a.w * b.w * c.w * w.w;
    }
    for (int off = 32; off > 0; off >>= 1) sum += __shfl_down(sum, off);
    __shared__ float red[4];
    if ((t & 63) == 0) red[t >> 6] = sum;
    __syncthreads();
    if (t == 0) atten[r] = red[0] + red[1] + red[2] + red[3] + Wwb[0];
}

// ---------------------------------------------------------------------------
__global__ __launch_bounds__(256) void build_A(
    const int* __restrict__ rel, const float* __restrict__ atten,
    float* __restrict__ Anorm)
{
    const int g = blockIdx.x;
    const int t = threadIdx.x;
    __shared__ float Am[64][64];
    __shared__ float S[64];
    __shared__ int headSh;
    for (int i = t; i < 4096; i += 256) ((float*)Am)[i] = 0.f;
    if (t == 0) headSh = 0x7fffffff;

    int lmin = 0x7fffffff;
    for (int rr = t; rr < RPER; rr += 256) {
        const int base = (g * RPER + rr) * 3;
        lmin = min(lmin, min(rel[base + 1], rel[base + 2]));
    }
    for (int off = 32; off > 0; off >>= 1) lmin = min(lmin, __shfl_down(lmin, off));
    __syncthreads();
    if ((t & 63) == 0) atomicMin(&headSh, lmin);
    __syncthreads();
    const int head = headSh;

    for (int rr = t; rr < RPER; rr += 256) {
        const int base = (g * RPER + rr) * 3;
        atomicAdd(&Am[rel[base + 1] - head][rel[base + 2] - head],
                  atten[g * RPER + rr]);
    }
    __syncthreads();

    for (int idx = t; idx < 4096; idx += 256) {
        const int i = idx >> 6, j = idx & 63;
        float v = 1.f / (1.f + expf(-Am[i][j]));
        if (i == j) v = 0.f;
        Am[i][j] = v;
    }
    __syncthreads();

    if (t < 64) {
        float sum = 0.f;
        for (int k = 0; k < 64; ++k) sum += Am[t][k];
        S[t] = sum;
    }
    __syncthreads();

    float* outg = Anorm + (size_t)g * 4096;
    for (int idx = t; idx < 4096; idx += 256) {
        const int j = idx & 63;
        outg[idx] = ((const float*)Am)[idx] / S[j];
    }
}

// ---------------------------------------------------------------------------
__device__ __forceinline__ void fma4(float4& d, float s, const float4 c) {
    d.x = fmaf(s, c.x, d.x); d.y = fmaf(s, c.y, d.y);
    d.z = fmaf(s, c.z, d.z); d.w = fmaf(s, c.w, d.w);
}
__device__ __forceinline__ void st4bf(__hip_bfloat16* p, float4 v) {
    union { __hip_bfloat16 h[4]; ushort4 u; } cv;
    cv.h[0] = __float2bfloat16(v.x); cv.h[1] = __float2bfloat16(v.y);
    cv.h[2] = __float2bfloat16(v.z); cv.h[3] = __float2bfloat16(v.w);
    *(ushort4*)p = cv.u;
}

__global__ __launch_bounds__(256) void ctx_kernel(
    const float* __restrict__ Anorm, const float* __restrict__ allout,
    __hip_bfloat16* __restrict__ ctx)
{
    const int g = blockIdx.x >> 6;
    const int i = blockIdx.x & 63;
    const int t = threadIdx.x;
    __shared__ float Arow[64], Acol[64];
    if (t < 64) Arow[t] = Anorm[(size_t)g * 4096 + i * 64 + t];
    else if (t < 128) { const int j = t - 64; Acol[j] = Anorm[(size_t)g * 4096 + j * 64 + i]; }
    __syncthreads();

    const float* cg = allout + (size_t)g * NPER * LDO + 8192;
    float4 a0 = {0,0,0,0}, a1 = a0, a2 = a0, a3 = a0;
    for (int j = 0; j < 64; ++j) {
        const float ar = Arow[j], ac = Acol[j];
        float4 c0 = *(const float4*)(cg + (size_t)j * LDO + (t << 2));
        float4 c1 = *(const float4*)(cg + (size_t)j * LDO + 1024 + (t << 2));
        fma4(a0, ar, c0); fma4(a1, ar, c1);
        fma4(a2, ac, c0); fma4(a3, ac, c1);
    }
    __hip_bfloat16* crow = ctx + (size_t)(g * NPER + i) * D_;
    st4bf(crow + (t << 2),        a0);
    st4bf(crow + 1024 + (t << 2), a1);
    st4bf(crow + 2048 + (t << 2), a2);
    st4bf(crow + 3072 + (t << 2), a3);
}

// ---------------------------------------------------------------------------
// sum 4 K-slice partials + Wt1 bias -> LayerNorm(1024) + affine + relu -> bf16
// ---------------------------------------------------------------------------
__global__ __launch_bounds__(256) void ln_merge4(
    const float* __restrict__ hp, size_t zstr, const float* __restrict__ w1b,
    const float* __restrict__ gamma, const float* __restrict__ beta,
    __hip_bfloat16* __restrict__ hb)
{
    const int row = blockIdx.x;
    const int t = threadIdx.x;
    const size_t base = (size_t)row * DT + (t << 2);
    float4 v  = *(const float4*)(hp + base);
    float4 v1 = *(const float4*)(hp + zstr + base);
    float4 v2 = *(const float4*)(hp + 2 * zstr + base);
    float4 v3 = *(const float4*)(hp + 3 * zstr + base);
    float4 b0 = *(const float4*)(w1b + (t << 2));
    v.x += v1.x + v2.x + v3.x + b0.x;
    v.y += v1.y + v2.y + v3.y + b0.y;
    v.z += v1.z + v2.z + v3.z + b0.z;
    v.w += v1.w + v2.w + v3.w + b0.w;

    float s  = v.x + v.y + v.z + v.w;
    float ss = v.x * v.x + v.y * v.y + v.z * v.z + v.w * v.w;
    for (int off = 32; off > 0; off >>= 1) {
        s  += __shfl_down(s, off);
        ss += __shfl_down(ss, off);
    }
    __shared__ float rs[4], rss[4];
    if ((t & 63) == 0) { rs[t >> 6] = s; rss[t >> 6] = ss; }
    __syncthreads();
    const float tot  = rs[0] + rs[1] + rs[2] + rs[3];
    const float tot2 = rss[0] + rss[1] + rss[2] + rss[3];
    const float mu   = tot * (1.f / DT);
    const float var  = tot2 * (1.f / DT) - mu * mu;
    const float rstd = rsqrtf(var + 1e-5f);
    float4 g4 = *(const float4*)(gamma + (t << 2));
    float4 b4 = *(const float4*)(beta + (t << 2));
    float4 o;
    o.x = fmaxf(fmaf((v.x - mu) * rstd, g4.x, b4.x), 0.f);
    o.y = fmaxf(fmaf((v.y - mu) * rstd, g4.y, b4.y), 0.f);
    o.z = fmaxf(fmaf((v.z - mu) * rstd, g4.z, b4.z), 0.f);
    o.w = fmaxf(fmaf((v.w - mu) * rstd, g4.w, b4.w), 0.f);
    st4bf(hb + (size_t)row * DT + (t << 2), o);
}

// ---------------------------------------------------------------------------
extern "C" void kernel_launch(void* const* d_in, const int* in_sizes, int n_in,
                              void* d_out, int out_size, void* d_ws, size_t ws_size,
                              hipStream_t stream)
{
    const float* obj   = (const float*)d_in[0];
    const float* phr   = (const float*)d_in[1];
    const int*   rel   = (const int*)d_in[3];
    const float* Ws_w  = (const float*)d_in[5];
    const float* Ws_b  = (const float*)d_in[6];
    const float* Wo_w  = (const float*)d_in[7];
    const float* Wo_b  = (const float*)d_in[8];
    const float* Ww_w  = (const float*)d_in[9];
    const float* Ww_b  = (const float*)d_in[10];
    const float* Wc_w  = (const float*)d_in[11];
    const float* Wc_b  = (const float*)d_in[12];
    const float* Wt1_w = (const float*)d_in[13];
    const float* Wt1_b = (const float*)d_in[14];
    const float* ln_g  = (const float*)d_in[15];
    const float* ln_b  = (const float*)d_in[16];
    const float* Wt2_w = (const float*)d_in[17];
    const float* Wt2_b = (const float*)d_in[18];
    float* out = (float*)d_out;

    float* ws = (float*)d_ws;
    // workspace layout (float units), peak ~134.6 MB (same as round 4):
    __hip_bfloat16* wbuf    = (__hip_bfloat16*)ws;             // Ws|Wo|Wc, 41.9M bf16
    __hip_bfloat16* wbuf_t1 = wbuf;                            // reuse after fused GEMM
    __hip_bfloat16* wbuf_t2 = wbuf + 4194304;
    __hip_bfloat16* obj_bf  = (__hip_bfloat16*)(ws + 20971520);// 4.2M bf16
    __hip_bfloat16* ctx_bf  = obj_bf;                          // reuse after fused GEMM
    float* allout = ws + 23068672;                             // 1024 x 10240 f32
    float* h_part = allout;                                    // 4 x 1M f32 (after ctx)
    __hip_bfloat16* h_bf = (__hip_bfloat16*)(allout + 4194304);
    float* atten  = ws + 33554432;                             // 8192
    float* Anorm  = ws + 33562624;                             // 65536
    float* cbias  = ws + 33628160;                             // 10240

    const dim3 blk(256);
    const dim3 blk512(512);

    // 1. cast obj + Ws + Wo + Wc -> bf16
    Cast6 c1;
    c1.src[0] = obj;  c1.dst[0] = obj_bf;
    c1.src[1] = Ws_w; c1.dst[1] = wbuf;
    c1.src[2] = Wo_w; c1.dst[2] = wbuf + 16777216;
    c1.src[3] = Wc_w; c1.dst[3] = wbuf + 33554432;
    c1.src[4] = obj;  c1.dst[4] = obj_bf;   // unreachable
    c1.src[5] = obj;  c1.dst[5] = obj_bf;   // unreachable
    c1.cum[0] = 2048; c1.cum[1] = 10240; c1.cum[2] = 18432;
    c1.cum[3] = 22528; c1.cum[4] = 22528; c1.cum[5] = 22528;
    cast_multi<<<dim3(22528), blk, 0, stream>>>(c1);

    concat_bias<<<dim3(40), blk, 0, stream>>>(Ws_b, Wo_b, Wc_b, cbias);

    // 2. fused ws|wo|conv GEMM: [1024x4096] @ [10240x4096]^T -> allout
    gemm8<<<dim3(40, 4, 1), blk512, 0, stream>>>(
        (const ushort*)obj_bf, (const ushort*)wbuf, cbias, nullptr,
        allout, D_, D_, 0, LDO, 3, 8192);

    // 3. cast Wt1 + Wt2 into region freed by fused GEMM
    Cast6 c2;
    c2.src[0] = Wt1_w; c2.dst[0] = wbuf_t1;
    c2.src[1] = Wt2_w; c2.dst[1] = wbuf_t2;
    c2.src[2] = Wt1_w; c2.dst[2] = wbuf_t1;   // unreachable
    c2.src[3] = Wt1_w; c2.dst[3] = wbuf_t1;
    c2.src[4] = Wt1_w; c2.dst[4] = wbuf_t1;
    c2.src[5] = Wt1_w; c2.dst[5] = wbuf_t1;
    c2.cum[0] = 2048; c2.cum[1] = 4096; c2.cum[2] = 4096;
    c2.cum[3] = 4096; c2.cum[4] = 4096; c2.cum[5] = 4096;
    cast_multi<<<dim3(4096), blk, 0, stream>>>(c2);

    // 4. small/fused tail
    atten_kernel<<<dim3(RTOT), blk, 0, stream>>>(allout, phr, rel, Ww_w, Ww_b, atten);
    build_A<<<dim3(NIMG), blk, 0, stream>>>(rel, atten, Anorm);
    ctx_kernel<<<dim3(1024), blk, 0, stream>>>(Anorm, allout, ctx_bf);

    // 5. Wt1 with K-split x4 (grid.z), partials -> h_part (no bias)
    gemm8<<<dim3(4, 4, 4), blk512, 0, stream>>>(
        (const ushort*)ctx_bf, (const ushort*)wbuf_t1, nullptr, nullptr,
        h_part, D_, DT, (size_t)1048576, DT, 0, 0);

    // 6. merge partials + bias + LN + relu -> bf16
    ln_merge4<<<dim3(NTOT), blk, 0, stream>>>(
        h_part, (size_t)1048576, Wt1_b, ln_g, ln_b, h_bf);

    // 7. Wt2 + residual relu -> out
    gemm8<<<dim3(16, 4, 1), blk512, 0, stream>>>(
        (const ushort*)h_bf, (const ushort*)wbuf_t2, Wt2_b, obj,
        out, DT, DT, 0, D_, 2, 0);
}

// Round 8
// 357.210 us; speedup vs baseline: 1.6971x; 1.0576x over previous
//
#include <hip/hip_runtime.h>
#include <hip/hip_bf16.h>
#include <math.h>

#define D_   4096
#define NIMG 16
#define NPER 64
#define RPER 512
#define NTOT 1024
#define RTOT 8192
#define DC   2048
#define DT   1024
#define LDO  10240   // fused output row stride (4096 ws | 4096 wo | 2048 conv)

typedef __attribute__((ext_vector_type(4))) float f32x4;
typedef __attribute__((ext_vector_type(8))) short bf16x8;

#define GLD16(gp, lp) __builtin_amdgcn_global_load_lds( \
    (const __attribute__((address_space(1))) unsigned int*)(gp), \
    (__attribute__((address_space(3))) unsigned int*)(lp), 16, 0, 0)

template<int N> __device__ __forceinline__ void waitvm() {
    asm volatile("s_waitcnt vmcnt(%0)" :: "n"(N) : "memory");
}

// ---------------------------------------------------------------------------
// cast obj -> bf16 (blocks 0..2047) + bias concat (40 blocks). One dispatch.
// ---------------------------------------------------------------------------
__global__ __launch_bounds__(256) void cast_obj_bias(
    const float* __restrict__ obj, __hip_bfloat16* __restrict__ obj_bf,
    const float* __restrict__ b0, const float* __restrict__ b1,
    const float* __restrict__ b2, float* __restrict__ cb)
{
    const int b = blockIdx.x;
    if (b < 2048) {
        const int i = (b * 256 + threadIdx.x) * 8;
        float4 v0 = *(const float4*)(obj + i);
        float4 v1 = *(const float4*)(obj + i + 4);
        union { __hip_bfloat16 h[8]; ushort4 u[2]; } cv;
        cv.h[0] = __float2bfloat16(v0.x); cv.h[1] = __float2bfloat16(v0.y);
        cv.h[2] = __float2bfloat16(v0.z); cv.h[3] = __float2bfloat16(v0.w);
        cv.h[4] = __float2bfloat16(v1.x); cv.h[5] = __float2bfloat16(v1.y);
        cv.h[6] = __float2bfloat16(v1.z); cv.h[7] = __float2bfloat16(v1.w);
        *(ushort4*)(obj_bf + i)     = cv.u[0];
        *(ushort4*)(obj_bf + i + 4) = cv.u[1];
    } else {
        const int i = (b - 2048) * 256 + threadIdx.x;   // 0..10239
        float v;
        if (i < 4096) v = b0[i];
        else if (i < 8192) v = b1[i - 4096];
        else v = b2[i - 8192];
        cb[i] = v;
    }
}

// ---------------------------------------------------------------------------
// MFMA GEMM, C = A @ B^T (+bias, act). A bf16, B FP32 read directly (no cast
// pass). BM x BN tile, 256 thr (2x2 waves, wave tile BM/2 x BN/2), BK=32.
// 3 LDS buffers, 2-deep prefetch, counted vmcnt (round-4 proven schedule).
// A staged bf16 via global_load_lds (source pre-swizzled q=(s&3)^(row&3),
// LDS linear). B staged f32 via global_load_lds: row = 128 B = 8 x 16B slots,
// physical slot p holds logical slot p^(row&7) -> frag ds_read_b128 lands
// <=2-way bank aliased (free). Frag B: 2 x ds_read_b128 f32 + compiler cvt
// to bf16 (no reg staging, no ds_write -> round-6 failure mode avoided).
// B picked per block from 3 row-regions (no weight concat); BN divides 4096.
// mode: 0=+bias; 2=relu(resid+.+bias); 3=+bias, relu iff col>=reluStart
// ---------------------------------------------------------------------------
template<int BM, int BN>
__global__ __launch_bounds__(256) void gemm_f(
    const ushort* __restrict__ A,
    const float* __restrict__ B0, const float* __restrict__ B1,
    const float* __restrict__ B2, int ns1, int ns2,
    const float* __restrict__ bias, const float* __restrict__ resid,
    float* __restrict__ C, int M, int K, int ldc, int mode, int reluStart)
{
    constexpr int MREP = BM / 32;
    constexpr int NREP = BN / 32;
    constexpr int ABYTES = BM * 64;        // 32 bf16/row
    constexpr int BBYTES = BN * 128;       // 32 f32/row
    constexpr int NPA = BM * 4 / 256;      // A 16B slots per thread
    constexpr int NPB = BN * 8 / 256;      // B 16B slots per thread
    constexpr int INFLIGHT = NPA + NPB;    // one stage's vmem ops per thread

    __shared__ __align__(16) char lds[3][ABYTES + BBYTES];

    const int t = threadIdx.x;
    const int lane = t & 63;
    const int wid = t >> 6;
    const int wr = wid >> 1, wc = wid & 1;

    const int MT = M / BM;
    const int G = gridDim.x;
    const int bid = blockIdx.x;
    const int wgid = (bid & 7) * (G >> 3) + (bid >> 3);   // XCD swizzle (G%8==0)
    const int nt = wgid / MT, mt = wgid % MT;             // same-nt blocks share XCD
    const int bm = mt * BM, bn = nt * BN;

    // --- B matrix select (one region per block; BN | 4096) ---
    const float* Bp; int bnl;
    if (bn < ns1)      { Bp = B0; bnl = bn; }
    else if (bn < ns2) { Bp = B1; bnl = bn - ns1; }
    else               { Bp = B2; bnl = bn - ns2; }

    // --- staging precompute ---
    const ushort* gA[NPA]; int lofA[NPA];
#pragma unroll
    for (int i = 0; i < NPA; ++i) {
        const int s = i * 256 + t;
        const int row = s >> 2;
        const int q = (s & 3) ^ (row & 3);
        gA[i] = A + (size_t)(bm + row) * K + q * 8;
        lofA[i] = s * 16;
    }
    const float* gB[NPB]; int lofB[NPB];
#pragma unroll
    for (int i = 0; i < NPB; ++i) {
        const int s = i * 256 + t;
        const int row = s >> 3;
        const int lq = (s & 7) ^ (row & 7);               // pre-swizzled source
        gB[i] = Bp + (size_t)(bnl + row) * K + lq * 4;
        lofB[i] = ABYTES + s * 16;                        // linear LDS dest
    }

    auto stage = [&](int b, int T) {
#pragma unroll
        for (int i = 0; i < NPA; ++i) GLD16(gA[i] + T * 32, &lds[b][lofA[i]]);
#pragma unroll
        for (int i = 0; i < NPB; ++i) GLD16(gB[i] + T * 32, &lds[b][lofB[i]]);
    };

    // --- fragment read offsets (bytes) ---
    int aoff[MREP], b0off[NREP], b1off[NREP];
    const int axs = ((lane >> 4) ^ (lane & 3)) * 16;
#pragma unroll
    for (int m = 0; m < MREP; ++m)
        aoff[m] = (wr * (BM / 2) + m * 16 + (lane & 15)) * 64 + axs;
    const int c2 = (lane >> 4) * 2;
#pragma unroll
    for (int n = 0; n < NREP; ++n) {
        const int row = wc * (BN / 2) + n * 16 + (lane & 15);
        b0off[n] = ABYTES + row * 128 + ((c2    ) ^ (lane & 7)) * 16;
        b1off[n] = ABYTES + row * 128 + ((c2 + 1) ^ (lane & 7)) * 16;
    }

    f32x4 acc[MREP][NREP] = {};

    const int NT = K >> 5;   // >= 2 for all shapes used
    stage(0, 0);
    stage(1, 1);
    waitvm<INFLIGHT>();                  // tile 0 resident; tile 1 in flight
    __builtin_amdgcn_sched_barrier(0);
    __builtin_amdgcn_s_barrier();
    __builtin_amdgcn_sched_barrier(0);

    for (int tt = 0; tt < NT; ++tt) {
        const bool pf = (tt + 2 < NT);
        if (pf) stage((tt + 2) % 3, tt + 2);
        __builtin_amdgcn_sched_barrier(0);

        const char* lb = lds[tt % 3];
        bf16x8 af[MREP], bv[NREP];
#pragma unroll
        for (int m = 0; m < MREP; ++m) af[m] = *(const bf16x8*)(lb + aoff[m]);
#pragma unroll
        for (int n = 0; n < NREP; ++n) {
            f32x4 f0 = *(const f32x4*)(lb + b0off[n]);
            f32x4 f1 = *(const f32x4*)(lb + b1off[n]);
            union { __hip_bfloat16 h[8]; bf16x8 v; } cv;
#pragma unroll
            for (int j = 0; j < 4; ++j) {
                cv.h[j]     = __float2bfloat16(f0[j]);
                cv.h[4 + j] = __float2bfloat16(f1[j]);
            }
            bv[n] = cv.v;
        }
#pragma unroll
        for (int m = 0; m < MREP; ++m)
#pragma unroll
            for (int n = 0; n < NREP; ++n)
                acc[m][n] = __builtin_amdgcn_mfma_f32_16x16x32_bf16(
                    af[m], bv[n], acc[m][n], 0, 0, 0);

        __builtin_amdgcn_sched_barrier(0);
        if (pf) waitvm<INFLIGHT>(); else waitvm<0>();
        __builtin_amdgcn_sched_barrier(0);
        __builtin_amdgcn_s_barrier();
        __builtin_amdgcn_sched_barrier(0);
    }

    // --- epilogue: C/D map col=lane&15, row=(lane>>4)*4+reg ---
    const int col0 = bn + wc * (BN / 2) + (lane & 15);
    const int row0 = bm + wr * (BM / 2) + ((lane >> 4) << 2);
#pragma unroll
    for (int m = 0; m < MREP; ++m) {
#pragma unroll
        for (int n = 0; n < NREP; ++n) {
            const int cn = col0 + n * 16;
            const float bz = bias[cn];
#pragma unroll
            for (int rg = 0; rg < 4; ++rg) {
                const int gm = row0 + m * 16 + rg;
                float v = acc[m][n][rg] + bz;
                if (mode == 2) v = fmaxf(v + resid[(size_t)gm * ldc + cn], 0.f);
                else if (mode == 3 && cn >= reluStart) v = fmaxf(v, 0.f);
                C[(size_t)gm * ldc + cn] = v;
            }
        }
    }
}

// ---------------------------------------------------------------------------
// atten[r] = sum_d ws[s[r],d] * wo[o[r],d] * phr[r,d] * Www[d]  + Wwb
// ---------------------------------------------------------------------------
__global__ __launch_bounds__(256) void atten_kernel(
    const float* __restrict__ allout, const float* __restrict__ phr,
    const int* __restrict__ rel, const float* __restrict__ Www,
    const float* __restrict__ Wwb, float* __restrict__ atten)
{
    const int r = blockIdx.x;
    const int s = rel[r * 3 + 1], o = rel[r * 3 + 2];
    const int t = threadIdx.x;
    const float4* pws = (const float4*)(allout + (size_t)s * LDO);
    const float4* pwo = (const float4*)(allout + (size_t)o * LDO + 4096);
    const float4* pph = (const float4*)(phr + (size_t)r * D_);
    const float4* pww = (const float4*)Www;
    float sum = 0.f;
    for (int qq = t; qq < D_ / 4; qq += 256) {
        float4 a = pws[qq], b = pwo[qq], c = pph[qq], w = pww[qq];
        sum += a.x * b.x * c.x * w.x + a.y * b.y * c.y * w.y
             + a.z * b.z * c.z * w.z + a.w * b.w * c.w * w.w;
    }
    for (int off = 32; off > 0; off >>= 1) sum += __shfl_down(sum, off);
    __shared__ float red[4];
    if ((t & 63) == 0) red[t >> 6] = sum;
    __syncthreads();
    if (t == 0) atten[r] = red[0] + red[1] + red[2] + red[3] + Wwb[0];
}

// ---------------------------------------------------------------------------
__global__ __launch_bounds__(256) void build_A(
    const int* __restrict__ rel, const float* __restrict__ atten,
    float* __restrict__ Anorm)
{
    const int g = blockIdx.x;
    const int t = threadIdx.x;
    __shared__ float Am[64][64];
    __shared__ float S[64];
    __shared__ int headSh;
    for (int i = t; i < 4096; i += 256) ((float*)Am)[i] = 0.f;
    if (t == 0) headSh = 0x7fffffff;

    int lmin = 0x7fffffff;
    for (int rr = t; rr < RPER; rr += 256) {
        const int base = (g * RPER + rr) * 3;
        lmin = min(lmin, min(rel[base + 1], rel[base + 2]));
    }
    for (int off = 32; off > 0; off >>= 1) lmin = min(lmin, __shfl_down(lmin, off));
    __syncthreads();
    if ((t & 63) == 0) atomicMin(&headSh, lmin);
    __syncthreads();
    const int head = headSh;

    for (int rr = t; rr < RPER; rr += 256) {
        const int base = (g * RPER + rr) * 3;
        atomicAdd(&Am[rel[base + 1] - head][rel[base + 2] - head],
                  atten[g * RPER + rr]);
    }
    __syncthreads();

    for (int idx = t; idx < 4096; idx += 256) {
        const int i = idx >> 6, j = idx & 63;
        float v = 1.f / (1.f + expf(-Am[i][j]));
        if (i == j) v = 0.f;
        Am[i][j] = v;
    }
    __syncthreads();

    if (t < 64) {
        float sum = 0.f;
        for (int k = 0; k < 64; ++k) sum += Am[t][k];
        S[t] = sum;
    }
    __syncthreads();

    float* outg = Anorm + (size_t)g * 4096;
    for (int idx = t; idx < 4096; idx += 256) {
        const int j = idx & 63;
        outg[idx] = ((const float*)Am)[idx] / S[j];
    }
}

// ---------------------------------------------------------------------------
__device__ __forceinline__ void fma4(float4& d, float s, const float4 c) {
    d.x = fmaf(s, c.x, d.x); d.y = fmaf(s, c.y, d.y);
    d.z = fmaf(s, c.z, d.z); d.w = fmaf(s, c.w, d.w);
}
__device__ __forceinline__ void st4bf(__hip_bfloat16* p, float4 v) {
    union { __hip_bfloat16 h[4]; ushort4 u; } cv;
    cv.h[0] = __float2bfloat16(v.x); cv.h[1] = __float2bfloat16(v.y);
    cv.h[2] = __float2bfloat16(v.z); cv.h[3] = __float2bfloat16(v.w);
    *(ushort4*)p = cv.u;
}

__global__ __launch_bounds__(256) void ctx_kernel(
    const float* __restrict__ Anorm, const float* __restrict__ allout,
    __hip_bfloat16* __restrict__ ctx)
{
    const int g = blockIdx.x >> 6;
    const int i = blockIdx.x & 63;
    const int t = threadIdx.x;
    __shared__ float Arow[64], Acol[64];
    if (t < 64) Arow[t] = Anorm[(size_t)g * 4096 + i * 64 + t];
    else if (t < 128) { const int j = t - 64; Acol[j] = Anorm[(size_t)g * 4096 + j * 64 + i]; }
    __syncthreads();

    const float* cg = allout + (size_t)g * NPER * LDO + 8192;
    float4 a0 = {0,0,0,0}, a1 = a0, a2 = a0, a3 = a0;
    for (int j = 0; j < 64; ++j) {
        const float ar = Arow[j], ac = Acol[j];
        float4 c0 = *(const float4*)(cg + (size_t)j * LDO + (t << 2));
        float4 c1 = *(const float4*)(cg + (size_t)j * LDO + 1024 + (t << 2));
        fma4(a0, ar, c0); fma4(a1, ar, c1);
        fma4(a2, ac, c0); fma4(a3, ac, c1);
    }
    __hip_bfloat16* crow = ctx + (size_t)(g * NPER + i) * D_;
    st4bf(crow + (t << 2),        a0);
    st4bf(crow + 1024 + (t << 2), a1);
    st4bf(crow + 2048 + (t << 2), a2);
    st4bf(crow + 3072 + (t << 2), a3);
}

// ---------------------------------------------------------------------------
__global__ __launch_bounds__(256) void ln_relu_kernel(
    const float* __restrict__ h, const float* __restrict__ gamma,
    const float* __restrict__ beta, __hip_bfloat16* __restrict__ hb)
{
    const int row = blockIdx.x;
    const int t = threadIdx.x;
    const float* hr = h + (size_t)row * DT;
    float4 v = *(const float4*)(hr + (t << 2));
    float s  = v.x + v.y + v.z + v.w;
    float ss = v.x * v.x + v.y * v.y + v.z * v.z + v.w * v.w;
    for (int off = 32; off > 0; off >>= 1) {
        s  += __shfl_down(s, off);
        ss += __shfl_down(ss, off);
    }
    __shared__ float rs[4], rss[4];
    if ((t & 63) == 0) { rs[t >> 6] = s; rss[t >> 6] = ss; }
    __syncthreads();
    const float tot  = rs[0] + rs[1] + rs[2] + rs[3];
    const float tot2 = rss[0] + rss[1] + rss[2] + rss[3];
    const float mu   = tot * (1.f / DT);
    const float var  = tot2 * (1.f / DT) - mu * mu;
    const float rstd = rsqrtf(var + 1e-5f);
    float4 g4 = *(const float4*)(gamma + (t << 2));
    float4 b4 = *(const float4*)(beta + (t << 2));
    float4 o;
    o.x = fmaxf(fmaf((v.x - mu) * rstd, g4.x, b4.x), 0.f);
    o.y = fmaxf(fmaf((v.y - mu) * rstd, g4.y, b4.y), 0.f);
    o.z = fmaxf(fmaf((v.z - mu) * rstd, g4.z, b4.z), 0.f);
    o.w = fmaxf(fmaf((v.w - mu) * rstd, g4.w, b4.w), 0.f);
    st4bf(hb + (size_t)row * DT + (t << 2), o);
}

// ---------------------------------------------------------------------------
extern "C" void kernel_launch(void* const* d_in, const int* in_sizes, int n_in,
                              void* d_out, int out_size, void* d_ws, size_t ws_size,
                              hipStream_t stream)
{
    const float* obj   = (const float*)d_in[0];
    const float* phr   = (const float*)d_in[1];
    const int*   rel   = (const int*)d_in[3];
    const float* Ws_w  = (const float*)d_in[5];
    const float* Ws_b  = (const float*)d_in[6];
    const float* Wo_w  = (const float*)d_in[7];
    const float* Wo_b  = (const float*)d_in[8];
    const float* Ww_w  = (const float*)d_in[9];
    const float* Ww_b  = (const float*)d_in[10];
    const float* Wc_w  = (const float*)d_in[11];
    const float* Wc_b  = (const float*)d_in[12];
    const float* Wt1_w = (const float*)d_in[13];
    const float* Wt1_b = (const float*)d_in[14];
    const float* ln_g  = (const float*)d_in[15];
    const float* ln_b  = (const float*)d_in[16];
    const float* Wt2_w = (const float*)d_in[17];
    const float* Wt2_b = (const float*)d_in[18];
    float* out = (float*)d_out;

    float* ws = (float*)d_ws;
    // workspace layout (float units), peak ~51 MB:
    __hip_bfloat16* obj_bf = (__hip_bfloat16*)ws;              // 4.2M bf16
    __hip_bfloat16* ctx_bf = obj_bf;                           // alias (after fused GEMM)
    float* allout = ws + 2097152;                              // 1024 x 10240 f32
    float* h_f32  = allout;                                    // alias (after ctx)
    __hip_bfloat16* h_bf = (__hip_bfloat16*)(allout + 1048576);
    float* atten  = ws + 12582912;                             // 8192
    float* Anorm  = ws + 12591104;                             // 65536
    float* cbias  = ws + 12656640;                             // 10240

    const dim3 blk(256);
    const int BIG = 1 << 30;

    // 1. cast obj -> bf16 + bias concat, one dispatch (weights NOT cast)
    cast_obj_bias<<<dim3(2088), blk, 0, stream>>>(obj, obj_bf, Ws_b, Wo_b, Wc_b, cbias);

    // 2. fused ws|wo|conv GEMM: [1024x4096]bf16 @ ([10240x4096]f32)^T -> allout
    gemm_f<128, 128><<<dim3(640), blk, 0, stream>>>(
        (const ushort*)obj_bf, Ws_w, Wo_w, Wc_w, 4096, 8192,
        cbias, nullptr, allout, NTOT, D_, LDO, 3, 8192);

    // 3. small/fused tail
    atten_kernel<<<dim3(RTOT), blk, 0, stream>>>(allout, phr, rel, Ww_w, Ww_b, atten);
    build_A<<<dim3(NIMG), blk, 0, stream>>>(rel, atten, Anorm);
    ctx_kernel<<<dim3(1024), blk, 0, stream>>>(Anorm, allout, ctx_bf);

    // 4. Wt1 (f32 weights direct) -> LN+relu -> Wt2 (+resid relu)
    gemm_f<64, 64><<<dim3(256), blk, 0, stream>>>(
        (const ushort*)ctx_bf, Wt1_w, Wt1_w, Wt1_w, BIG, BIG,
        Wt1_b, nullptr, h_f32, NTOT, D_, DT, 0, 0);
    ln_relu_kernel<<<dim3(NTOT), blk, 0, stream>>>(h_f32, ln_g, ln_b, h_bf);
    gemm_f<128, 128><<<dim3(256), blk, 0, stream>>>(
        (const ushort*)h_bf, Wt2_w, Wt2_w, Wt2_w, BIG, BIG,
        Wt2_b, obj, out, NTOT, DT, D_, 2, 0);
}

// Round 9
// 331.565 us; speedup vs baseline: 1.8284x; 1.0773x over previous
//
#include <hip/hip_runtime.h>
#include <hip/hip_bf16.h>
#include <math.h>

#define D_   4096
#define NIMG 16
#define NPER 64
#define RPER 512
#define NTOT 1024
#define RTOT 8192
#define DC   2048
#define DT   1024
#define LDO  10240   // fused output row stride (4096 ws | 4096 wo | 2048 conv)

typedef __attribute__((ext_vector_type(4))) float f32x4;
typedef __attribute__((ext_vector_type(8))) short bf16x8;

#define GLD16(gp, lp) __builtin_amdgcn_global_load_lds( \
    (const __attribute__((address_space(1))) unsigned int*)(gp), \
    (__attribute__((address_space(3))) unsigned int*)(lp), 16, 0, 0)

template<int N> __device__ __forceinline__ void waitvm() {
    asm volatile("s_waitcnt vmcnt(%0)" :: "n"(N) : "memory");
}

// ---------------------------------------------------------------------------
// One dispatch: cast obj + Ws + Wo + Wc -> bf16 (2048 elems/block) and
// concat biases (last 40 blocks).
// ---------------------------------------------------------------------------
__global__ __launch_bounds__(256) void cast_all(
    const float* __restrict__ obj, __hip_bfloat16* __restrict__ obj_bf,
    const float* __restrict__ Ws, const float* __restrict__ Wo,
    const float* __restrict__ Wc, __hip_bfloat16* __restrict__ wbuf,
    const float* __restrict__ b0, const float* __restrict__ b1,
    const float* __restrict__ b2, float* __restrict__ cb)
{
    const int b = blockIdx.x;
    if (b < 22528) {
        const float* s; __hip_bfloat16* d; int rb;
        if (b < 2048)       { s = obj; d = obj_bf;          rb = b; }
        else if (b < 10240) { s = Ws;  d = wbuf;            rb = b - 2048; }
        else if (b < 18432) { s = Wo;  d = wbuf + 16777216; rb = b - 10240; }
        else                { s = Wc;  d = wbuf + 33554432; rb = b - 18432; }
        const int i = (rb * 256 + threadIdx.x) * 8;
        float4 v0 = *(const float4*)(s + i);
        float4 v1 = *(const float4*)(s + i + 4);
        union { __hip_bfloat16 h[8]; ushort4 u[2]; } cv;
        cv.h[0] = __float2bfloat16(v0.x); cv.h[1] = __float2bfloat16(v0.y);
        cv.h[2] = __float2bfloat16(v0.z); cv.h[3] = __float2bfloat16(v0.w);
        cv.h[4] = __float2bfloat16(v1.x); cv.h[5] = __float2bfloat16(v1.y);
        cv.h[6] = __float2bfloat16(v1.z); cv.h[7] = __float2bfloat16(v1.w);
        *(ushort4*)(d + i)     = cv.u[0];
        *(ushort4*)(d + i + 4) = cv.u[1];
    } else {
        const int i = (b - 22528) * 256 + threadIdx.x;   // 0..10239
        float v;
        if (i < 4096) v = b0[i];
        else if (i < 8192) v = b1[i - 4096];
        else v = b2[i - 8192];
        cb[i] = v;
    }
}

// ---------------------------------------------------------------------------
// MFMA GEMM, C = A @ B^T (+bias, act). bf16 in, f32 out. (round-4 schedule)
// BM x BN tile, 256 thr (2x2 waves, wave tile BM/2 x BN/2), BK=32.
// 3 LDS buffers, 2-deep prefetch over counted vmcnt + raw s_barrier.
// SWIZZLE FIX vs round 4: physical 16B slot p of LDS row r holds K-quarter
// p ^ ((r>>1)&3)  (was (r&3)) -> frag ds_read_b128 bank pattern matches
// gemm8's measured-zero-conflict layout (round-4's (r&3) gave 4-way, 1.05e7).
// Staging swizzle on the GLOBAL source; LDS dest linear (gld_lds constraint).
// mode: 0 = +bias; 2 = relu(resid + . + bias); 3 = +bias, relu iff col>=reluStart
// ---------------------------------------------------------------------------
template<int BM, int BN>
__global__ __launch_bounds__(256) void gemm_p2(
    const ushort* __restrict__ A, const ushort* __restrict__ B,
    const float* __restrict__ bias, const float* __restrict__ resid,
    float* __restrict__ C, int M, int K, int ldc, int mode, int reluStart)
{
    constexpr int MREP = BM / 32;
    constexpr int NREP = BN / 32;
    constexpr int SLOTS = (BM + BN) * 4;      // 16B slots per tile-pair
    constexpr int NPW = SLOTS / 256;          // gld_lds per thread per stage
    constexpr int BUFE = SLOTS * 8;           // ushorts per buffer

    __shared__ ushort lds[3][BUFE];

    const int t = threadIdx.x;
    const int lane = t & 63;
    const int wid = t >> 6;
    const int wr = wid >> 1, wc = wid & 1;

    const int MT = M / BM;
    const int G = gridDim.x;
    const int bid = blockIdx.x;
    const int wgid = (bid & 7) * (G >> 3) + (bid >> 3);   // XCD swizzle (G%8==0)
    const int nt = wgid / MT, mt = wgid % MT;
    const int bm = mt * BM, bn = nt * BN;

    // --- staging: thread t serves 16B slots {t + i*256} ---
    const ushort* gp[NPW];
    int loff[NPW];
#pragma unroll
    for (int i = 0; i < NPW; ++i) {
        const int slot = i * 256 + t;
        const bool isA = slot < BM * 4;
        const int s2 = isA ? slot : slot - BM * 4;
        const int row = s2 >> 2;
        const int q = (s2 & 3) ^ ((row >> 1) & 3);        // pre-swizzled source
        gp[i] = (isA ? A + (size_t)(bm + row) * K : B + (size_t)(bn + row) * K) + q * 8;
        loff[i] = slot * 8;                               // linear LDS dest
    }

    auto stage = [&](int b, int kpos) {
#pragma unroll
        for (int i = 0; i < NPW; ++i) GLD16(gp[i] + kpos, &lds[b][loff[i]]);
    };

    // --- fragment read offsets (swizzled; (row>>1)&3 == (lane>>1)&3) ---
    int aoff[MREP], boff[NREP];
    const int sx = (((lane >> 4) ^ ((lane >> 1) & 3))) << 3;
#pragma unroll
    for (int m = 0; m < MREP; ++m)
        aoff[m] = (wr * (BM / 2) + (lane & 15) + m * 16) * 32 + sx;
#pragma unroll
    for (int n = 0; n < NREP; ++n)
        boff[n] = BM * 32 + (wc * (BN / 2) + (lane & 15) + n * 16) * 32 + sx;

    f32x4 acc[MREP][NREP] = {};

    const int NT = K >> 5;   // NT >= 2 required (K >= 64)
    stage(0, 0);
    stage(1, 32);
    if constexpr (NPW == 2) waitvm<2>();
    else if constexpr (NPW == 3) waitvm<3>();
    else waitvm<4>();
    __builtin_amdgcn_sched_barrier(0);
    __builtin_amdgcn_s_barrier();
    __builtin_amdgcn_sched_barrier(0);

    for (int tt = 0; tt < NT; ++tt) {
        const bool pf = (tt + 2 < NT);
        if (pf) stage((tt + 2) % 3, (tt + 2) << 5);
        __builtin_amdgcn_sched_barrier(0);

        const ushort* lb = lds[tt % 3];
        bf16x8 af[MREP], bfv[NREP];
#pragma unroll
        for (int m = 0; m < MREP; ++m) af[m] = *(const bf16x8*)(lb + aoff[m]);
#pragma unroll
        for (int n = 0; n < NREP; ++n) bfv[n] = *(const bf16x8*)(lb + boff[n]);
#pragma unroll
        for (int m = 0; m < MREP; ++m)
#pragma unroll
            for (int n = 0; n < NREP; ++n)
                acc[m][n] = __builtin_amdgcn_mfma_f32_16x16x32_bf16(
                    af[m], bfv[n], acc[m][n], 0, 0, 0);

        __builtin_amdgcn_sched_barrier(0);
        if (pf) {
            if constexpr (NPW == 2) waitvm<2>();
            else if constexpr (NPW == 3) waitvm<3>();
            else waitvm<4>();
        } else {
            waitvm<0>();
        }
        __builtin_amdgcn_sched_barrier(0);
        __builtin_amdgcn_s_barrier();
        __builtin_amdgcn_sched_barrier(0);
    }

    // --- epilogue: C/D map col=lane&15, row=(lane>>4)*4+reg ---
    const int col0 = bn + wc * (BN / 2) + (lane & 15);
    const int row0 = bm + wr * (BM / 2) + ((lane >> 4) << 2);
#pragma unroll
    for (int m = 0; m < MREP; ++m) {
#pragma unroll
        for (int n = 0; n < NREP; ++n) {
            const int cn = col0 + n * 16;
            const float bz = bias[cn];
#pragma unroll
            for (int rg = 0; rg < 4; ++rg) {
                const int gm = row0 + m * 16 + rg;
                float v = acc[m][n][rg] + bz;
                if (mode == 2) v = fmaxf(v + resid[(size_t)gm * ldc + cn], 0.f);
                else if (mode == 3 && cn >= reluStart) v = fmaxf(v, 0.f);
                C[(size_t)gm * ldc + cn] = v;
            }
        }
    }
}

// ---------------------------------------------------------------------------
// MFMA GEMM with B read as FP32 directly (no cast pass) — round-8 version,
// byte-identical (used only for wt1/wt2 where it measured well).
// ---------------------------------------------------------------------------
template<int BM, int BN>
__global__ __launch_bounds__(256) void gemm_f(
    const ushort* __restrict__ A,
    const float* __restrict__ B0, const float* __restrict__ B1,
    const float* __restrict__ B2, int ns1, int ns2,
    const float* __restrict__ bias, const float* __restrict__ resid,
    float* __restrict__ C, int M, int K, int ldc, int mode, int reluStart)
{
    constexpr int MREP = BM / 32;
    constexpr int NREP = BN / 32;
    constexpr int ABYTES = BM * 64;
    constexpr int BBYTES = BN * 128;
    constexpr int NPA = BM * 4 / 256;
    constexpr int NPB = BN * 8 / 256;
    constexpr int INFLIGHT = NPA + NPB;

    __shared__ __align__(16) char lds[3][ABYTES + BBYTES];

    const int t = threadIdx.x;
    const int lane = t & 63;
    const int wid = t >> 6;
    const int wr = wid >> 1, wc = wid & 1;

    const int MT = M / BM;
    const int G = gridDim.x;
    const int bid = blockIdx.x;
    const int wgid = (bid & 7) * (G >> 3) + (bid >> 3);
    const int nt = wgid / MT, mt = wgid % MT;
    const int bm = mt * BM, bn = nt * BN;

    const float* Bp; int bnl;
    if (bn < ns1)      { Bp = B0; bnl = bn; }
    else if (bn < ns2) { Bp = B1; bnl = bn - ns1; }
    else               { Bp = B2; bnl = bn - ns2; }

    const ushort* gA[NPA]; int lofA[NPA];
#pragma unroll
    for (int i = 0; i < NPA; ++i) {
        const int s = i * 256 + t;
        const int row = s >> 2;
        const int q = (s & 3) ^ (row & 3);
        gA[i] = A + (size_t)(bm + row) * K + q * 8;
        lofA[i] = s * 16;
    }
    const float* gB[NPB]; int lofB[NPB];
#pragma unroll
    for (int i = 0; i < NPB; ++i) {
        const int s = i * 256 + t;
        const int row = s >> 3;
        const int lq = (s & 7) ^ (row & 7);
        gB[i] = Bp + (size_t)(bnl + row) * K + lq * 4;
        lofB[i] = ABYTES + s * 16;
    }

    auto stage = [&](int b, int T) {
#pragma unroll
        for (int i = 0; i < NPA; ++i) GLD16(gA[i] + T * 32, &lds[b][lofA[i]]);
#pragma unroll
        for (int i = 0; i < NPB; ++i) GLD16(gB[i] + T * 32, &lds[b][lofB[i]]);
    };

    int aoff[MREP], b0off[NREP], b1off[NREP];
    const int axs = ((lane >> 4) ^ (lane & 3)) * 16;
#pragma unroll
    for (int m = 0; m < MREP; ++m)
        aoff[m] = (wr * (BM / 2) + m * 16 + (lane & 15)) * 64 + axs;
    const int c2 = (lane >> 4) * 2;
#pragma unroll
    for (int n = 0; n < NREP; ++n) {
        const int row = wc * (BN / 2) + n * 16 + (lane & 15);
        b0off[n] = ABYTES + row * 128 + ((c2    ) ^ (lane & 7)) * 16;
        b1off[n] = ABYTES + row * 128 + ((c2 + 1) ^ (lane & 7)) * 16;
    }

    f32x4 acc[MREP][NREP] = {};

    const int NT = K >> 5;
    stage(0, 0);
    stage(1, 1);
    waitvm<INFLIGHT>();
    __builtin_amdgcn_sched_barrier(0);
    __builtin_amdgcn_s_barrier();
    __builtin_amdgcn_sched_barrier(0);

    for (int tt = 0; tt < NT; ++tt) {
        const bool pf = (tt + 2 < NT);
        if (pf) stage((tt + 2) % 3, tt + 2);
        __builtin_amdgcn_sched_barrier(0);

        const char* lb = lds[tt % 3];
        bf16x8 af[MREP], bv[NREP];
#pragma unroll
        for (int m = 0; m < MREP; ++m) af[m] = *(const bf16x8*)(lb + aoff[m]);
#pragma unroll
        for (int n = 0; n < NREP; ++n) {
            f32x4 f0 = *(const f32x4*)(lb + b0off[n]);
            f32x4 f1 = *(const f32x4*)(lb + b1off[n]);
            union { __hip_bfloat16 h[8]; bf16x8 v; } cv;
#pragma unroll
            for (int j = 0; j < 4; ++j) {
                cv.h[j]     = __float2bfloat16(f0[j]);
                cv.h[4 + j] = __float2bfloat16(f1[j]);
            }
            bv[n] = cv.v;
        }
#pragma unroll
        for (int m = 0; m < MREP; ++m)
#pragma unroll
            for (int n = 0; n < NREP; ++n)
                acc[m][n] = __builtin_amdgcn_mfma_f32_16x16x32_bf16(
                    af[m], bv[n], acc[m][n], 0, 0, 0);

        __builtin_amdgcn_sched_barrier(0);
        if (pf) waitvm<INFLIGHT>(); else waitvm<0>();
        __builtin_amdgcn_sched_barrier(0);
        __builtin_amdgcn_s_barrier();
        __builtin_amdgcn_sched_barrier(0);
    }

    const int col0 = bn + wc * (BN / 2) + (lane & 15);
    const int row0 = bm + wr * (BM / 2) + ((lane >> 4) << 2);
#pragma unroll
    for (int m = 0; m < MREP; ++m) {
#pragma unroll
        for (int n = 0; n < NREP; ++n) {
            const int cn = col0 + n * 16;
            const float bz = bias[cn];
#pragma unroll
            for (int rg = 0; rg < 4; ++rg) {
                const int gm = row0 + m * 16 + rg;
                float v = acc[m][n][rg] + bz;
                if (mode == 2) v = fmaxf(v + resid[(size_t)gm * ldc + cn], 0.f);
                else if (mode == 3 && cn >= reluStart) v = fmaxf(v, 0.f);
                C[(size_t)gm * ldc + cn] = v;
            }
        }
    }
}

// ---------------------------------------------------------------------------
// atten[r] = sum_d ws[s[r],d] * wo[o[r],d] * phr[r,d] * Www[d]  + Wwb
// ---------------------------------------------------------------------------
__global__ __launch_bounds__(256) void atten_kernel(
    const float* __restrict__ allout, const float* __restrict__ phr,
    const int* __restrict__ rel, const float* __restrict__ Www,
    const float* __restrict__ Wwb, float* __restrict__ atten)
{
    const int r = blockIdx.x;
    const int s = rel[r * 3 + 1], o = rel[r * 3 + 2];
    const int t = threadIdx.x;
    const float4* pws = (const float4*)(allout + (size_t)s * LDO);
    const float4* pwo = (const float4*)(allout + (size_t)o * LDO + 4096);
    const float4* pph = (const float4*)(phr + (size_t)r * D_);
    const float4* pww = (const float4*)Www;
    float sum = 0.f;
    for (int qq = t; qq < D_ / 4; qq += 256) {
        float4 a = pws[qq], b = pwo[qq], c = pph[qq], w = pww[qq];
        sum += a.x * b.x * c.x * w.x + a.y * b.y * c.y * w.y
             + a.z * b.z * c.z * w.z + a.w * b.w * c.w * w.w;
    }
    for (int off = 32; off > 0; off >>= 1) sum += __shfl_down(sum, off);
    __shared__ float red[4];
    if ((t & 63) == 0) red[t >> 6] = sum;
    __syncthreads();
    if (t == 0) atten[r] = red[0] + red[1] + red[2] + red[3] + Wwb[0];
}

// ---------------------------------------------------------------------------
__global__ __launch_bounds__(256) void build_A(
    const int* __restrict__ rel, const float* __restrict__ atten,
    float* __restrict__ Anorm)
{
    const int g = blockIdx.x;
    const int t = threadIdx.x;
    __shared__ float Am[64][64];
    __shared__ float S[64];
    __shared__ int headSh;
    for (int i = t; i < 4096; i += 256) ((float*)Am)[i] = 0.f;
    if (t == 0) headSh = 0x7fffffff;

    int lmin = 0x7fffffff;
    for (int rr = t; rr < RPER; rr += 256) {
        const int base = (g * RPER + rr) * 3;
        lmin = min(lmin, min(rel[base + 1], rel[base + 2]));
    }
    for (int off = 32; off > 0; off >>= 1) lmin = min(lmin, __shfl_down(lmin, off));
    __syncthreads();
    if ((t & 63) == 0) atomicMin(&headSh, lmin);
    __syncthreads();
    const int head = headSh;

    for (int rr = t; rr < RPER; rr += 256) {
        const int base = (g * RPER + rr) * 3;
        atomicAdd(&Am[rel[base + 1] - head][rel[base + 2] - head],
                  atten[g * RPER + rr]);
    }
    __syncthreads();

    for (int idx = t; idx < 4096; idx += 256) {
        const int i = idx >> 6, j = idx & 63;
        float v = 1.f / (1.f + expf(-Am[i][j]));
        if (i == j) v = 0.f;
        Am[i][j] = v;
    }
    __syncthreads();

    if (t < 64) {
        float sum = 0.f;
        for (int k = 0; k < 64; ++k) sum += Am[t][k];
        S[t] = sum;
    }
    __syncthreads();

    float* outg = Anorm + (size_t)g * 4096;
    for (int idx = t; idx < 4096; idx += 256) {
        const int j = idx & 63;
        outg[idx] = ((const float*)Am)[idx] / S[j];
    }
}

// ---------------------------------------------------------------------------
__device__ __forceinline__ void fma4(float4& d, float s, const float4 c) {
    d.x = fmaf(s, c.x, d.x); d.y = fmaf(s, c.y, d.y);
    d.z = fmaf(s, c.z, d.z); d.w = fmaf(s, c.w, d.w);
}
__device__ __forceinline__ void st4bf(__hip_bfloat16* p, float4 v) {
    union { __hip_bfloat16 h[4]; ushort4 u; } cv;
    cv.h[0] = __float2bfloat16(v.x); cv.h[1] = __float2bfloat16(v.y);
    cv.h[2] = __float2bfloat16(v.z); cv.h[3] = __float2bfloat16(v.w);
    *(ushort4*)p = cv.u;
}

__global__ __launch_bounds__(256) void ctx_kernel(
    const float* __restrict__ Anorm, const float* __restrict__ allout,
    __hip_bfloat16* __restrict__ ctx)
{
    const int g = blockIdx.x >> 6;
    const int i = blockIdx.x & 63;
    const int t = threadIdx.x;
    __shared__ float Arow[64], Acol[64];
    if (t < 64) Arow[t] = Anorm[(size_t)g * 4096 + i * 64 + t];
    else if (t < 128) { const int j = t - 64; Acol[j] = Anorm[(size_t)g * 4096 + j * 64 + i]; }
    __syncthreads();

    const float* cg = allout + (size_t)g * NPER * LDO + 8192;
    float4 a0 = {0,0,0,0}, a1 = a0, a2 = a0, a3 = a0;
    for (int j = 0; j < 64; ++j) {
        const float ar = Arow[j], ac = Acol[j];
        float4 c0 = *(const float4*)(cg + (size_t)j * LDO + (t << 2));
        float4 c1 = *(const float4*)(cg + (size_t)j * LDO + 1024 + (t << 2));
        fma4(a0, ar, c0); fma4(a1, ar, c1);
        fma4(a2, ac, c0); fma4(a3, ac, c1);
    }
    __hip_bfloat16* crow = ctx + (size_t)(g * NPER + i) * D_;
    st4bf(crow + (t << 2),        a0);
    st4bf(crow + 1024 + (t << 2), a1);
    st4bf(crow + 2048 + (t << 2), a2);
    st4bf(crow + 3072 + (t << 2), a3);
}

// ---------------------------------------------------------------------------
__global__ __launch_bounds__(256) void ln_relu_kernel(
    const float* __restrict__ h, const float* __restrict__ gamma,
    const float* __restrict__ beta, __hip_bfloat16* __restrict__ hb)
{
    const int row = blockIdx.x;
    const int t = threadIdx.x;
    const float* hr = h + (size_t)row * DT;
    float4 v = *(const float4*)(hr + (t << 2));
    float s  = v.x + v.y + v.z + v.w;
    float ss = v.x * v.x + v.y * v.y + v.z * v.z + v.w * v.w;
    for (int off = 32; off > 0; off >>= 1) {
        s  += __shfl_down(s, off);
        ss += __shfl_down(ss, off);
    }
    __shared__ float rs[4], rss[4];
    if ((t & 63) == 0) { rs[t >> 6] = s; rss[t >> 6] = ss; }
    __syncthreads();
    const float tot  = rs[0] + rs[1] + rs[2] + rs[3];
    const float tot2 = rss[0] + rss[1] + rss[2] + rss[3];
    const float mu   = tot * (1.f / DT);
    const float var  = tot2 * (1.f / DT) - mu * mu;
    const float rstd = rsqrtf(var + 1e-5f);
    float4 g4 = *(const float4*)(gamma + (t << 2));
    float4 b4 = *(const float4*)(beta + (t << 2));
    float4 o;
    o.x = fmaxf(fmaf((v.x - mu) * rstd, g4.x, b4.x), 0.f);
    o.y = fmaxf(fmaf((v.y - mu) * rstd, g4.y, b4.y), 0.f);
    o.z = fmaxf(fmaf((v.z - mu) * rstd, g4.z, b4.z), 0.f);
    o.w = fmaxf(fmaf((v.w - mu) * rstd, g4.w, b4.w), 0.f);
    st4bf(hb + (size_t)row * DT + (t << 2), o);
}

// ---------------------------------------------------------------------------
extern "C" void kernel_launch(void* const* d_in, const int* in_sizes, int n_in,
                              void* d_out, int out_size, void* d_ws, size_t ws_size,
                              hipStream_t stream)
{
    const float* obj   = (const float*)d_in[0];
    const float* phr   = (const float*)d_in[1];
    const int*   rel   = (const int*)d_in[3];
    const float* Ws_w  = (const float*)d_in[5];
    const float* Ws_b  = (const float*)d_in[6];
    const float* Wo_w  = (const float*)d_in[7];
    const float* Wo_b  = (const float*)d_in[8];
    const float* Ww_w  = (const float*)d_in[9];
    const float* Ww_b  = (const float*)d_in[10];
    const float* Wc_w  = (const float*)d_in[11];
    const float* Wc_b  = (const float*)d_in[12];
    const float* Wt1_w = (const float*)d_in[13];
    const float* Wt1_b = (const float*)d_in[14];
    const float* ln_g  = (const float*)d_in[15];
    const float* ln_b  = (const float*)d_in[16];
    const float* Wt2_w = (const float*)d_in[17];
    const float* Wt2_b = (const float*)d_in[18];
    float* out = (float*)d_out;

    float* ws = (float*)d_ws;
    // workspace layout (float units), peak ~134.6 MB (round-4 proven):
    __hip_bfloat16* wbuf   = (__hip_bfloat16*)ws;              // Ws|Wo|Wc, 41.9M bf16
    __hip_bfloat16* obj_bf = (__hip_bfloat16*)(ws + 20971520); // 4.2M bf16
    __hip_bfloat16* ctx_bf = obj_bf;                           // alias (after fused GEMM)
    float* allout = ws + 23068672;                             // 1024 x 10240 f32
    float* h_f32  = allout;                                    // alias (ws/wo dead after atten)
    __hip_bfloat16* h_bf = (__hip_bfloat16*)(allout + 1048576);
    float* atten  = ws + 33554432;                             // 8192
    float* Anorm  = ws + 33562624;                             // 65536
    float* cbias  = ws + 33628160;                             // 10240

    const dim3 blk(256);
    const int BIG = 1 << 30;

    // 1. one dispatch: cast obj + Ws + Wo + Wc -> bf16, concat biases
    cast_all<<<dim3(22568), blk, 0, stream>>>(
        obj, obj_bf, Ws_w, Wo_w, Wc_w, wbuf, Ws_b, Wo_b, Wc_b, cbias);

    // 2. fused ws|wo|conv GEMM: [1024x4096] @ [10240x4096]^T -> allout
    gemm_p2<128, 128><<<dim3(640), blk, 0, stream>>>(
        (const ushort*)obj_bf, (const ushort*)wbuf, cbias, nullptr,
        allout, NTOT, D_, LDO, 3, 8192);

    // 3. small/fused tail
    atten_kernel<<<dim3(RTOT), blk, 0, stream>>>(allout, phr, rel, Ww_w, Ww_b, atten);
    build_A<<<dim3(NIMG), blk, 0, stream>>>(rel, atten, Anorm);
    ctx_kernel<<<dim3(1024), blk, 0, stream>>>(Anorm, allout, ctx_bf);

    // 4. Wt1 (f32 weights direct) -> LN+relu -> Wt2 (f32 direct, +resid relu)
    gemm_f<64, 64><<<dim3(256), blk, 0, stream>>>(
        (const ushort*)ctx_bf, Wt1_w, Wt1_w, Wt1_w, BIG, BIG,
        Wt1_b, nullptr, h_f32, NTOT, D_, DT, 0, 0);
    ln_relu_kernel<<<dim3(NTOT), blk, 0, stream>>>(h_f32, ln_g, ln_b, h_bf);
    gemm_f<128, 128><<<dim3(256), blk, 0, stream>>>(
        (const ushort*)h_bf, Wt2_w, Wt2_w, Wt2_w, BIG, BIG,
        Wt2_b, obj, out, NTOT, DT, D_, 2, 0);
}

// Round 10
// 318.011 us; speedup vs baseline: 1.9063x; 1.0426x over previous
//
#include <hip/hip_runtime.h>
#include <hip/hip_bf16.h>
#include <math.h>

#define D_   4096
#define NIMG 16
#define NPER 64
#define RPER 512
#define NTOT 1024
#define RTOT 8192
#define DC   2048
#define DT   1024
#define LDA  8192    // allout row stride (4096 ws | 4096 wo)

typedef __attribute__((ext_vector_type(4))) float f32x4;
typedef __attribute__((ext_vector_type(8))) short bf16x8;

#define GLD16(gp, lp) __builtin_amdgcn_global_load_lds( \
    (const __attribute__((address_space(1))) unsigned int*)(gp), \
    (__attribute__((address_space(3))) unsigned int*)(lp), 16, 0, 0)

template<int N> __device__ __forceinline__ void waitvm() {
    asm volatile("s_waitcnt vmcnt(%0)" :: "n"(N) : "memory");
}

__device__ __forceinline__ void fma4(float4& d, float s, const float4 c) {
    d.x = fmaf(s, c.x, d.x); d.y = fmaf(s, c.y, d.y);
    d.z = fmaf(s, c.z, d.z); d.w = fmaf(s, c.w, d.w);
}
__device__ __forceinline__ void st4bf(__hip_bfloat16* p, float4 v) {
    union { __hip_bfloat16 h[4]; ushort4 u; } cv;
    cv.h[0] = __float2bfloat16(v.x); cv.h[1] = __float2bfloat16(v.y);
    cv.h[2] = __float2bfloat16(v.z); cv.h[3] = __float2bfloat16(v.w);
    *(ushort4*)p = cv.u;
}

// ---------------------------------------------------------------------------
// One dispatch: cast obj + Ws + Wo + Wc -> bf16 (2048 elems/block) + bias
// concat (last 40 blocks).
// ---------------------------------------------------------------------------
__global__ __launch_bounds__(256) void cast_all(
    const float* __restrict__ obj, __hip_bfloat16* __restrict__ obj_bf,
    const float* __restrict__ Ws, const float* __restrict__ Wo,
    const float* __restrict__ Wc, __hip_bfloat16* __restrict__ wbuf,
    const float* __restrict__ b0, const float* __restrict__ b1,
    const float* __restrict__ b2, float* __restrict__ cb)
{
    const int b = blockIdx.x;
    if (b < 22528) {
        const float* s; __hip_bfloat16* d; int rb;
        if (b < 2048)       { s = obj; d = obj_bf;          rb = b; }
        else if (b < 10240) { s = Ws;  d = wbuf;            rb = b - 2048; }
        else if (b < 18432) { s = Wo;  d = wbuf + 16777216; rb = b - 10240; }
        else                { s = Wc;  d = wbuf + 33554432; rb = b - 18432; }
        const int i = (rb * 256 + threadIdx.x) * 8;
        float4 v0 = *(const float4*)(s + i);
        float4 v1 = *(const float4*)(s + i + 4);
        union { __hip_bfloat16 h[8]; ushort4 u[2]; } cv;
        cv.h[0] = __float2bfloat16(v0.x); cv.h[1] = __float2bfloat16(v0.y);
        cv.h[2] = __float2bfloat16(v0.z); cv.h[3] = __float2bfloat16(v0.w);
        cv.h[4] = __float2bfloat16(v1.x); cv.h[5] = __float2bfloat16(v1.y);
        cv.h[6] = __float2bfloat16(v1.z); cv.h[7] = __float2bfloat16(v1.w);
        *(ushort4*)(d + i)     = cv.u[0];
        *(ushort4*)(d + i + 4) = cv.u[1];
    } else {
        const int i = (b - 22528) * 256 + threadIdx.x;   // 0..10239
        float v;
        if (i < 4096) v = b0[i];
        else if (i < 8192) v = b1[i - 4096];
        else v = b2[i - 8192];
        cb[i] = v;
    }
}

// ---------------------------------------------------------------------------
// cast2 (runs after fused GEMM, into dead wbuf space):
// blocks 0..2047:    Wt1 REARRANGED -> wt1r[2048][2048]:
//                    wt1r[r][c] = Wt1[r&1023][(r>>10)*2048 + c]
//                    (rows 0..1023 = W1 = Wt1[:, :2048]; rows 1024.. = W2)
// blocks 2048..4095: Wt2 straight cast (4096x1024)
// ---------------------------------------------------------------------------
__global__ __launch_bounds__(256) void cast2(
    const float* __restrict__ Wt1, const float* __restrict__ Wt2,
    __hip_bfloat16* __restrict__ wt1r, __hip_bfloat16* __restrict__ wt2b)
{
    const int b = blockIdx.x;
    const int t = threadIdx.x;
    const float* s; __hip_bfloat16* d;
    if (b < 2048) {
        const int r = b, c = t * 8;
        s = Wt1 + (size_t)(r & 1023) * 4096 + (r >> 10) * 2048 + c;
        d = wt1r + (size_t)r * 2048 + c;
    } else {
        const int i = ((b - 2048) * 256 + t) * 8;
        s = Wt2 + i;
        d = wt2b + i;
    }
    float4 v0 = *(const float4*)s;
    float4 v1 = *(const float4*)(s + 4);
    union { __hip_bfloat16 h[8]; ushort4 u[2]; } cv;
    cv.h[0] = __float2bfloat16(v0.x); cv.h[1] = __float2bfloat16(v0.y);
    cv.h[2] = __float2bfloat16(v0.z); cv.h[3] = __float2bfloat16(v0.w);
    cv.h[4] = __float2bfloat16(v1.x); cv.h[5] = __float2bfloat16(v1.y);
    cv.h[6] = __float2bfloat16(v1.z); cv.h[7] = __float2bfloat16(v1.w);
    *(ushort4*)d       = cv.u[0];
    *(ushort4*)(d + 4) = cv.u[1];
}

// ---------------------------------------------------------------------------
// MFMA GEMM, C = A @ B^T (+bias, act). bf16 in, f32 out. Round-4 schedule +
// round-9 zero-conflict swizzle (slot p of row r holds K-quarter p^((r>>1)&3)).
// BM x BN tile, 256 thr (2x2 waves), BK=32, 3 LDS buffers, 2-deep prefetch,
// counted vmcnt + raw s_barrier.
// mode: 0 = +bias (nullable); 2 = relu(resid + . + bias);
//       4 = split epilogue: cn < reluStart -> f32 +bias into C (stride ldc);
//           cn >= reluStart -> relu(+bias) -> bf16 into C2 (stride 2048,
//           col offset -8192). (fused ws|wo|conv output)
// ---------------------------------------------------------------------------
template<int BM, int BN>
__global__ __launch_bounds__(256) void gemm_p2(
    const ushort* __restrict__ A, const ushort* __restrict__ B,
    const float* __restrict__ bias, const float* __restrict__ resid,
    float* __restrict__ C, __hip_bfloat16* __restrict__ C2,
    int M, int K, int ldc, int mode, int reluStart)
{
    constexpr int MREP = BM / 32;
    constexpr int NREP = BN / 32;
    constexpr int SLOTS = (BM + BN) * 4;
    constexpr int NPW = SLOTS / 256;
    constexpr int BUFE = SLOTS * 8;

    __shared__ ushort lds[3][BUFE];

    const int t = threadIdx.x;
    const int lane = t & 63;
    const int wid = t >> 6;
    const int wr = wid >> 1, wc = wid & 1;

    const int MT = M / BM;
    const int G = gridDim.x;
    const int bid = blockIdx.x;
    const int wgid = (bid & 7) * (G >> 3) + (bid >> 3);   // XCD swizzle (G%8==0)
    const int nt = wgid / MT, mt = wgid % MT;
    const int bm = mt * BM, bn = nt * BN;

    const ushort* gp[NPW];
    int loff[NPW];
#pragma unroll
    for (int i = 0; i < NPW; ++i) {
        const int slot = i * 256 + t;
        const bool isA = slot < BM * 4;
        const int s2 = isA ? slot : slot - BM * 4;
        const int row = s2 >> 2;
        const int q = (s2 & 3) ^ ((row >> 1) & 3);        // pre-swizzled source
        gp[i] = (isA ? A + (size_t)(bm + row) * K : B + (size_t)(bn + row) * K) + q * 8;
        loff[i] = slot * 8;                               // linear LDS dest
    }

    auto stage = [&](int b, int kpos) {
#pragma unroll
        for (int i = 0; i < NPW; ++i) GLD16(gp[i] + kpos, &lds[b][loff[i]]);
    };

    int aoff[MREP], boff[NREP];
    const int sx = (((lane >> 4) ^ ((lane >> 1) & 3))) << 3;
#pragma unroll
    for (int m = 0; m < MREP; ++m)
        aoff[m] = (wr * (BM / 2) + (lane & 15) + m * 16) * 32 + sx;
#pragma unroll
    for (int n = 0; n < NREP; ++n)
        boff[n] = BM * 32 + (wc * (BN / 2) + (lane & 15) + n * 16) * 32 + sx;

    f32x4 acc[MREP][NREP] = {};

    const int NT = K >> 5;
    stage(0, 0);
    stage(1, 32);
    if constexpr (NPW == 2) waitvm<2>();
    else if constexpr (NPW == 3) waitvm<3>();
    else waitvm<4>();
    __builtin_amdgcn_sched_barrier(0);
    __builtin_amdgcn_s_barrier();
    __builtin_amdgcn_sched_barrier(0);

    for (int tt = 0; tt < NT; ++tt) {
        const bool pf = (tt + 2 < NT);
        if (pf) stage((tt + 2) % 3, (tt + 2) << 5);
        __builtin_amdgcn_sched_barrier(0);

        const ushort* lb = lds[tt % 3];
        bf16x8 af[MREP], bfv[NREP];
#pragma unroll
        for (int m = 0; m < MREP; ++m) af[m] = *(const bf16x8*)(lb + aoff[m]);
#pragma unroll
        for (int n = 0; n < NREP; ++n) bfv[n] = *(const bf16x8*)(lb + boff[n]);
#pragma unroll
        for (int m = 0; m < MREP; ++m)
#pragma unroll
            for (int n = 0; n < NREP; ++n)
                acc[m][n] = __builtin_amdgcn_mfma_f32_16x16x32_bf16(
                    af[m], bfv[n], acc[m][n], 0, 0, 0);

        __builtin_amdgcn_sched_barrier(0);
        if (pf) {
            if constexpr (NPW == 2) waitvm<2>();
            else if constexpr (NPW == 3) waitvm<3>();
            else waitvm<4>();
        } else {
            waitvm<0>();
        }
        __builtin_amdgcn_sched_barrier(0);
        __builtin_amdgcn_s_barrier();
        __builtin_amdgcn_sched_barrier(0);
    }

    // --- epilogue: C/D map col=lane&15, row=(lane>>4)*4+reg ---
    const int col0 = bn + wc * (BN / 2) + (lane & 15);
    const int row0 = bm + wr * (BM / 2) + ((lane >> 4) << 2);
#pragma unroll
    for (int m = 0; m < MREP; ++m) {
#pragma unroll
        for (int n = 0; n < NREP; ++n) {
            const int cn = col0 + n * 16;
            const float bz = bias ? bias[cn] : 0.f;
#pragma unroll
            for (int rg = 0; rg < 4; ++rg) {
                const int gm = row0 + m * 16 + rg;
                float v = acc[m][n][rg] + bz;
                if (mode == 2) {
                    v = fmaxf(v + resid[(size_t)gm * ldc + cn], 0.f);
                    C[(size_t)gm * ldc + cn] = v;
                } else if (mode == 4) {
                    if (cn < reluStart) {
                        C[(size_t)gm * ldc + cn] = v;
                    } else {
                        C2[(size_t)gm * 2048 + (cn - 8192)] =
                            __float2bfloat16(fmaxf(v, 0.f));
                    }
                } else {
                    C[(size_t)gm * ldc + cn] = v;
                }
            }
        }
    }
}

// ---------------------------------------------------------------------------
// atten[r] = sum_d ws[s[r],d] * wo[o[r],d] * phr[r,d] * Www[d]  + Wwb
// ws/wo in allout, row stride LDA=8192, col offsets 0 / 4096.
// ---------------------------------------------------------------------------
__global__ __launch_bounds__(256) void atten_kernel(
    const float* __restrict__ allout, const float* __restrict__ phr,
    const int* __restrict__ rel, const float* __restrict__ Www,
    const float* __restrict__ Wwb, float* __restrict__ atten)
{
    const int r = blockIdx.x;
    const int s = rel[r * 3 + 1], o = rel[r * 3 + 2];
    const int t = threadIdx.x;
    const float4* pws = (const float4*)(allout + (size_t)s * LDA);
    const float4* pwo = (const float4*)(allout + (size_t)o * LDA + 4096);
    const float4* pph = (const float4*)(phr + (size_t)r * D_);
    const float4* pww = (const float4*)Www;
    float sum = 0.f;
    for (int qq = t; qq < D_ / 4; qq += 256) {
        float4 a = pws[qq], b = pwo[qq], c = pph[qq], w = pww[qq];
        sum += a.x * b.x * c.x * w.x + a.y * b.y * c.y * w.y
             + a.z * b.z * c.z * w.z + a.w * b.w * c.w * w.w;
    }
    for (int off = 32; off > 0; off >>= 1) sum += __shfl_down(sum, off);
    __shared__ float red[4];
    if ((t & 63) == 0) red[t >> 6] = sum;
    __syncthreads();
    if (t == 0) atten[r] = red[0] + red[1] + red[2] + red[3] + Wwb[0];
}

// ---------------------------------------------------------------------------
__global__ __launch_bounds__(256) void build_A(
    const int* __restrict__ rel, const float* __restrict__ atten,
    float* __restrict__ Anorm)
{
    const int g = blockIdx.x;
    const int t = threadIdx.x;
    __shared__ float Am[64][64];
    __shared__ float S[64];
    __shared__ int headSh;
    for (int i = t; i < 4096; i += 256) ((float*)Am)[i] = 0.f;
    if (t == 0) headSh = 0x7fffffff;

    int lmin = 0x7fffffff;
    for (int rr = t; rr < RPER; rr += 256) {
        const int base = (g * RPER + rr) * 3;
        lmin = min(lmin, min(rel[base + 1], rel[base + 2]));
    }
    for (int off = 32; off > 0; off >>= 1) lmin = min(lmin, __shfl_down(lmin, off));
    __syncthreads();
    if ((t & 63) == 0) atomicMin(&headSh, lmin);
    __syncthreads();
    const int head = headSh;

    for (int rr = t; rr < RPER; rr += 256) {
        const int base = (g * RPER + rr) * 3;
        atomicAdd(&Am[rel[base + 1] - head][rel[base + 2] - head],
                  atten[g * RPER + rr]);
    }
    __syncthreads();

    for (int idx = t; idx < 4096; idx += 256) {
        const int i = idx >> 6, j = idx & 63;
        float v = 1.f / (1.f + expf(-Am[i][j]));
        if (i == j) v = 0.f;
        Am[i][j] = v;
    }
    __syncthreads();

    if (t < 64) {
        float sum = 0.f;
        for (int k = 0; k < 64; ++k) sum += Am[t][k];
        S[t] = sum;
    }
    __syncthreads();

    float* outg = Anorm + (size_t)g * 4096;
    for (int idx = t; idx < 4096; idx += 256) {
        const int j = idx & 63;
        outg[idx] = ((const float*)Am)[idx] / S[j];
    }
}

// ---------------------------------------------------------------------------
// h[g*64+i, :] = sum_j Arow[j]*P1[g*64+j, :] + Acol[j]*P2[g*64+j, :] + Wt1_b
// then LayerNorm(1024) + affine + relu -> bf16.  One block per (g,i); 256 thr
// cover the full 1024-col row (1 float4 each) so LN is block-local.
// P row stride 2048: cols 0..1023 = P1, 1024..2047 = P2.
// ---------------------------------------------------------------------------
__global__ __launch_bounds__(256) void amult_ln(
    const float* __restrict__ Anorm, const float* __restrict__ P,
    const float* __restrict__ w1b, const float* __restrict__ gamma,
    const float* __restrict__ beta, __hip_bfloat16* __restrict__ hb)
{
    const int g = blockIdx.x >> 6;
    const int i = blockIdx.x & 63;
    const int t = threadIdx.x;
    __shared__ float Ar[64], Ac[64];
    if (t < 64) Ar[t] = Anorm[(size_t)g * 4096 + i * 64 + t];
    else if (t < 128) { const int j = t - 64; Ac[j] = Anorm[(size_t)g * 4096 + j * 64 + i]; }
    __syncthreads();

    const float* pg = P + (size_t)g * 64 * 2048;
    float4 v = {0, 0, 0, 0};
    for (int j = 0; j < 64; ++j) {
        float4 p1 = *(const float4*)(pg + (size_t)j * 2048 + (t << 2));
        float4 p2 = *(const float4*)(pg + (size_t)j * 2048 + 1024 + (t << 2));
        fma4(v, Ar[j], p1);
        fma4(v, Ac[j], p2);
    }
    float4 b0 = *(const float4*)(w1b + (t << 2));
    v.x += b0.x; v.y += b0.y; v.z += b0.z; v.w += b0.w;

    float s  = v.x + v.y + v.z + v.w;
    float ss = v.x * v.x + v.y * v.y + v.z * v.z + v.w * v.w;
    for (int off = 32; off > 0; off >>= 1) {
        s  += __shfl_down(s, off);
        ss += __shfl_down(ss, off);
    }
    __shared__ float rs[4], rss[4];
    if ((t & 63) == 0) { rs[t >> 6] = s; rss[t >> 6] = ss; }
    __syncthreads();
    const float tot  = rs[0] + rs[1] + rs[2] + rs[3];
    const float tot2 = rss[0] + rss[1] + rss[2] + rss[3];
    const float mu   = tot * (1.f / DT);
    const float var  = tot2 * (1.f / DT) - mu * mu;
    const float rstd = rsqrtf(var + 1e-5f);
    float4 g4 = *(const float4*)(gamma + (t << 2));
    float4 b4 = *(const float4*)(beta + (t << 2));
    float4 o;
    o.x = fmaxf(fmaf((v.x - mu) * rstd, g4.x, b4.x), 0.f);
    o.y = fmaxf(fmaf((v.y - mu) * rstd, g4.y, b4.y), 0.f);
    o.z = fmaxf(fmaf((v.z - mu) * rstd, g4.z, b4.z), 0.f);
    o.w = fmaxf(fmaf((v.w - mu) * rstd, g4.w, b4.w), 0.f);
    st4bf(hb + (size_t)(g * 64 + i) * DT + (t << 2), o);
}

// ---------------------------------------------------------------------------
extern "C" void kernel_launch(void* const* d_in, const int* in_sizes, int n_in,
                              void* d_out, int out_size, void* d_ws, size_t ws_size,
                              hipStream_t stream)
{
    const float* obj   = (const float*)d_in[0];
    const float* phr   = (const float*)d_in[1];
    const int*   rel   = (const int*)d_in[3];
    const float* Ws_w  = (const float*)d_in[5];
    const float* Ws_b  = (const float*)d_in[6];
    const float* Wo_w  = (const float*)d_in[7];
    const float* Wo_b  = (const float*)d_in[8];
    const float* Ww_w  = (const float*)d_in[9];
    const float* Ww_b  = (const float*)d_in[10];
    const float* Wc_w  = (const float*)d_in[11];
    const float* Wc_b  = (const float*)d_in[12];
    const float* Wt1_w = (const float*)d_in[13];
    const float* Wt1_b = (const float*)d_in[14];
    const float* ln_g  = (const float*)d_in[15];
    const float* ln_b  = (const float*)d_in[16];
    const float* Wt2_w = (const float*)d_in[17];
    const float* Wt2_b = (const float*)d_in[18];
    float* out = (float*)d_out;

    float* ws = (float*)d_ws;
    // workspace (float units), peak ~130.4 MB:
    __hip_bfloat16* wbuf   = (__hip_bfloat16*)ws;              // Ws|Wo|Wc bf16 (dead after fused)
    __hip_bfloat16* wt1r   = (__hip_bfloat16*)ws;              // cast2: 2048x2048 bf16 (alias wbuf)
    __hip_bfloat16* wt2b   = (__hip_bfloat16*)(ws + 2097152);  // cast2: 4096x1024 bf16 (alias wbuf)
    __hip_bfloat16* obj_bf = (__hip_bfloat16*)(ws + 20971520); // 4.2M bf16 (dead after fused)
    float* allout = ws + 23068672;                             // 1024 x 8192 f32 (dead after atten)
    float* Pbuf   = allout;                                    // 1024 x 2048 f32 (alias, after atten)
    __hip_bfloat16* h_bf = (__hip_bfloat16*)(allout + 2097152);// 1024x1024 bf16 (alias)
    __hip_bfloat16* conv_bf = (__hip_bfloat16*)(ws + 31457280);// 1024 x 2048 bf16
    float* atten  = ws + 32505856;                             // 8192
    float* Anorm  = ws + 32514048;                             // 65536
    float* cbias  = ws + 32579584;                             // 10240

    const dim3 blk(256);

    // 1. cast obj/Ws/Wo/Wc -> bf16 + bias concat
    cast_all<<<dim3(22568), blk, 0, stream>>>(
        obj, obj_bf, Ws_w, Wo_w, Wc_w, wbuf, Ws_b, Wo_b, Wc_b, cbias);

    // 2. fused ws|wo|conv GEMM; ws|wo f32 -> allout (ld 8192), conv relu bf16 -> conv_bf
    gemm_p2<128, 128><<<dim3(640), blk, 0, stream>>>(
        (const ushort*)obj_bf, (const ushort*)wbuf, cbias, nullptr,
        allout, conv_bf, NTOT, D_, LDA, 4, 8192);

    // 3. cast Wt1 (rearranged) + Wt2 into dead wbuf space
    cast2<<<dim3(4096), blk, 0, stream>>>(Wt1_w, Wt2_w, wt1r, wt2b);

    // 4. atten + A build
    atten_kernel<<<dim3(RTOT), blk, 0, stream>>>(allout, phr, rel, Ww_w, Ww_b, atten);
    build_A<<<dim3(NIMG), blk, 0, stream>>>(rel, atten, Anorm);

    // 5. P = conv_bf @ wt1r^T  (1024 x 2048, K=2048) -> Pbuf (aliases dead allout)
    gemm_p2<64, 64><<<dim3(512), blk, 0, stream>>>(
        (const ushort*)conv_bf, (const ushort*)wt1r, nullptr, nullptr,
        Pbuf, nullptr, NTOT, DC, DC, 0, 0);

    // 6. h = A*P1 + A^T*P2 + b, LN, relu -> bf16
    amult_ln<<<dim3(1024), blk, 0, stream>>>(Anorm, Pbuf, Wt1_b, ln_g, ln_b, h_bf);

    // 7. out = relu(obj + h @ Wt2^T + b)
    gemm_p2<128, 128><<<dim3(256), blk, 0, stream>>>(
        (const ushort*)h_bf, (const ushort*)wt2b, Wt2_b, obj,
        out, nullptr, NTOT, DT, D_, 2, 0);
}

// Round 11
// 299.135 us; speedup vs baseline: 2.0266x; 1.0631x over previous
//
#include <hip/hip_runtime.h>
#include <hip/hip_bf16.h>
#include <math.h>

#define D_   4096
#define NIMG 16
#define NPER 64
#define RPER 512
#define NTOT 1024
#define RTOT 8192
#define DC   2048
#define DT   1024
#define LDW  8192    // wswo_bf row stride (4096 ws | 4096 wo), bf16

typedef __attribute__((ext_vector_type(4))) float f32x4;
typedef __attribute__((ext_vector_type(8))) short bf16x8;

#define GLD16(gp, lp) __builtin_amdgcn_global_load_lds( \
    (const __attribute__((address_space(1))) unsigned int*)(gp), \
    (__attribute__((address_space(3))) unsigned int*)(lp), 16, 0, 0)

template<int N> __device__ __forceinline__ void waitvm() {
    asm volatile("s_waitcnt vmcnt(%0)" :: "n"(N) : "memory");
}

__device__ __forceinline__ void fma4(float4& d, float s, const float4 c) {
    d.x = fmaf(s, c.x, d.x); d.y = fmaf(s, c.y, d.y);
    d.z = fmaf(s, c.z, d.z); d.w = fmaf(s, c.w, d.w);
}
__device__ __forceinline__ void st4bf(__hip_bfloat16* p, float4 v) {
    union { __hip_bfloat16 h[4]; ushort4 u; } cv;
    cv.h[0] = __float2bfloat16(v.x); cv.h[1] = __float2bfloat16(v.y);
    cv.h[2] = __float2bfloat16(v.z); cv.h[3] = __float2bfloat16(v.w);
    *(ushort4*)p = cv.u;
}
__device__ __forceinline__ float bf2f(ushort u) {
    union { float f; unsigned int i; } c; c.i = (unsigned int)u << 16; return c.f;
}

// ---------------------------------------------------------------------------
// ONE up-front dispatch: cast obj/Ws/Wo/Wc/Wt1(rearranged)/Wt2 -> bf16,
// concat biases. 2048 elems per block (bias blocks: 256).
// wt1r[r][c] = Wt1[r&1023][(r>>10)*2048 + c]  (rows 0..1023 = Wt1[:, :2048])
// ---------------------------------------------------------------------------
__global__ __launch_bounds__(256) void cast_all(
    const float* __restrict__ obj, __hip_bfloat16* __restrict__ obj_bf,
    const float* __restrict__ Ws, const float* __restrict__ Wo,
    const float* __restrict__ Wc, __hip_bfloat16* __restrict__ wbuf,
    const float* __restrict__ Wt1, __hip_bfloat16* __restrict__ wt1r,
    const float* __restrict__ Wt2, __hip_bfloat16* __restrict__ wt2b,
    const float* __restrict__ b0, const float* __restrict__ b1,
    const float* __restrict__ b2, float* __restrict__ cb)
{
    const int b = blockIdx.x;
    const int t = threadIdx.x;
    if (b >= 26624) {                                    // bias concat
        const int i = (b - 26624) * 256 + t;             // 0..10239
        float v;
        if (i < 4096) v = b0[i];
        else if (i < 8192) v = b1[i - 4096];
        else v = b2[i - 8192];
        cb[i] = v;
        return;
    }
    const float* s; __hip_bfloat16* d;
    if (b < 2048)       { s = obj + (size_t)b * 2048;            d = obj_bf + (size_t)b * 2048; }
    else if (b < 10240) { const int rb = b - 2048;  s = Ws + (size_t)rb * 2048; d = wbuf + (size_t)rb * 2048; }
    else if (b < 18432) { const int rb = b - 10240; s = Wo + (size_t)rb * 2048; d = wbuf + 16777216 + (size_t)rb * 2048; }
    else if (b < 22528) { const int rb = b - 18432; s = Wc + (size_t)rb * 2048; d = wbuf + 33554432 + (size_t)rb * 2048; }
    else if (b < 24576) { const int r = b - 22528;                // wt1 rearranged
                          s = Wt1 + (size_t)(r & 1023) * 4096 + (r >> 10) * 2048;
                          d = wt1r + (size_t)r * 2048; }
    else                { const int rb = b - 24576; s = Wt2 + (size_t)rb * 2048; d = wt2b + (size_t)rb * 2048; }
    const int i = t * 8;
    float4 v0 = *(const float4*)(s + i);
    float4 v1 = *(const float4*)(s + i + 4);
    union { __hip_bfloat16 h[8]; ushort4 u[2]; } cv;
    cv.h[0] = __float2bfloat16(v0.x); cv.h[1] = __float2bfloat16(v0.y);
    cv.h[2] = __float2bfloat16(v0.z); cv.h[3] = __float2bfloat16(v0.w);
    cv.h[4] = __float2bfloat16(v1.x); cv.h[5] = __float2bfloat16(v1.y);
    cv.h[6] = __float2bfloat16(v1.z); cv.h[7] = __float2bfloat16(v1.w);
    *(ushort4*)(d + i)     = cv.u[0];
    *(ushort4*)(d + i + 4) = cv.u[1];
}

// ---------------------------------------------------------------------------
// MFMA GEMM, C = A @ B^T (+bias, act). bf16 in. Round-4 schedule + round-9
// zero-conflict swizzle (slot p of row r holds K-quarter p^((r>>1)&3)).
// BM x BN tile, 256 thr (2x2 waves), BK=32, 3 LDS buffers, 2-deep prefetch,
// counted vmcnt + raw s_barrier.
// mode: 0 = +bias (nullable), f32 out C
//       2 = relu(resid + . + bias), f32 out C
//       4 = fused ws|wo|conv epilogue: cn < 8192 -> bf16 +bias into C2
//           (stride 8192); cn >= 8192 -> relu(+bias) bf16 into C3 (stride
//           2048, col offset -8192)
// ---------------------------------------------------------------------------
template<int BM, int BN>
__global__ __launch_bounds__(256) void gemm_p2(
    const ushort* __restrict__ A, const ushort* __restrict__ B,
    const float* __restrict__ bias, const float* __restrict__ resid,
    float* __restrict__ C, __hip_bfloat16* __restrict__ C2,
    __hip_bfloat16* __restrict__ C3,
    int M, int K, int ldc, int mode)
{
    constexpr int MREP = BM / 32;
    constexpr int NREP = BN / 32;
    constexpr int SLOTS = (BM + BN) * 4;
    constexpr int NPW = SLOTS / 256;
    constexpr int BUFE = SLOTS * 8;

    __shared__ ushort lds[3][BUFE];

    const int t = threadIdx.x;
    const int lane = t & 63;
    const int wid = t >> 6;
    const int wr = wid >> 1, wc = wid & 1;

    const int MT = M / BM;
    const int G = gridDim.x;
    const int bid = blockIdx.x;
    const int wgid = (bid & 7) * (G >> 3) + (bid >> 3);   // XCD swizzle (G%8==0)
    const int nt = wgid / MT, mt = wgid % MT;
    const int bm = mt * BM, bn = nt * BN;

    const ushort* gp[NPW];
    int loff[NPW];
#pragma unroll
    for (int i = 0; i < NPW; ++i) {
        const int slot = i * 256 + t;
        const bool isA = slot < BM * 4;
        const int s2 = isA ? slot : slot - BM * 4;
        const int row = s2 >> 2;
        const int q = (s2 & 3) ^ ((row >> 1) & 3);        // pre-swizzled source
        gp[i] = (isA ? A + (size_t)(bm + row) * K : B + (size_t)(bn + row) * K) + q * 8;
        loff[i] = slot * 8;                               // linear LDS dest
    }

    auto stage = [&](int b, int kpos) {
#pragma unroll
        for (int i = 0; i < NPW; ++i) GLD16(gp[i] + kpos, &lds[b][loff[i]]);
    };

    int aoff[MREP], boff[NREP];
    const int sx = (((lane >> 4) ^ ((lane >> 1) & 3))) << 3;
#pragma unroll
    for (int m = 0; m < MREP; ++m)
        aoff[m] = (wr * (BM / 2) + (lane & 15) + m * 16) * 32 + sx;
#pragma unroll
    for (int n = 0; n < NREP; ++n)
        boff[n] = BM * 32 + (wc * (BN / 2) + (lane & 15) + n * 16) * 32 + sx;

    f32x4 acc[MREP][NREP] = {};

    const int NT = K >> 5;
    stage(0, 0);
    stage(1, 32);
    if constexpr (NPW == 2) waitvm<2>();
    else if constexpr (NPW == 3) waitvm<3>();
    else waitvm<4>();
    __builtin_amdgcn_sched_barrier(0);
    __builtin_amdgcn_s_barrier();
    __builtin_amdgcn_sched_barrier(0);

    for (int tt = 0; tt < NT; ++tt) {
        const bool pf = (tt + 2 < NT);
        if (pf) stage((tt + 2) % 3, (tt + 2) << 5);
        __builtin_amdgcn_sched_barrier(0);

        const ushort* lb = lds[tt % 3];
        bf16x8 af[MREP], bfv[NREP];
#pragma unroll
        for (int m = 0; m < MREP; ++m) af[m] = *(const bf16x8*)(lb + aoff[m]);
#pragma unroll
        for (int n = 0; n < NREP; ++n) bfv[n] = *(const bf16x8*)(lb + boff[n]);
#pragma unroll
        for (int m = 0; m < MREP; ++m)
#pragma unroll
            for (int n = 0; n < NREP; ++n)
                acc[m][n] = __builtin_amdgcn_mfma_f32_16x16x32_bf16(
                    af[m], bfv[n], acc[m][n], 0, 0, 0);

        __builtin_amdgcn_sched_barrier(0);
        if (pf) {
            if constexpr (NPW == 2) waitvm<2>();
            else if constexpr (NPW == 3) waitvm<3>();
            else waitvm<4>();
        } else {
            waitvm<0>();
        }
        __builtin_amdgcn_sched_barrier(0);
        __builtin_amdgcn_s_barrier();
        __builtin_amdgcn_sched_barrier(0);
    }

    // --- epilogue: C/D map col=lane&15, row=(lane>>4)*4+reg ---
    const int col0 = bn + wc * (BN / 2) + (lane & 15);
    const int row0 = bm + wr * (BM / 2) + ((lane >> 4) << 2);
#pragma unroll
    for (int m = 0; m < MREP; ++m) {
#pragma unroll
        for (int n = 0; n < NREP; ++n) {
            const int cn = col0 + n * 16;
            const float bz = bias ? bias[cn] : 0.f;
#pragma unroll
            for (int rg = 0; rg < 4; ++rg) {
                const int gm = row0 + m * 16 + rg;
                float v = acc[m][n][rg] + bz;
                if (mode == 2) {
                    C[(size_t)gm * ldc + cn] = fmaxf(v + resid[(size_t)gm * ldc + cn], 0.f);
                } else if (mode == 4) {
                    if (cn < 8192)
                        C2[(size_t)gm * LDW + cn] = __float2bfloat16(v);
                    else
                        C3[(size_t)gm * 2048 + (cn - 8192)] =
                            __float2bfloat16(fmaxf(v, 0.f));
                } else {
                    C[(size_t)gm * ldc + cn] = v;
                }
            }
        }
    }
}

// ---------------------------------------------------------------------------
// atten[r] = sum_d ws[s[r],d] * wo[o[r],d] * phr[r,d] * Www[d]  + Wwb
// ws/wo are bf16 in wswo (row stride LDW, col offsets 0 / 4096).
// ---------------------------------------------------------------------------
__global__ __launch_bounds__(256) void atten_kernel(
    const ushort* __restrict__ wswo, const float* __restrict__ phr,
    const int* __restrict__ rel, const float* __restrict__ Www,
    const float* __restrict__ Wwb, float* __restrict__ atten)
{
    const int r = blockIdx.x;
    const int s = rel[r * 3 + 1], o = rel[r * 3 + 2];
    const int t = threadIdx.x;
    const ushort* pws = wswo + (size_t)s * LDW;
    const ushort* pwo = wswo + (size_t)o * LDW + 4096;
    const float*  pph = phr + (size_t)r * D_;
    float sum = 0.f;
#pragma unroll
    for (int half = 0; half < 2; ++half) {
        const int q = t * 8 + half * 2048;
        ushort4 w0 = *(const ushort4*)(pws + q);
        ushort4 w1 = *(const ushort4*)(pws + q + 4);
        ushort4 u0 = *(const ushort4*)(pwo + q);
        ushort4 u1 = *(const ushort4*)(pwo + q + 4);
        float4 p0 = *(const float4*)(pph + q);
        float4 p1 = *(const float4*)(pph + q + 4);
        float4 g0 = *(const float4*)(Www + q);
        float4 g1 = *(const float4*)(Www + q + 4);
        sum += bf2f(w0.x) * bf2f(u0.x) * p0.x * g0.x
             + bf2f(w0.y) * bf2f(u0.y) * p0.y * g0.y
             + bf2f(w0.z) * bf2f(u0.z) * p0.z * g0.z
             + bf2f(w0.w) * bf2f(u0.w) * p0.w * g0.w
             + bf2f(w1.x) * bf2f(u1.x) * p1.x * g1.x
             + bf2f(w1.y) * bf2f(u1.y) * p1.y * g1.y
             + bf2f(w1.z) * bf2f(u1.z) * p1.z * g1.z
             + bf2f(w1.w) * bf2f(u1.w) * p1.w * g1.w;
    }
    for (int off = 32; off > 0; off >>= 1) sum += __shfl_down(sum, off);
    __shared__ float red[4];
    if ((t & 63) == 0) red[t >> 6] = sum;
    __syncthreads();
    if (t == 0) atten[r] = red[0] + red[1] + red[2] + red[3] + Wwb[0];
}

// ---------------------------------------------------------------------------
__global__ __launch_bounds__(256) void build_A(
    const int* __restrict__ rel, const float* __restrict__ atten,
    float* __restrict__ Anorm)
{
    const int g = blockIdx.x;
    const int t = threadIdx.x;
    __shared__ float Am[64][64];
    __shared__ float S[64];
    __shared__ int headSh;
    for (int i = t; i < 4096; i += 256) ((float*)Am)[i] = 0.f;
    if (t == 0) headSh = 0x7fffffff;

    int lmin = 0x7fffffff;
    for (int rr = t; rr < RPER; rr += 256) {
        const int base = (g * RPER + rr) * 3;
        lmin = min(lmin, min(rel[base + 1], rel[base + 2]));
    }
    for (int off = 32; off > 0; off >>= 1) lmin = min(lmin, __shfl_down(lmin, off));
    __syncthreads();
    if ((t & 63) == 0) atomicMin(&headSh, lmin);
    __syncthreads();
    const int head = headSh;

    for (int rr = t; rr < RPER; rr += 256) {
        const int base = (g * RPER + rr) * 3;
        atomicAdd(&Am[rel[base + 1] - head][rel[base + 2] - head],
                  atten[g * RPER + rr]);
    }
    __syncthreads();

    for (int idx = t; idx < 4096; idx += 256) {
        const int i = idx >> 6, j = idx & 63;
        float v = 1.f / (1.f + expf(-Am[i][j]));
        if (i == j) v = 0.f;
        Am[i][j] = v;
    }
    __syncthreads();

    if (t < 64) {
        float sum = 0.f;
        for (int k = 0; k < 64; ++k) sum += Am[t][k];
        S[t] = sum;
    }
    __syncthreads();

    float* outg = Anorm + (size_t)g * 4096;
    for (int idx = t; idx < 4096; idx += 256) {
        const int j = idx & 63;
        outg[idx] = ((const float*)Am)[idx] / S[j];
    }
}

// ---------------------------------------------------------------------------
// h[g*64+i, :] = sum_j Ar[j]*P1[g*64+j, :] + Ac[j]*P2[g*64+j, :] + Wt1_b
// then LayerNorm(1024) + affine + relu -> bf16. One block per (g,i).
// P row stride 2048: cols 0..1023 = P1, 1024..2047 = P2.
// ---------------------------------------------------------------------------
__global__ __launch_bounds__(256) void amult_ln(
    const float* __restrict__ Anorm, const float* __restrict__ P,
    const float* __restrict__ w1b, const float* __restrict__ gamma,
    const float* __restrict__ beta, __hip_bfloat16* __restrict__ hb)
{
    const int g = blockIdx.x >> 6;
    const int i = blockIdx.x & 63;
    const int t = threadIdx.x;
    __shared__ float Ar[64], Ac[64];
    if (t < 64) Ar[t] = Anorm[(size_t)g * 4096 + i * 64 + t];
    else if (t < 128) { const int j = t - 64; Ac[j] = Anorm[(size_t)g * 4096 + j * 64 + i]; }
    __syncthreads();

    const float* pg = P + (size_t)g * 64 * 2048;
    float4 v = {0, 0, 0, 0};
    for (int j = 0; j < 64; ++j) {
        float4 p1 = *(const float4*)(pg + (size_t)j * 2048 + (t << 2));
        float4 p2 = *(const float4*)(pg + (size_t)j * 2048 + 1024 + (t << 2));
        fma4(v, Ar[j], p1);
        fma4(v, Ac[j], p2);
    }
    float4 b0 = *(const float4*)(w1b + (t << 2));
    v.x += b0.x; v.y += b0.y; v.z += b0.z; v.w += b0.w;

    float s  = v.x + v.y + v.z + v.w;
    float ss = v.x * v.x + v.y * v.y + v.z * v.z + v.w * v.w;
    for (int off = 32; off > 0; off >>= 1) {
        s  += __shfl_down(s, off);
        ss += __shfl_down(ss, off);
    }
    __shared__ float rs[4], rss[4];
    if ((t & 63) == 0) { rs[t >> 6] = s; rss[t >> 6] = ss; }
    __syncthreads();
    const float tot  = rs[0] + rs[1] + rs[2] + rs[3];
    const float tot2 = rss[0] + rss[1] + rss[2] + rss[3];
    const float mu   = tot * (1.f / DT);
    const float var  = tot2 * (1.f / DT) - mu * mu;
    const float rstd = rsqrtf(var + 1e-5f);
    float4 g4 = *(const float4*)(gamma + (t << 2));
    float4 b4 = *(const float4*)(beta + (t << 2));
    float4 o;
    o.x = fmaxf(fmaf((v.x - mu) * rstd, g4.x, b4.x), 0.f);
    o.y = fmaxf(fmaf((v.y - mu) * rstd, g4.y, b4.y), 0.f);
    o.z = fmaxf(fmaf((v.z - mu) * rstd, g4.z, b4.z), 0.f);
    o.w = fmaxf(fmaf((v.w - mu) * rstd, g4.w, b4.w), 0.f);
    st4bf(hb + (size_t)(g * 64 + i) * DT + (t << 2), o);
}

// ---------------------------------------------------------------------------
extern "C" void kernel_launch(void* const* d_in, const int* in_sizes, int n_in,
                              void* d_out, int out_size, void* d_ws, size_t ws_size,
                              hipStream_t stream)
{
    const float* obj   = (const float*)d_in[0];
    const float* phr   = (const float*)d_in[1];
    const int*   rel   = (const int*)d_in[3];
    const float* Ws_w  = (const float*)d_in[5];
    const float* Ws_b  = (const float*)d_in[6];
    const float* Wo_w  = (const float*)d_in[7];
    const float* Wo_b  = (const float*)d_in[8];
    const float* Ww_w  = (const float*)d_in[9];
    const float* Ww_b  = (const float*)d_in[10];
    const float* Wc_w  = (const float*)d_in[11];
    const float* Wc_b  = (const float*)d_in[12];
    const float* Wt1_w = (const float*)d_in[13];
    const float* Wt1_b = (const float*)d_in[14];
    const float* ln_g  = (const float*)d_in[15];
    const float* ln_b  = (const float*)d_in[16];
    const float* Wt2_w = (const float*)d_in[17];
    const float* Wt2_b = (const float*)d_in[18];
    float* out = (float*)d_out;

    float* ws = (float*)d_ws;
    // workspace (float units), peak ~130.4 MB:
    __hip_bfloat16* wbuf    = (__hip_bfloat16*)ws;              // Ws|Wo|Wc bf16 [0, 20971520) — dead after fused
    __hip_bfloat16* h_bf    = (__hip_bfloat16*)ws;              // 1024x1024 bf16 (alias dead wbuf)
    __hip_bfloat16* obj_bf  = (__hip_bfloat16*)(ws + 20971520); // 4.2M bf16 — dead after fused
    float* Pbuf             = ws + 20971520;                    // 1024x2048 f32 (alias dead obj_bf)
    __hip_bfloat16* wswo_bf = (__hip_bfloat16*)(ws + 23068672); // 1024x8192 bf16
    __hip_bfloat16* conv_bf = (__hip_bfloat16*)(ws + 27262976); // 1024x2048 bf16
    __hip_bfloat16* wt1r    = (__hip_bfloat16*)(ws + 28311552); // 2048x2048 bf16
    __hip_bfloat16* wt2b    = (__hip_bfloat16*)(ws + 30408704); // 4096x1024 bf16
    float* atten  = ws + 32505856;                              // 8192
    float* Anorm  = ws + 32514048;                              // 65536
    float* cbias  = ws + 32579584;                              // 10240

    const dim3 blk(256);

    // 1. single cast dispatch: obj, Ws, Wo, Wc, Wt1r, Wt2 -> bf16 + biases
    cast_all<<<dim3(26664), blk, 0, stream>>>(
        obj, obj_bf, Ws_w, Wo_w, Wc_w, wbuf, Wt1_w, wt1r, Wt2_w, wt2b,
        Ws_b, Wo_b, Wc_b, cbias);

    // 2. fused ws|wo|conv GEMM; ws|wo bf16 -> wswo_bf, conv relu bf16 -> conv_bf
    gemm_p2<128, 128><<<dim3(640), blk, 0, stream>>>(
        (const ushort*)obj_bf, (const ushort*)wbuf, cbias, nullptr,
        nullptr, wswo_bf, conv_bf, NTOT, D_, 0, 4);

    // 3. atten (bf16 ws/wo) + A build
    atten_kernel<<<dim3(RTOT), blk, 0, stream>>>(
        (const ushort*)wswo_bf, phr, rel, Ww_w, Ww_b, atten);
    build_A<<<dim3(NIMG), blk, 0, stream>>>(rel, atten, Anorm);

    // 4. P = conv_bf @ wt1r^T (1024 x 2048, K=2048) -> Pbuf (aliases dead obj_bf)
    gemm_p2<64, 64><<<dim3(512), blk, 0, stream>>>(
        (const ushort*)conv_bf, (const ushort*)wt1r, nullptr, nullptr,
        Pbuf, nullptr, nullptr, NTOT, DC, DC, 0);

    // 5. h = A*P1 + A^T*P2 + b, LN, relu -> bf16 (aliases dead wbuf)
    amult_ln<<<dim3(1024), blk, 0, stream>>>(Anorm, Pbuf, Wt1_b, ln_g, ln_b, h_bf);

    // 6. out = relu(obj + h @ Wt2^T + b)  — 64x128 tiles, 512 blocks (4/CU)
    gemm_p2<64, 128><<<dim3(512), blk, 0, stream>>>(
        (const ushort*)h_bf, (const ushort*)wt2b, Wt2_b, obj,
        out, nullptr, nullptr, NTOT, DT, D_, 2);
}

// Round 12
// 289.795 us; speedup vs baseline: 2.0919x; 1.0322x over previous
//
#include <hip/hip_runtime.h>
#include <hip/hip_bf16.h>
#include <math.h>

#define D_   4096
#define NIMG 16
#define NPER 64
#define RPER 512
#define NTOT 1024
#define RTOT 8192
#define DC   2048
#define DT   1024
#define LDW  8192    // wswo_bf row stride (4096 ws | 4096 wo), bf16

typedef __attribute__((ext_vector_type(4))) float f32x4;
typedef __attribute__((ext_vector_type(8))) short bf16x8;

#define GLD16(gp, lp) __builtin_amdgcn_global_load_lds( \
    (const __attribute__((address_space(1))) unsigned int*)(gp), \
    (__attribute__((address_space(3))) unsigned int*)(lp), 16, 0, 0)

template<int N> __device__ __forceinline__ void waitvm() {
    asm volatile("s_waitcnt vmcnt(%0)" :: "n"(N) : "memory");
}

__device__ __forceinline__ void fma4(float4& d, float s, const float4 c) {
    d.x = fmaf(s, c.x, d.x); d.y = fmaf(s, c.y, d.y);
    d.z = fmaf(s, c.z, d.z); d.w = fmaf(s, c.w, d.w);
}
__device__ __forceinline__ void st4bf(__hip_bfloat16* p, float4 v) {
    union { __hip_bfloat16 h[4]; ushort4 u; } cv;
    cv.h[0] = __float2bfloat16(v.x); cv.h[1] = __float2bfloat16(v.y);
    cv.h[2] = __float2bfloat16(v.z); cv.h[3] = __float2bfloat16(v.w);
    *(ushort4*)p = cv.u;
}
__device__ __forceinline__ float bf2f(ushort u) {
    union { float f; unsigned int i; } c; c.i = (unsigned int)u << 16; return c.f;
}
__device__ __forceinline__ ushort f2bfu(float v) {
    union { __hip_bfloat16 h; ushort u; } c; c.h = __float2bfloat16(v); return c.u;
}

// ---------------------------------------------------------------------------
// ONE up-front dispatch: cast obj/Ws/Wo/Wc/Wt1(rearranged)/Wt2 -> bf16,
// concat biases. 2048 elems per block (bias blocks: 256).
// wt1r[r][c] = Wt1[r&1023][(r>>10)*2048 + c]
// ---------------------------------------------------------------------------
__global__ __launch_bounds__(256) void cast_all(
    const float* __restrict__ obj, __hip_bfloat16* __restrict__ obj_bf,
    const float* __restrict__ Ws, const float* __restrict__ Wo,
    const float* __restrict__ Wc, __hip_bfloat16* __restrict__ wbuf,
    const float* __restrict__ Wt1, __hip_bfloat16* __restrict__ wt1r,
    const float* __restrict__ Wt2, __hip_bfloat16* __restrict__ wt2b,
    const float* __restrict__ b0, const float* __restrict__ b1,
    const float* __restrict__ b2, float* __restrict__ cb)
{
    const int b = blockIdx.x;
    const int t = threadIdx.x;
    if (b >= 26624) {                                    // bias concat
        const int i = (b - 26624) * 256 + t;             // 0..10239
        float v;
        if (i < 4096) v = b0[i];
        else if (i < 8192) v = b1[i - 4096];
        else v = b2[i - 8192];
        cb[i] = v;
        return;
    }
    const float* s; __hip_bfloat16* d;
    if (b < 2048)       { s = obj + (size_t)b * 2048;            d = obj_bf + (size_t)b * 2048; }
    else if (b < 10240) { const int rb = b - 2048;  s = Ws + (size_t)rb * 2048; d = wbuf + (size_t)rb * 2048; }
    else if (b < 18432) { const int rb = b - 10240; s = Wo + (size_t)rb * 2048; d = wbuf + 16777216 + (size_t)rb * 2048; }
    else if (b < 22528) { const int rb = b - 18432; s = Wc + (size_t)rb * 2048; d = wbuf + 33554432 + (size_t)rb * 2048; }
    else if (b < 24576) { const int r = b - 22528;                // wt1 rearranged
                          s = Wt1 + (size_t)(r & 1023) * 4096 + (r >> 10) * 2048;
                          d = wt1r + (size_t)r * 2048; }
    else                { const int rb = b - 24576; s = Wt2 + (size_t)rb * 2048; d = wt2b + (size_t)rb * 2048; }
    const int i = t * 8;
    float4 v0 = *(const float4*)(s + i);
    float4 v1 = *(const float4*)(s + i + 4);
    union { __hip_bfloat16 h[8]; ushort4 u[2]; } cv;
    cv.h[0] = __float2bfloat16(v0.x); cv.h[1] = __float2bfloat16(v0.y);
    cv.h[2] = __float2bfloat16(v0.z); cv.h[3] = __float2bfloat16(v0.w);
    cv.h[4] = __float2bfloat16(v1.x); cv.h[5] = __float2bfloat16(v1.y);
    cv.h[6] = __float2bfloat16(v1.z); cv.h[7] = __float2bfloat16(v1.w);
    *(ushort4*)(d + i)     = cv.u[0];
    *(ushort4*)(d + i + 4) = cv.u[1];
}

// ---------------------------------------------------------------------------
// MFMA GEMM, C = A @ B^T (+bias, act). bf16 in. Round-4 schedule + round-9
// zero-conflict swizzle. BM x BN tile, 256 thr (2x2 waves), BK=32, 3 LDS
// buffers, 2-deep prefetch, counted vmcnt + raw s_barrier.
// mode: 0 = +bias (nullable), f32 out C
//       2 = relu(resid + . + bias), f32 out C
//       4 = fused ws|wo|conv: bf16 out via LDS-bounce epilogue (see below);
//           cn < 8192 -> C2 (stride LDW); cn >= 8192 -> relu -> C3 (stride
//           2048, col offset -8192). 128x128 only; block col-range uniform.
// ---------------------------------------------------------------------------
template<int BM, int BN>
__global__ __launch_bounds__(256) void gemm_p2(
    const ushort* __restrict__ A, const ushort* __restrict__ B,
    const float* __restrict__ bias, const float* __restrict__ resid,
    float* __restrict__ C, __hip_bfloat16* __restrict__ C2,
    __hip_bfloat16* __restrict__ C3,
    int M, int K, int ldc, int mode)
{
    constexpr int MREP = BM / 32;
    constexpr int NREP = BN / 32;
    constexpr int SLOTS = (BM + BN) * 4;
    constexpr int NPW = SLOTS / 256;
    constexpr int BUFE = SLOTS * 8;

    __shared__ ushort lds[3][BUFE];

    const int t = threadIdx.x;
    const int lane = t & 63;
    const int wid = t >> 6;
    const int wr = wid >> 1, wc = wid & 1;

    const int MT = M / BM;
    const int G = gridDim.x;
    const int bid = blockIdx.x;
    const int wgid = (bid & 7) * (G >> 3) + (bid >> 3);   // XCD swizzle (G%8==0)
    const int nt = wgid / MT, mt = wgid % MT;
    const int bm = mt * BM, bn = nt * BN;

    const ushort* gp[NPW];
    int loff[NPW];
#pragma unroll
    for (int i = 0; i < NPW; ++i) {
        const int slot = i * 256 + t;
        const bool isA = slot < BM * 4;
        const int s2 = isA ? slot : slot - BM * 4;
        const int row = s2 >> 2;
        const int q = (s2 & 3) ^ ((row >> 1) & 3);        // pre-swizzled source
        gp[i] = (isA ? A + (size_t)(bm + row) * K : B + (size_t)(bn + row) * K) + q * 8;
        loff[i] = slot * 8;                               // linear LDS dest
    }

    auto stage = [&](int b, int kpos) {
#pragma unroll
        for (int i = 0; i < NPW; ++i) GLD16(gp[i] + kpos, &lds[b][loff[i]]);
    };

    int aoff[MREP], boff[NREP];
    const int sx = (((lane >> 4) ^ ((lane >> 1) & 3))) << 3;
#pragma unroll
    for (int m = 0; m < MREP; ++m)
        aoff[m] = (wr * (BM / 2) + (lane & 15) + m * 16) * 32 + sx;
#pragma unroll
    for (int n = 0; n < NREP; ++n)
        boff[n] = BM * 32 + (wc * (BN / 2) + (lane & 15) + n * 16) * 32 + sx;

    f32x4 acc[MREP][NREP] = {};

    const int NT = K >> 5;
    stage(0, 0);
    stage(1, 32);
    if constexpr (NPW == 2) waitvm<2>();
    else if constexpr (NPW == 3) waitvm<3>();
    else waitvm<4>();
    __builtin_amdgcn_sched_barrier(0);
    __builtin_amdgcn_s_barrier();
    __builtin_amdgcn_sched_barrier(0);

    for (int tt = 0; tt < NT; ++tt) {
        const bool pf = (tt + 2 < NT);
        if (pf) stage((tt + 2) % 3, (tt + 2) << 5);
        __builtin_amdgcn_sched_barrier(0);

        const ushort* lb = lds[tt % 3];
        bf16x8 af[MREP], bfv[NREP];
#pragma unroll
        for (int m = 0; m < MREP; ++m) af[m] = *(const bf16x8*)(lb + aoff[m]);
#pragma unroll
        for (int n = 0; n < NREP; ++n) bfv[n] = *(const bf16x8*)(lb + boff[n]);
#pragma unroll
        for (int m = 0; m < MREP; ++m)
#pragma unroll
            for (int n = 0; n < NREP; ++n)
                acc[m][n] = __builtin_amdgcn_mfma_f32_16x16x32_bf16(
                    af[m], bfv[n], acc[m][n], 0, 0, 0);

        __builtin_amdgcn_sched_barrier(0);
        if (pf) {
            if constexpr (NPW == 2) waitvm<2>();
            else if constexpr (NPW == 3) waitvm<3>();
            else waitvm<4>();
        } else {
            waitvm<0>();
        }
        __builtin_amdgcn_sched_barrier(0);
        __builtin_amdgcn_s_barrier();
        __builtin_amdgcn_sched_barrier(0);
    }

    // --- epilogue: C/D map col=lane&15, row=(lane>>4)*4+reg ---
    const int col0 = bn + wc * (BN / 2) + (lane & 15);
    const int row0 = bm + wr * (BM / 2) + ((lane >> 4) << 2);

    if (mode == 4) {
        // LDS-bounce: wave-private patch (64 rows x 64 cols bf16, pitch 72
        // ushorts = 144 B, 16B-aligned rows). Scalar b16 writes (~4-way max),
        // readback 16B/lane, global stores 8 x 1KB/wave contiguous.
        ushort* patch = ((ushort*)lds) + wid * (64 * 72);
        const bool doRelu = (bn >= 8192);   // conv region, block-uniform
#pragma unroll
        for (int m = 0; m < MREP; ++m) {
#pragma unroll
            for (int n = 0; n < NREP; ++n) {
                const float bz = bias[col0 + n * 16];
#pragma unroll
                for (int rg = 0; rg < 4; ++rg) {
                    float v = acc[m][n][rg] + bz;
                    if (doRelu) v = fmaxf(v, 0.f);
                    const int lr = m * 16 + ((lane >> 4) << 2) + rg;
                    const int lc = n * 16 + (lane & 15);
                    patch[lr * 72 + lc] = f2bfu(v);
                }
            }
        }
        const int lcol8 = (lane & 7) * 8;
        const int gcol = bn + wc * (BN / 2) + lcol8;
#pragma unroll
        for (int m = 0; m < MREP; ++m) {
#pragma unroll
            for (int pass = 0; pass < 2; ++pass) {
                const int lr = m * 16 + pass * 8 + (lane >> 3);
                uint4 v4 = *(const uint4*)(patch + lr * 72 + lcol8);
                const int grow = bm + wr * (BM / 2) + lr;
                if (gcol < 8192)
                    *(uint4*)((ushort*)C2 + (size_t)grow * LDW + gcol) = v4;
                else
                    *(uint4*)((ushort*)C3 + (size_t)grow * 2048 + (gcol - 8192)) = v4;
            }
        }
        return;
    }

#pragma unroll
    for (int m = 0; m < MREP; ++m) {
#pragma unroll
        for (int n = 0; n < NREP; ++n) {
            const int cn = col0 + n * 16;
            const float bz = bias ? bias[cn] : 0.f;
#pragma unroll
            for (int rg = 0; rg < 4; ++rg) {
                const int gm = row0 + m * 16 + rg;
                float v = acc[m][n][rg] + bz;
                if (mode == 2)
                    v = fmaxf(v + resid[(size_t)gm * ldc + cn], 0.f);
                C[(size_t)gm * ldc + cn] = v;
            }
        }
    }
}

// ---------------------------------------------------------------------------
// atten[r] = sum_d ws[s[r],d] * wo[o[r],d] * phr[r,d] * Www[d]  + Wwb
// ws/wo bf16 in wswo (row stride LDW). XCD-grouped: blocks of one image land
// on one XCD so the 2 MB ws/wo slice is L2-resident.
// ---------------------------------------------------------------------------
__global__ __launch_bounds__(256) void atten_kernel(
    const ushort* __restrict__ wswo, const float* __restrict__ phr,
    const int* __restrict__ rel, const float* __restrict__ Www,
    const float* __restrict__ Wwb, float* __restrict__ atten)
{
    const int r = (blockIdx.x & 7) * 1024 + (blockIdx.x >> 3);   // 8192 = 8*1024
    const int s = rel[r * 3 + 1], o = rel[r * 3 + 2];
    const int t = threadIdx.x;
    const ushort* pws = wswo + (size_t)s * LDW;
    const ushort* pwo = wswo + (size_t)o * LDW + 4096;
    const float*  pph = phr + (size_t)r * D_;
    float sum = 0.f;
#pragma unroll
    for (int half = 0; half < 2; ++half) {
        const int q = t * 8 + half * 2048;
        ushort4 w0 = *(const ushort4*)(pws + q);
        ushort4 w1 = *(const ushort4*)(pws + q + 4);
        ushort4 u0 = *(const ushort4*)(pwo + q);
        ushort4 u1 = *(const ushort4*)(pwo + q + 4);
        float4 p0 = *(const float4*)(pph + q);
        float4 p1 = *(const float4*)(pph + q + 4);
        float4 g0 = *(const float4*)(Www + q);
        float4 g1 = *(const float4*)(Www + q + 4);
        sum += bf2f(w0.x) * bf2f(u0.x) * p0.x * g0.x
             + bf2f(w0.y) * bf2f(u0.y) * p0.y * g0.y
             + bf2f(w0.z) * bf2f(u0.z) * p0.z * g0.z
             + bf2f(w0.w) * bf2f(u0.w) * p0.w * g0.w
             + bf2f(w1.x) * bf2f(u1.x) * p1.x * g1.x
             + bf2f(w1.y) * bf2f(u1.y) * p1.y * g1.y
             + bf2f(w1.z) * bf2f(u1.z) * p1.z * g1.z
             + bf2f(w1.w) * bf2f(u1.w) * p1.w * g1.w;
    }
    for (int off = 32; off > 0; off >>= 1) sum += __shfl_down(sum, off);
    __shared__ float red[4];
    if ((t & 63) == 0) red[t >> 6] = sum;
    __syncthreads();
    if (t == 0) atten[r] = red[0] + red[1] + red[2] + red[3] + Wwb[0];
}

// ---------------------------------------------------------------------------
__global__ __launch_bounds__(256) void build_A(
    const int* __restrict__ rel, const float* __restrict__ atten,
    float* __restrict__ Anorm)
{
    const int g = blockIdx.x;
    const int t = threadIdx.x;
    __shared__ float Am[64][64];
    __shared__ float S[64];
    __shared__ int headSh;
    for (int i = t; i < 4096; i += 256) ((float*)Am)[i] = 0.f;
    if (t == 0) headSh = 0x7fffffff;

    int lmin = 0x7fffffff;
    for (int rr = t; rr < RPER; rr += 256) {
        const int base = (g * RPER + rr) * 3;
        lmin = min(lmin, min(rel[base + 1], rel[base + 2]));
    }
    for (int off = 32; off > 0; off >>= 1) lmin = min(lmin, __shfl_down(lmin, off));
    __syncthreads();
    if ((t & 63) == 0) atomicMin(&headSh, lmin);
    __syncthreads();
    const int head = headSh;

    for (int rr = t; rr < RPER; rr += 256) {
        const int base = (g * RPER + rr) * 3;
        atomicAdd(&Am[rel[base + 1] - head][rel[base + 2] - head],
                  atten[g * RPER + rr]);
    }
    __syncthreads();

    for (int idx = t; idx < 4096; idx += 256) {
        const int i = idx >> 6, j = idx & 63;
        float v = 1.f / (1.f + expf(-Am[i][j]));
        if (i == j) v = 0.f;
        Am[i][j] = v;
    }
    __syncthreads();

    if (t < 64) {
        float sum = 0.f;
        for (int k = 0; k < 64; ++k) sum += Am[t][k];
        S[t] = sum;
    }
    __syncthreads();

    float* outg = Anorm + (size_t)g * 4096;
    for (int idx = t; idx < 4096; idx += 256) {
        const int j = idx & 63;
        outg[idx] = ((const float*)Am)[idx] / S[j];
    }
}

// ---------------------------------------------------------------------------
// h[g*64+i, :] = sum_j Ar[j]*P1[g*64+j, :] + Ac[j]*P2[g*64+j, :] + Wt1_b
// then LN + affine + relu -> bf16. XCD-grouped: one image's 64 blocks land on
// one XCD so its 512 KB P-slice is fetched into that L2 once.
// ---------------------------------------------------------------------------
__global__ __launch_bounds__(256) void amult_ln(
    const float* __restrict__ Anorm, const float* __restrict__ P,
    const float* __restrict__ w1b, const float* __restrict__ gamma,
    const float* __restrict__ beta, __hip_bfloat16* __restrict__ hb)
{
    const int wg = (blockIdx.x & 7) * 128 + (blockIdx.x >> 3);   // 1024 = 8*128
    const int g = wg >> 6;
    const int i = wg & 63;
    const int t = threadIdx.x;
    __shared__ float Ar[64], Ac[64];
    if (t < 64) Ar[t] = Anorm[(size_t)g * 4096 + i * 64 + t];
    else if (t < 128) { const int j = t - 64; Ac[j] = Anorm[(size_t)g * 4096 + j * 64 + i]; }
    __syncthreads();

    const float* pg = P + (size_t)g * 64 * 2048;
    float4 v = {0, 0, 0, 0};
    for (int j = 0; j < 64; ++j) {
        float4 p1 = *(const float4*)(pg + (size_t)j * 2048 + (t << 2));
        float4 p2 = *(const float4*)(pg + (size_t)j * 2048 + 1024 + (t << 2));
        fma4(v, Ar[j], p1);
        fma4(v, Ac[j], p2);
    }
    float4 b0 = *(const float4*)(w1b + (t << 2));
    v.x += b0.x; v.y += b0.y; v.z += b0.z; v.w += b0.w;

    float s  = v.x + v.y + v.z + v.w;
    float ss = v.x * v.x + v.y * v.y + v.z * v.z + v.w * v.w;
    for (int off = 32; off > 0; off >>= 1) {
        s  += __shfl_down(s, off);
        ss += __shfl_down(ss, off);
    }
    __shared__ float rs[4], rss[4];
    if ((t & 63) == 0) { rs[t >> 6] = s; rss[t >> 6] = ss; }
    __syncthreads();
    const float tot  = rs[0] + rs[1] + rs[2] + rs[3];
    const float tot2 = rss[0] + rss[1] + rss[2] + rss[3];
    const float mu   = tot * (1.f / DT);
    const float var  = tot2 * (1.f / DT) - mu * mu;
    const float rstd = rsqrtf(var + 1e-5f);
    float4 g4 = *(const float4*)(gamma + (t << 2));
    float4 b4 = *(const float4*)(beta + (t << 2));
    float4 o;
    o.x = fmaxf(fmaf((v.x - mu) * rstd, g4.x, b4.x), 0.f);
    o.y = fmaxf(fmaf((v.y - mu) * rstd, g4.y, b4.y), 0.f);
    o.z = fmaxf(fmaf((v.z - mu) * rstd, g4.z, b4.z), 0.f);
    o.w = fmaxf(fmaf((v.w - mu) * rstd, g4.w, b4.w), 0.f);
    st4bf(hb + (size_t)(g * 64 + i) * DT + (t << 2), o);
}

// ---------------------------------------------------------------------------
extern "C" void kernel_launch(void* const* d_in, const int* in_sizes, int n_in,
                              void* d_out, int out_size, void* d_ws, size_t ws_size,
                              hipStream_t stream)
{
    const float* obj   = (const float*)d_in[0];
    const float* phr   = (const float*)d_in[1];
    const int*   rel   = (const int*)d_in[3];
    const float* Ws_w  = (const float*)d_in[5];
    const float* Ws_b  = (const float*)d_in[6];
    const float* Wo_w  = (const float*)d_in[7];
    const float* Wo_b  = (const float*)d_in[8];
    const float* Ww_w  = (const float*)d_in[9];
    const float* Ww_b  = (const float*)d_in[10];
    const float* Wc_w  = (const float*)d_in[11];
    const float* Wc_b  = (const float*)d_in[12];
    const float* Wt1_w = (const float*)d_in[13];
    const float* Wt1_b = (const float*)d_in[14];
    const float* ln_g  = (const float*)d_in[15];
    const float* ln_b  = (const float*)d_in[16];
    const float* Wt2_w = (const float*)d_in[17];
    const float* Wt2_b = (const float*)d_in[18];
    float* out = (float*)d_out;

    float* ws = (float*)d_ws;
    // workspace (float units), peak ~130.4 MB:
    __hip_bfloat16* wbuf    = (__hip_bfloat16*)ws;              // Ws|Wo|Wc bf16 — dead after fused
    __hip_bfloat16* h_bf    = (__hip_bfloat16*)ws;              // alias dead wbuf
    __hip_bfloat16* obj_bf  = (__hip_bfloat16*)(ws + 20971520); // dead after fused
    float* Pbuf             = ws + 20971520;                    // alias dead obj_bf
    __hip_bfloat16* wswo_bf = (__hip_bfloat16*)(ws + 23068672); // 1024x8192 bf16
    __hip_bfloat16* conv_bf = (__hip_bfloat16*)(ws + 27262976); // 1024x2048 bf16
    __hip_bfloat16* wt1r    = (__hip_bfloat16*)(ws + 28311552); // 2048x2048 bf16
    __hip_bfloat16* wt2b    = (__hip_bfloat16*)(ws + 30408704); // 4096x1024 bf16
    float* atten  = ws + 32505856;                              // 8192
    float* Anorm  = ws + 32514048;                              // 65536
    float* cbias  = ws + 32579584;                              // 10240

    const dim3 blk(256);

    // 1. single cast dispatch: obj, Ws, Wo, Wc, Wt1r, Wt2 -> bf16 + biases
    cast_all<<<dim3(26664), blk, 0, stream>>>(
        obj, obj_bf, Ws_w, Wo_w, Wc_w, wbuf, Wt1_w, wt1r, Wt2_w, wt2b,
        Ws_b, Wo_b, Wc_b, cbias);

    // 2. fused ws|wo|conv GEMM; ws|wo bf16 -> wswo_bf, conv relu bf16 -> conv_bf
    gemm_p2<128, 128><<<dim3(640), blk, 0, stream>>>(
        (const ushort*)obj_bf, (const ushort*)wbuf, cbias, nullptr,
        nullptr, wswo_bf, conv_bf, NTOT, D_, 0, 4);

    // 3. atten (bf16 ws/wo) + A build
    atten_kernel<<<dim3(RTOT), blk, 0, stream>>>(
        (const ushort*)wswo_bf, phr, rel, Ww_w, Ww_b, atten);
    build_A<<<dim3(NIMG), blk, 0, stream>>>(rel, atten, Anorm);

    // 4. P = conv_bf @ wt1r^T (1024 x 2048, K=2048) -> Pbuf
    gemm_p2<64, 64><<<dim3(512), blk, 0, stream>>>(
        (const ushort*)conv_bf, (const ushort*)wt1r, nullptr, nullptr,
        Pbuf, nullptr, nullptr, NTOT, DC, DC, 0);

    // 5. h = A*P1 + A^T*P2 + b, LN, relu -> bf16
    amult_ln<<<dim3(1024), blk, 0, stream>>>(Anorm, Pbuf, Wt1_b, ln_g, ln_b, h_bf);

    // 6. out = relu(obj + h @ Wt2^T + b)
    gemm_p2<64, 128><<<dim3(512), blk, 0, stream>>>(
        (const ushort*)h_bf, (const ushort*)wt2b, Wt2_b, obj,
        out, nullptr, nullptr, NTOT, DT, D_, 2);
}

// Round 13
// 287.963 us; speedup vs baseline: 2.1052x; 1.0064x over previous
//
#include <hip/hip_runtime.h>
#include <hip/hip_bf16.h>
#include <math.h>

#define D_   4096
#define NIMG 16
#define NPER 64
#define RPER 512
#define NTOT 1024
#define RTOT 8192
#define DC   2048
#define DT   1024
#define LDW  8192    // wswo_bf row stride (4096 ws | 4096 wo), bf16

typedef __attribute__((ext_vector_type(4))) float f32x4;
typedef __attribute__((ext_vector_type(8))) short bf16x8;

#define GLD16(gp, lp) __builtin_amdgcn_global_load_lds( \
    (const __attribute__((address_space(1))) unsigned int*)(gp), \
    (__attribute__((address_space(3))) unsigned int*)(lp), 16, 0, 0)

template<int N> __device__ __forceinline__ void waitvm() {
    asm volatile("s_waitcnt vmcnt(%0)" :: "n"(N) : "memory");
}

__device__ __forceinline__ void fma4(float4& d, float s, const float4 c) {
    d.x = fmaf(s, c.x, d.x); d.y = fmaf(s, c.y, d.y);
    d.z = fmaf(s, c.z, d.z); d.w = fmaf(s, c.w, d.w);
}
__device__ __forceinline__ void st4bf(__hip_bfloat16* p, float4 v) {
    union { __hip_bfloat16 h[4]; ushort4 u; } cv;
    cv.h[0] = __float2bfloat16(v.x); cv.h[1] = __float2bfloat16(v.y);
    cv.h[2] = __float2bfloat16(v.z); cv.h[3] = __float2bfloat16(v.w);
    *(ushort4*)p = cv.u;
}
__device__ __forceinline__ float bf2f(ushort u) {
    union { float f; unsigned int i; } c; c.i = (unsigned int)u << 16; return c.f;
}
__device__ __forceinline__ ushort f2bfu(float v) {
    union { __hip_bfloat16 h; ushort u; } c; c.h = __float2bfloat16(v); return c.u;
}

// ---------------------------------------------------------------------------
// ONE up-front dispatch: cast obj/Ws/Wo/Wc/Wt1(rearranged)/Wt2 -> bf16,
// concat biases.  wt1r[r][c] = Wt1[r&1023][(r>>10)*2048 + c]
// ---------------------------------------------------------------------------
__global__ __launch_bounds__(256) void cast_all(
    const float* __restrict__ obj, __hip_bfloat16* __restrict__ obj_bf,
    const float* __restrict__ Ws, const float* __restrict__ Wo,
    const float* __restrict__ Wc, __hip_bfloat16* __restrict__ wbuf,
    const float* __restrict__ Wt1, __hip_bfloat16* __restrict__ wt1r,
    const float* __restrict__ Wt2, __hip_bfloat16* __restrict__ wt2b,
    const float* __restrict__ b0, const float* __restrict__ b1,
    const float* __restrict__ b2, float* __restrict__ cb)
{
    const int b = blockIdx.x;
    const int t = threadIdx.x;
    if (b >= 26624) {                                    // bias concat
        const int i = (b - 26624) * 256 + t;             // 0..10239
        float v;
        if (i < 4096) v = b0[i];
        else if (i < 8192) v = b1[i - 4096];
        else v = b2[i - 8192];
        cb[i] = v;
        return;
    }
    const float* s; __hip_bfloat16* d;
    if (b < 2048)       { s = obj + (size_t)b * 2048;            d = obj_bf + (size_t)b * 2048; }
    else if (b < 10240) { const int rb = b - 2048;  s = Ws + (size_t)rb * 2048; d = wbuf + (size_t)rb * 2048; }
    else if (b < 18432) { const int rb = b - 10240; s = Wo + (size_t)rb * 2048; d = wbuf + 16777216 + (size_t)rb * 2048; }
    else if (b < 22528) { const int rb = b - 18432; s = Wc + (size_t)rb * 2048; d = wbuf + 33554432 + (size_t)rb * 2048; }
    else if (b < 24576) { const int r = b - 22528;                // wt1 rearranged
                          s = Wt1 + (size_t)(r & 1023) * 4096 + (r >> 10) * 2048;
                          d = wt1r + (size_t)r * 2048; }
    else                { const int rb = b - 24576; s = Wt2 + (size_t)rb * 2048; d = wt2b + (size_t)rb * 2048; }
    const int i = t * 8;
    float4 v0 = *(const float4*)(s + i);
    float4 v1 = *(const float4*)(s + i + 4);
    union { __hip_bfloat16 h[8]; ushort4 u[2]; } cv;
    cv.h[0] = __float2bfloat16(v0.x); cv.h[1] = __float2bfloat16(v0.y);
    cv.h[2] = __float2bfloat16(v0.z); cv.h[3] = __float2bfloat16(v0.w);
    cv.h[4] = __float2bfloat16(v1.x); cv.h[5] = __float2bfloat16(v1.y);
    cv.h[6] = __float2bfloat16(v1.z); cv.h[7] = __float2bfloat16(v1.w);
    *(ushort4*)(d + i)     = cv.u[0];
    *(ushort4*)(d + i + 4) = cv.u[1];
}

// ---------------------------------------------------------------------------
// Phase-split fused GEMM (ws|wo|conv): C = A @ B^T + bias, bf16 dual-output.
// 256x256 tile, 512 thr = 8 waves (2M x 4N), wave tile 128x64, BK=32.
// 3 LDS buffers (96 KB), 2-tiles-ahead staging with counted vmcnt(4) ONCE
// per K-tile (never 0 in-loop) — round-4's proven discipline — plus the
// phase-split: each K-tile = 2 phases {stage 2 gld_lds; ds_read frags;
// s_barrier; lgkmcnt(0); setprio(1) 16 MFMA setprio(0); s_barrier}.
// B-frags loaded in phase A, register-reused in phase B.
// Race-free: buf[(T+2)%3]'s readers (tile T-1) all passed T-1's final
// barrier before T's stages are issued.
// Swizzle (HW-verified zero-conflict, r9): phys 16B slot p of row r holds
// K-quarter p ^ ((r>>1)&3); applied on global source, LDS dest linear.
// Epilogue: per-wave LDS-bounce -> contiguous 16B bf16 stores.
//   cols < 8192 -> C2 (ws|wo, stride LDW); cols >= 8192 -> relu -> C3
//   (conv, stride 2048, col offset -8192).
// ---------------------------------------------------------------------------
__global__ __launch_bounds__(512, 2) void gemm8v2(
    const ushort* __restrict__ A, const ushort* __restrict__ B,
    const float* __restrict__ bias,
    __hip_bfloat16* __restrict__ C2, __hip_bfloat16* __restrict__ C3,
    int M, int K)
{
    __shared__ ushort sh[3][16384];   // per buf: A 8192 ushorts | B 8192

    const int t = threadIdx.x;
    const int lane = t & 63;
    const int wid = t >> 6;
    const int wm = wid >> 2, wn = wid & 3;

    const int MT = M >> 8;                                // 4
    const int G = gridDim.x;                              // 160 (G%8==0)
    const int wgid = (blockIdx.x & 7) * (G >> 3) + (blockIdx.x >> 3);
    const int nt = wgid / MT, mt = wgid % MT;
    const int bm = mt * 256, bn = nt * 256;

    // --- staging: thread serves A slots {t, t+512} and B slots {t, t+512} ---
    // slot s: row = s>>2 (0..255), phys quarter s&3 holds logical (s&3)^((row>>1)&3)
    const int rA0 = t >> 2,          qA0 = (t & 3) ^ ((rA0 >> 1) & 3);
    const int rA1 = (t + 512) >> 2,  qA1 = (t & 3) ^ ((rA1 >> 1) & 3);
    const ushort* gA0 = A + (size_t)(bm + rA0) * K + qA0 * 8;
    const ushort* gA1 = A + (size_t)(bm + rA1) * K + qA1 * 8;
    const ushort* gB0 = B + (size_t)(bn + rA0) * K + qA0 * 8;
    const ushort* gB1 = B + (size_t)(bn + rA1) * K + qA1 * 8;
    const int dA0 = t * 8, dA1 = (t + 512) * 8;
    const int dB0 = 8192 + t * 8, dB1 = 8192 + (t + 512) * 8;

    // --- fragment read offsets (ushort units; row pitch 32) ---
    const int sx = ((lane >> 4) ^ ((lane >> 1) & 3)) * 8;
    int aoff[8], boff[4];
#pragma unroll
    for (int m = 0; m < 8; ++m)
        aoff[m] = (wm * 128 + m * 16 + (lane & 15)) * 32 + sx;
#pragma unroll
    for (int n = 0; n < 4; ++n)
        boff[n] = 8192 + (wn * 64 + n * 16 + (lane & 15)) * 32 + sx;

    f32x4 acc[8][4] = {};
    const int NT = K >> 5;   // 128

    // prologue: stage tiles 0 and 1
    GLD16(gA0, &sh[0][dA0]); GLD16(gA1, &sh[0][dA1]);
    GLD16(gB0, &sh[0][dB0]); GLD16(gB1, &sh[0][dB1]);
    GLD16(gA0 + 32, &sh[1][dA0]); GLD16(gA1 + 32, &sh[1][dA1]);
    GLD16(gB0 + 32, &sh[1][dB0]); GLD16(gB1 + 32, &sh[1][dB1]);
    waitvm<4>();                      // tile 0 resident; tile 1 in flight
    __builtin_amdgcn_sched_barrier(0);
    __builtin_amdgcn_s_barrier();
    __builtin_amdgcn_sched_barrier(0);

    for (int T = 0; T < NT; ++T) {
        const ushort* lb = sh[T % 3];
        ushort* nb = sh[(T + 2) % 3];
        const bool pf = (T + 2 < NT);
        const int kpos = (T + 2) << 5;

        // ---------------- phase A: m 0-3 ----------------
        if (pf) { GLD16(gA0 + kpos, nb + dA0); GLD16(gA1 + kpos, nb + dA1); }
        bf16x8 bv[4], af[4];
#pragma unroll
        for (int n = 0; n < 4; ++n) bv[n] = *(const bf16x8*)(lb + boff[n]);
#pragma unroll
        for (int m = 0; m < 4; ++m) af[m] = *(const bf16x8*)(lb + aoff[m]);
        __builtin_amdgcn_s_barrier();
        asm volatile("s_waitcnt lgkmcnt(0)" ::: "memory");
        __builtin_amdgcn_sched_barrier(0);
        __builtin_amdgcn_s_setprio(1);
#pragma unroll
        for (int m = 0; m < 4; ++m)
#pragma unroll
            for (int n = 0; n < 4; ++n)
                acc[m][n] = __builtin_amdgcn_mfma_f32_16x16x32_bf16(
                    af[m], bv[n], acc[m][n], 0, 0, 0);
        __builtin_amdgcn_s_setprio(0);
        __builtin_amdgcn_sched_barrier(0);
        __builtin_amdgcn_s_barrier();

        // ---------------- phase B: m 4-7 ----------------
        if (pf) { GLD16(gB0 + kpos, nb + dB0); GLD16(gB1 + kpos, nb + dB1); }
#pragma unroll
        for (int m = 0; m < 4; ++m) af[m] = *(const bf16x8*)(lb + aoff[4 + m]);
        __builtin_amdgcn_s_barrier();
        asm volatile("s_waitcnt lgkmcnt(0)" ::: "memory");
        __builtin_amdgcn_sched_barrier(0);
        __builtin_amdgcn_s_setprio(1);
#pragma unroll
        for (int m = 0; m < 4; ++m)
#pragma unroll
            for (int n = 0; n < 4; ++n)
                acc[4 + m][n] = __builtin_amdgcn_mfma_f32_16x16x32_bf16(
                    af[m], bv[n], acc[4 + m][n], 0, 0, 0);
        __builtin_amdgcn_s_setprio(0);
        __builtin_amdgcn_sched_barrier(0);
        if (pf) waitvm<4>(); else waitvm<0>();   // tile T+1 resident; T+2 in flight
        __builtin_amdgcn_sched_barrier(0);
        __builtin_amdgcn_s_barrier();
        __builtin_amdgcn_sched_barrier(0);
    }

    // --- epilogue: LDS-bounce, wave-private patch 64x64 (pitch 72) x 2 chunks
    ushort* patch = ((ushort*)sh) + wid * (64 * 72);
    const bool doRelu = (bn >= 8192);
    const int lcol8 = (lane & 7) * 8;
#pragma unroll
    for (int chunk = 0; chunk < 2; ++chunk) {
#pragma unroll
        for (int m2 = 0; m2 < 4; ++m2) {
            const int m = chunk * 4 + m2;
#pragma unroll
            for (int n = 0; n < 4; ++n) {
                const float bz = bias[bn + wn * 64 + n * 16 + (lane & 15)];
#pragma unroll
                for (int rg = 0; rg < 4; ++rg) {
                    float v = acc[m][n][rg] + bz;
                    if (doRelu) v = fmaxf(v, 0.f);
                    const int lr = m2 * 16 + ((lane >> 4) << 2) + rg;
                    const int lc = n * 16 + (lane & 15);
                    patch[lr * 72 + lc] = f2bfu(v);
                }
            }
        }
#pragma unroll
        for (int m2 = 0; m2 < 4; ++m2) {
#pragma unroll
            for (int pass = 0; pass < 2; ++pass) {
                const int lr = m2 * 16 + pass * 8 + (lane >> 3);
                uint4 v4 = *(const uint4*)(patch + lr * 72 + lcol8);
                const int grow = bm + wm * 128 + chunk * 64 + lr;
                const int gcol = bn + wn * 64 + lcol8;
                if (gcol < 8192)
                    *(uint4*)((ushort*)C2 + (size_t)grow * LDW + gcol) = v4;
                else
                    *(uint4*)((ushort*)C3 + (size_t)grow * 2048 + (gcol - 8192)) = v4;
            }
        }
    }
}

// ---------------------------------------------------------------------------
// MFMA GEMM (round-4 schedule + r9 swizzle) — used for P-GEMM and wt2.
// mode: 0 = +bias (nullable), f32 out; 2 = relu(resid + . + bias), f32 out
// ---------------------------------------------------------------------------
template<int BM, int BN>
__global__ __launch_bounds__(256) void gemm_p2(
    const ushort* __restrict__ A, const ushort* __restrict__ B,
    const float* __restrict__ bias, const float* __restrict__ resid,
    float* __restrict__ C, int M, int K, int ldc, int mode)
{
    constexpr int MREP = BM / 32;
    constexpr int NREP = BN / 32;
    constexpr int SLOTS = (BM + BN) * 4;
    constexpr int NPW = SLOTS / 256;
    constexpr int BUFE = SLOTS * 8;

    __shared__ ushort lds[3][BUFE];

    const int t = threadIdx.x;
    const int lane = t & 63;
    const int wid = t >> 6;
    const int wr = wid >> 1, wc = wid & 1;

    const int MT = M / BM;
    const int G = gridDim.x;
    const int bid = blockIdx.x;
    const int wgid = (bid & 7) * (G >> 3) + (bid >> 3);
    const int nt = wgid / MT, mt = wgid % MT;
    const int bm = mt * BM, bn = nt * BN;

    const ushort* gp[NPW];
    int loff[NPW];
#pragma unroll
    for (int i = 0; i < NPW; ++i) {
        const int slot = i * 256 + t;
        const bool isA = slot < BM * 4;
        const int s2 = isA ? slot : slot - BM * 4;
        const int row = s2 >> 2;
        const int q = (s2 & 3) ^ ((row >> 1) & 3);
        gp[i] = (isA ? A + (size_t)(bm + row) * K : B + (size_t)(bn + row) * K) + q * 8;
        loff[i] = slot * 8;
    }

    auto stage = [&](int b, int kpos) {
#pragma unroll
        for (int i = 0; i < NPW; ++i) GLD16(gp[i] + kpos, &lds[b][loff[i]]);
    };

    int aoff[MREP], boff[NREP];
    const int sx = (((lane >> 4) ^ ((lane >> 1) & 3))) << 3;
#pragma unroll
    for (int m = 0; m < MREP; ++m)
        aoff[m] = (wr * (BM / 2) + (lane & 15) + m * 16) * 32 + sx;
#pragma unroll
    for (int n = 0; n < NREP; ++n)
        boff[n] = BM * 32 + (wc * (BN / 2) + (lane & 15) + n * 16) * 32 + sx;

    f32x4 acc[MREP][NREP] = {};

    const int NT = K >> 5;
    stage(0, 0);
    stage(1, 32);
    if constexpr (NPW == 2) waitvm<2>();
    else if constexpr (NPW == 3) waitvm<3>();
    else waitvm<4>();
    __builtin_amdgcn_sched_barrier(0);
    __builtin_amdgcn_s_barrier();
    __builtin_amdgcn_sched_barrier(0);

    for (int tt = 0; tt < NT; ++tt) {
        const bool pf = (tt + 2 < NT);
        if (pf) stage((tt + 2) % 3, (tt + 2) << 5);
        __builtin_amdgcn_sched_barrier(0);

        const ushort* lb = lds[tt % 3];
        bf16x8 af[MREP], bfv[NREP];
#pragma unroll
        for (int m = 0; m < MREP; ++m) af[m] = *(const bf16x8*)(lb + aoff[m]);
#pragma unroll
        for (int n = 0; n < NREP; ++n) bfv[n] = *(const bf16x8*)(lb + boff[n]);
#pragma unroll
        for (int m = 0; m < MREP; ++m)
#pragma unroll
            for (int n = 0; n < NREP; ++n)
                acc[m][n] = __builtin_amdgcn_mfma_f32_16x16x32_bf16(
                    af[m], bfv[n], acc[m][n], 0, 0, 0);

        __builtin_amdgcn_sched_barrier(0);
        if (pf) {
            if constexpr (NPW == 2) waitvm<2>();
            else if constexpr (NPW == 3) waitvm<3>();
            else waitvm<4>();
        } else {
            waitvm<0>();
        }
        __builtin_amdgcn_sched_barrier(0);
        __builtin_amdgcn_s_barrier();
        __builtin_amdgcn_sched_barrier(0);
    }

    const int col0 = bn + wc * (BN / 2) + (lane & 15);
    const int row0 = bm + wr * (BM / 2) + ((lane >> 4) << 2);
#pragma unroll
    for (int m = 0; m < MREP; ++m) {
#pragma unroll
        for (int n = 0; n < NREP; ++n) {
            const int cn = col0 + n * 16;
            const float bz = bias ? bias[cn] : 0.f;
#pragma unroll
            for (int rg = 0; rg < 4; ++rg) {
                const int gm = row0 + m * 16 + rg;
                float v = acc[m][n][rg] + bz;
                if (mode == 2)
                    v = fmaxf(v + resid[(size_t)gm * ldc + cn], 0.f);
                C[(size_t)gm * ldc + cn] = v;
            }
        }
    }
}

// ---------------------------------------------------------------------------
// atten[r] = sum_d ws[s[r],d] * wo[o[r],d] * phr[r,d] * Www[d]  + Wwb
// ws/wo bf16 in wswo (row stride LDW). XCD-grouped per image.
// ---------------------------------------------------------------------------
__global__ __launch_bounds__(256) void atten_kernel(
    const ushort* __restrict__ wswo, const float* __restrict__ phr,
    const int* __restrict__ rel, const float* __restrict__ Www,
    const float* __restrict__ Wwb, float* __restrict__ atten)
{
    const int r = (blockIdx.x & 7) * 1024 + (blockIdx.x >> 3);
    const int s = rel[r * 3 + 1], o = rel[r * 3 + 2];
    const int t = threadIdx.x;
    const ushort* pws = wswo + (size_t)s * LDW;
    const ushort* pwo = wswo + (size_t)o * LDW + 4096;
    const float*  pph = phr + (size_t)r * D_;
    float sum = 0.f;
#pragma unroll
    for (int half = 0; half < 2; ++half) {
        const int q = t * 8 + half * 2048;
        ushort4 w0 = *(const ushort4*)(pws + q);
        ushort4 w1 = *(const ushort4*)(pws + q + 4);
        ushort4 u0 = *(const ushort4*)(pwo + q);
        ushort4 u1 = *(const ushort4*)(pwo + q + 4);
        float4 p0 = *(const float4*)(pph + q);
        float4 p1 = *(const float4*)(pph + q + 4);
        float4 g0 = *(const float4*)(Www + q);
        float4 g1 = *(const float4*)(Www + q + 4);
        sum += bf2f(w0.x) * bf2f(u0.x) * p0.x * g0.x
             + bf2f(w0.y) * bf2f(u0.y) * p0.y * g0.y
             + bf2f(w0.z) * bf2f(u0.z) * p0.z * g0.z
             + bf2f(w0.w) * bf2f(u0.w) * p0.w * g0.w
             + bf2f(w1.x) * bf2f(u1.x) * p1.x * g1.x
             + bf2f(w1.y) * bf2f(u1.y) * p1.y * g1.y
             + bf2f(w1.z) * bf2f(u1.z) * p1.z * g1.z
             + bf2f(w1.w) * bf2f(u1.w) * p1.w * g1.w;
    }
    for (int off = 32; off > 0; off >>= 1) sum += __shfl_down(sum, off);
    __shared__ float red[4];
    if ((t & 63) == 0) red[t >> 6] = sum;
    __syncthreads();
    if (t == 0) atten[r] = red[0] + red[1] + red[2] + red[3] + Wwb[0];
}

// ---------------------------------------------------------------------------
__global__ __launch_bounds__(256) void build_A(
    const int* __restrict__ rel, const float* __restrict__ atten,
    float* __restrict__ Anorm)
{
    const int g = blockIdx.x;
    const int t = threadIdx.x;
    __shared__ float Am[64][64];
    __shared__ float S[64];
    __shared__ int headSh;
    for (int i = t; i < 4096; i += 256) ((float*)Am)[i] = 0.f;
    if (t == 0) headSh = 0x7fffffff;

    int lmin = 0x7fffffff;
    for (int rr = t; rr < RPER; rr += 256) {
        const int base = (g * RPER + rr) * 3;
        lmin = min(lmin, min(rel[base + 1], rel[base + 2]));
    }
    for (int off = 32; off > 0; off >>= 1) lmin = min(lmin, __shfl_down(lmin, off));
    __syncthreads();
    if ((t & 63) == 0) atomicMin(&headSh, lmin);
    __syncthreads();
    const int head = headSh;

    for (int rr = t; rr < RPER; rr += 256) {
        const int base = (g * RPER + rr) * 3;
        atomicAdd(&Am[rel[base + 1] - head][rel[base + 2] - head],
                  atten[g * RPER + rr]);
    }
    __syncthreads();

    for (int idx = t; idx < 4096; idx += 256) {
        const int i = idx >> 6, j = idx & 63;
        float v = 1.f / (1.f + expf(-Am[i][j]));
        if (i == j) v = 0.f;
        Am[i][j] = v;
    }
    __syncthreads();

    if (t < 64) {
        float sum = 0.f;
        for (int k = 0; k < 64; ++k) sum += Am[t][k];
        S[t] = sum;
    }
    __syncthreads();

    float* outg = Anorm + (size_t)g * 4096;
    for (int idx = t; idx < 4096; idx += 256) {
        const int j = idx & 63;
        outg[idx] = ((const float*)Am)[idx] / S[j];
    }
}

// ---------------------------------------------------------------------------
// h[g*64+i, :] = sum_j Ar[j]*P1[g*64+j, :] + Ac[j]*P2[g*64+j, :] + Wt1_b
// then LN + affine + relu -> bf16. XCD-grouped per image.
// ---------------------------------------------------------------------------
__global__ __launch_bounds__(256) void amult_ln(
    const float* __restrict__ Anorm, const float* __restrict__ P,
    const float* __restrict__ w1b, const float* __restrict__ gamma,
    const float* __restrict__ beta, __hip_bfloat16* __restrict__ hb)
{
    const int wg = (blockIdx.x & 7) * 128 + (blockIdx.x >> 3);
    const int g = wg >> 6;
    const int i = wg & 63;
    const int t = threadIdx.x;
    __shared__ float Ar[64], Ac[64];
    if (t < 64) Ar[t] = Anorm[(size_t)g * 4096 + i * 64 + t];
    else if (t < 128) { const int j = t - 64; Ac[j] = Anorm[(size_t)g * 4096 + j * 64 + i]; }
    __syncthreads();

    const float* pg = P + (size_t)g * 64 * 2048;
    float4 v = {0, 0, 0, 0};
    for (int j = 0; j < 64; ++j) {
        float4 p1 = *(const float4*)(pg + (size_t)j * 2048 + (t << 2));
        float4 p2 = *(const float4*)(pg + (size_t)j * 2048 + 1024 + (t << 2));
        fma4(v, Ar[j], p1);
        fma4(v, Ac[j], p2);
    }
    float4 b0 = *(const float4*)(w1b + (t << 2));
    v.x += b0.x; v.y += b0.y; v.z += b0.z; v.w += b0.w;

    float s  = v.x + v.y + v.z + v.w;
    float ss = v.x * v.x + v.y * v.y + v.z * v.z + v.w * v.w;
    for (int off = 32; off > 0; off >>= 1) {
        s  += __shfl_down(s, off);
        ss += __shfl_down(ss, off);
    }
    __shared__ float rs[4], rss[4];
    if ((t & 63) == 0) { rs[t >> 6] = s; rss[t >> 6] = ss; }
    __syncthreads();
    const float tot  = rs[0] + rs[1] + rs[2] + rs[3];
    const float tot2 = rss[0] + rss[1] + rss[2] + rss[3];
    const float mu   = tot * (1.f / DT);
    const float var  = tot2 * (1.f / DT) - mu * mu;
    const float rstd = rsqrtf(var + 1e-5f);
    float4 g4 = *(const float4*)(gamma + (t << 2));
    float4 b4 = *(const float4*)(beta + (t << 2));
    float4 o;
    o.x = fmaxf(fmaf((v.x - mu) * rstd, g4.x, b4.x), 0.f);
    o.y = fmaxf(fmaf((v.y - mu) * rstd, g4.y, b4.y), 0.f);
    o.z = fmaxf(fmaf((v.z - mu) * rstd, g4.z, b4.z), 0.f);
    o.w = fmaxf(fmaf((v.w - mu) * rstd, g4.w, b4.w), 0.f);
    st4bf(hb + (size_t)(g * 64 + i) * DT + (t << 2), o);
}

// ---------------------------------------------------------------------------
extern "C" void kernel_launch(void* const* d_in, const int* in_sizes, int n_in,
                              void* d_out, int out_size, void* d_ws, size_t ws_size,
                              hipStream_t stream)
{
    const float* obj   = (const float*)d_in[0];
    const float* phr   = (const float*)d_in[1];
    const int*   rel   = (const int*)d_in[3];
    const float* Ws_w  = (const float*)d_in[5];
    const float* Ws_b  = (const float*)d_in[6];
    const float* Wo_w  = (const float*)d_in[7];
    const float* Wo_b  = (const float*)d_in[8];
    const float* Ww_w  = (const float*)d_in[9];
    const float* Ww_b  = (const float*)d_in[10];
    const float* Wc_w  = (const float*)d_in[11];
    const float* Wc_b  = (const float*)d_in[12];
    const float* Wt1_w = (const float*)d_in[13];
    const float* Wt1_b = (const float*)d_in[14];
    const float* ln_g  = (const float*)d_in[15];
    const float* ln_b  = (const float*)d_in[16];
    const float* Wt2_w = (const float*)d_in[17];
    const float* Wt2_b = (const float*)d_in[18];
    float* out = (float*)d_out;

    float* ws = (float*)d_ws;
    // workspace (float units), peak ~130.4 MB:
    __hip_bfloat16* wbuf    = (__hip_bfloat16*)ws;              // Ws|Wo|Wc bf16 — dead after fused
    __hip_bfloat16* h_bf    = (__hip_bfloat16*)ws;              // alias dead wbuf
    __hip_bfloat16* obj_bf  = (__hip_bfloat16*)(ws + 20971520); // dead after fused
    float* Pbuf             = ws + 20971520;                    // alias dead obj_bf
    __hip_bfloat16* wswo_bf = (__hip_bfloat16*)(ws + 23068672); // 1024x8192 bf16
    __hip_bfloat16* conv_bf = (__hip_bfloat16*)(ws + 27262976); // 1024x2048 bf16
    __hip_bfloat16* wt1r    = (__hip_bfloat16*)(ws + 28311552); // 2048x2048 bf16
    __hip_bfloat16* wt2b    = (__hip_bfloat16*)(ws + 30408704); // 4096x1024 bf16
    float* atten  = ws + 32505856;                              // 8192
    float* Anorm  = ws + 32514048;                              // 65536
    float* cbias  = ws + 32579584;                              // 10240

    const dim3 blk(256);

    // 1. single cast dispatch: obj, Ws, Wo, Wc, Wt1r, Wt2 -> bf16 + biases
    cast_all<<<dim3(26664), blk, 0, stream>>>(
        obj, obj_bf, Ws_w, Wo_w, Wc_w, wbuf, Wt1_w, wt1r, Wt2_w, wt2b,
        Ws_b, Wo_b, Wc_b, cbias);

    // 2. fused ws|wo|conv GEMM — phase-split 256² 8-wave kernel
    gemm8v2<<<dim3(160), dim3(512), 0, stream>>>(
        (const ushort*)obj_bf, (const ushort*)wbuf, cbias,
        wswo_bf, conv_bf, NTOT, D_);

    // 3. atten (bf16 ws/wo) + A build
    atten_kernel<<<dim3(RTOT), blk, 0, stream>>>(
        (const ushort*)wswo_bf, phr, rel, Ww_w, Ww_b, atten);
    build_A<<<dim3(NIMG), blk, 0, stream>>>(rel, atten, Anorm);

    // 4. P = conv_bf @ wt1r^T (1024 x 2048, K=2048) -> Pbuf
    gemm_p2<64, 64><<<dim3(512), blk, 0, stream>>>(
        (const ushort*)conv_bf, (const ushort*)wt1r, nullptr, nullptr,
        Pbuf, NTOT, DC, DC, 0);

    // 5. h = A*P1 + A^T*P2 + b, LN, relu -> bf16
    amult_ln<<<dim3(1024), blk, 0, stream>>>(Anorm, Pbuf, Wt1_b, ln_g, ln_b, h_bf);

    // 6. out = relu(obj + h @ Wt2^T + b)
    gemm_p2<64, 128><<<dim3(512), blk, 0, stream>>>(
        (const ushort*)h_bf, (const ushort*)wt2b, Wt2_b, obj,
        out, NTOT, DT, D_, 2);
}